// Round 1
// baseline (1226.812 us; speedup 1.0000x reference)
//
#include <hip/hip_runtime.h>
#include <hip/hip_bf16.h>

#define N_NODES 100000
#define N_EDGES 1600000
#define DD 128
#define N_GRAPHS 512
#define BN_EPS 1e-5f
#define NTILES 1563            // ceil(100000/64)
#define SCAN_B 98              // ceil(100000/1024)

typedef unsigned int u32;
typedef unsigned char u8;
typedef __bf16 bf16_t;
typedef __bf16 bf16x2 __attribute__((ext_vector_type(2)));
typedef __bf16 bf16x4 __attribute__((ext_vector_type(4)));
typedef __bf16 bf16x8 __attribute__((ext_vector_type(8)));
typedef float f32x4 __attribute__((ext_vector_type(4)));

__device__ __forceinline__ float bflo2f(u32 u) {
    union { u32 i; float f; } x; x.i = u << 16; return x.f;
}
__device__ __forceinline__ float bfhi2f(u32 u) {
    union { u32 i; float f; } x; x.i = u & 0xffff0000u; return x.f;
}
__device__ __forceinline__ u32 pack4u(float v0, float v1, float v2, float v3, float inv) {
    u32 q0 = (u32)fminf(rintf(v0 * inv), 255.f);
    u32 q1 = (u32)fminf(rintf(v1 * inv), 255.f);
    u32 q2 = (u32)fminf(rintf(v2 * inv), 255.f);
    u32 q3 = (u32)fminf(rintf(v3 * inv), 255.f);
    return q0 | (q1 << 8) | (q2 << 16) | (q3 << 24);
}

// ---------------- utility kernels ----------------

__global__ void k_zero(float4* p, int n) {
    float4 z = make_float4(0.f, 0.f, 0.f, 0.f);
    for (int i = blockIdx.x * blockDim.x + threadIdx.x; i < n; i += gridDim.x * blockDim.x)
        p[i] = z;
}

__global__ void k_hist(const int* __restrict__ dst, int* __restrict__ deg) {
    for (int e = blockIdx.x * blockDim.x + threadIdx.x; e < N_EDGES; e += gridDim.x * blockDim.x)
        atomicAdd(&deg[dst[e]], 1);
}

// hierarchical scan of padded degrees ((deg+3)&~3) -> poffs, cursor
__global__ void k_scan1(const int* __restrict__ deg, int* __restrict__ bsum) {
    __shared__ int sh[1024];
    int b = blockIdx.x, t = threadIdx.x;
    int i = b * 1024 + t;
    int pd = (i < N_NODES) ? ((deg[i] + 3) & ~3) : 0;
    sh[t] = pd;
    __syncthreads();
    for (int s = 512; s > 0; s >>= 1) {
        if (t < s) sh[t] += sh[t + s];
        __syncthreads();
    }
    if (t == 0) bsum[b] = sh[0];
}
__global__ void k_scan2(const int* __restrict__ bsum, int* __restrict__ bbase,
                        int* __restrict__ poffs) {
    __shared__ int sh[128];
    int t = threadIdx.x;
    int v = (t < SCAN_B) ? bsum[t] : 0;
    sh[t] = v;
    __syncthreads();
    for (int d = 1; d < 128; d <<= 1) {
        int o = (t >= d) ? sh[t - d] : 0;
        __syncthreads();
        sh[t] += o;
        __syncthreads();
    }
    if (t < SCAN_B) bbase[t] = sh[t] - v;          // exclusive base per block
    if (t == SCAN_B - 1) poffs[N_NODES] = sh[t];   // total padded edges
}
__global__ void k_scan3(const int* __restrict__ deg, const int* __restrict__ bbase,
                        int* __restrict__ poffs, int* __restrict__ cursor) {
    __shared__ int sh[1024];
    int b = blockIdx.x, t = threadIdx.x;
    int i = b * 1024 + t;
    int pd = (i < N_NODES) ? ((deg[i] + 3) & ~3) : 0;
    sh[t] = pd;
    __syncthreads();
    for (int d = 1; d < 1024; d <<= 1) {
        int o = (t >= d) ? sh[t - d] : 0;
        __syncthreads();
        sh[t] += o;
        __syncthreads();
    }
    if (i < N_NODES) {
        int off = bbase[b] + sh[t] - pd;
        poffs[i] = off; cursor[i] = off;
    }
}

__global__ void k_fill(const int* __restrict__ src, const int* __restrict__ dst,
                       int* __restrict__ cursor, int* __restrict__ csr) {
    for (int e = blockIdx.x * blockDim.x + threadIdx.x; e < N_EDGES; e += gridDim.x * blockDim.x) {
        int pos = atomicAdd(&cursor[dst[e]], 1);
        csr[pos] = src[e];
    }
}

// fill pad slots with the DEST node's own index; gather subtracts the
// overcount via the self-term coefficient (1 - #pads). Self line is L1-hot.
__global__ void k_pad(const int* __restrict__ deg, const int* __restrict__ poffs,
                      int* __restrict__ csr) {
    int t = blockIdx.x * blockDim.x + threadIdx.x;
    if (t >= N_NODES * 4) return;
    int n = t >> 2, j = t & 3;
    int s = poffs[n] + deg[n];
    if (s + j < poffs[n + 1]) csr[s + j] = n;
}

__global__ void k_cvt(const float* __restrict__ x, bf16_t* __restrict__ xb) {
    const int n4 = N_NODES * DD / 4;
    const float4* x4 = (const float4*)x;
    bf16x4* o4 = (bf16x4*)xb;
    for (int i = blockIdx.x * blockDim.x + threadIdx.x; i < n4; i += gridDim.x * blockDim.x) {
        float4 v = x4[i];
        bf16x4 o;
        o.x = (bf16_t)v.x; o.y = (bf16_t)v.y; o.z = (bf16_t)v.z; o.w = (bf16_t)v.w;
        o4[i] = o;
    }
}

// Pre-shuffle the 6 weight matrices into exact MFMA B-fragment order (bf16).
__global__ void k_shufw(const float* __restrict__ W1s, const float* __restrict__ W2s,
                        bf16_t* __restrict__ wshuf) {
    int t = blockIdx.x * blockDim.x + threadIdx.x;
    if (t >= 6 * 16384) return;
    int g  = t >> 14;
    int r  = t & 16383;
    int j  = r & 7;
    int L  = (r >> 3) & 63;
    int nt = (r >> 9) & 7;
    int ks = r >> 12;
    int l  = g >> 1;
    const float* src = (g & 1) ? (W2s + l * 16384) : (W1s + l * 16384);
    int k = ks * 32 + (L >> 4) * 8 + j;
    int n = nt * 16 + (L & 15);
    wshuf[t] = (bf16_t)src[k * DD + n];
}

__global__ void k_aff_init(float* __restrict__ ss) {
    int f = threadIdx.x;
    if (f < DD) { ss[f] = 1.0f; ss[DD + f] = 0.0f; }
}

__global__ void k_aff_update(const float* __restrict__ stats, const float* __restrict__ gamma,
                             const float* __restrict__ beta, float* __restrict__ scale,
                             float* __restrict__ shift) {
    int f = threadIdx.x;
    if (f < DD) {
        float mu  = stats[f] * (1.0f / N_NODES);
        float var = stats[DD + f] * (1.0f / N_NODES) - mu * mu;
        float inv = rsqrtf(var + BN_EPS);
        float sc  = gamma[f] * inv;
        scale[f] = sc;
        shift[f] = beta[f] - mu * sc;
    }
}

__global__ void k_gbounds(const int* __restrict__ batch, int* __restrict__ gstart) {
    int i = blockIdx.x * blockDim.x + threadIdx.x;
    if (i >= N_NODES) return;
    int b = batch[i];
    int bp = (i == 0) ? -1 : batch[i - 1];
    for (int g = bp + 1; g <= b; ++g) gstart[g] = i;
    if (i == N_NODES - 1)
        for (int g = b + 1; g <= N_GRAPHS; ++g) gstart[g] = N_NODES;
}

// ---------------- gather helpers ----------------

// one int4-group (4 padded edges) of one node
template<bool IN_U8>
__device__ __forceinline__ void gather_step(
    const bf16_t* __restrict__ xb, const u8* __restrict__ x8,
    const float* __restrict__ xsc, const int* __restrict__ csr,
    int e, int fb, int fb2, float& a0, float& a1)
{
    int4 q = *(const int4*)(csr + e);
    if (IN_U8) {
        u32 u0 = *(const unsigned short*)(x8 + ((size_t)q.x << 7) + fb);
        u32 u1 = *(const unsigned short*)(x8 + ((size_t)q.y << 7) + fb);
        u32 u2 = *(const unsigned short*)(x8 + ((size_t)q.z << 7) + fb);
        u32 u3 = *(const unsigned short*)(x8 + ((size_t)q.w << 7) + fb);
        float s0 = xsc[q.x], s1 = xsc[q.y], s2 = xsc[q.z], s3 = xsc[q.w];
        a0 += s0 * (float)(u0 & 0xffu); a1 += s0 * (float)(u0 >> 8);
        a0 += s1 * (float)(u1 & 0xffu); a1 += s1 * (float)(u1 >> 8);
        a0 += s2 * (float)(u2 & 0xffu); a1 += s2 * (float)(u2 >> 8);
        a0 += s3 * (float)(u3 & 0xffu); a1 += s3 * (float)(u3 >> 8);
    } else {
        u32 v0 = *(const u32*)((const u8*)xb + ((size_t)q.x << 8) + fb2);
        u32 v1 = *(const u32*)((const u8*)xb + ((size_t)q.y << 8) + fb2);
        u32 v2 = *(const u32*)((const u8*)xb + ((size_t)q.z << 8) + fb2);
        u32 v3 = *(const u32*)((const u8*)xb + ((size_t)q.w << 8) + fb2);
        a0 += bflo2f(v0) + bflo2f(v1) + bflo2f(v2) + bflo2f(v3);
        a1 += bfhi2f(v0) + bfhi2f(v1) + bfhi2f(v2) + bfhi2f(v3);
    }
}

// self term + BN-affine + LDS row write
template<bool IN_U8>
__device__ __forceinline__ void finalize_row(
    const bf16_t* __restrict__ xb, const u8* __restrict__ x8,
    const float* __restrict__ xsc, const int* __restrict__ deg,
    int node, bool valid, int row, float a0, float a1,
    float sc0, float sc1, float sh0, float sh1, int fb, int fb2,
    bf16_t* __restrict__ tile)
{
    if (valid) {
        int dg = deg[node];
        float selfco = 1.f - (float)(((dg + 3) & ~3) - dg);
        if (IN_U8) {
            u32 sv = *(const unsigned short*)(x8 + ((size_t)node << 7) + fb);
            float ssv = selfco * xsc[node];
            a0 += ssv * (float)(sv & 0xffu); a1 += ssv * (float)(sv >> 8);
        } else {
            u32 sv = *(const u32*)((const u8*)xb + ((size_t)node << 8) + fb2);
            a0 += selfco * bflo2f(sv); a1 += selfco * bfhi2f(sv);
        }
        float cnt = (float)(dg + 1);
        bf16x2 pk;
        pk.x = (bf16_t)(a0 * sc0 + cnt * sh0);
        pk.y = (bf16_t)(a1 * sc1 + cnt * sh1);
        *(bf16x2*)(&tile[row * 136 + fb]) = pk;
    } else {
        bf16x2 z; z.x = (bf16_t)0.f; z.y = (bf16_t)0.f;
        *(bf16x2*)(&tile[row * 136 + fb]) = z;
    }
}

// ---------------- fused GIN layer ----------------
// block = 256 (4 waves), 64 nodes. Divergence-free gather: lane l covers
// features (2l, 2l+1); one edge = one wave-load (u8: 1 line; bf16: 2 lines).
// R12: FOUR independent nodes interleaved per wave (rows rp, rp+4, rp+8,
// rp+12) — the quad master loop issues 16 row loads + 4 uniform index
// vectors per iteration, 2x the outstanding misses of the dual version at
// identical traffic and identical per-node summation order. Indices/scales
// are wave-uniform -> SGPR loads (no vmcnt slots). launch_bounds min-waves
// relaxed 8->6 so the allocator can keep 16 row values live; runtime
// occupancy stays 8 blocks/CU while VGPR<=64 (LDS allows 9).
template<bool IN_U8>
__global__ __launch_bounds__(256, 6) void k_layer(
    const bf16_t* __restrict__ xb,
    const u8* __restrict__ x8, const float* __restrict__ xsc,
    u8* __restrict__ y8, float* __restrict__ ysc,
    const int* __restrict__ poffs, const int* __restrict__ csr,
    const int* __restrict__ deg,
    const float* __restrict__ scale, const float* __restrict__ shift,
    const bf16_t* __restrict__ w1s, const bf16_t* __restrict__ w2s,
    const float* __restrict__ b1, const float* __restrict__ b2,
    float* __restrict__ stats)
{
    __shared__ __align__(16) bf16_t tile[64 * 136];

    const int tid  = threadIdx.x;
    const int w    = tid >> 6;
    const int lane = tid & 63;
    const int base = blockIdx.x * 64;
    const int fb   = lane << 1;          // feature pair
    const int fb2  = fb << 1;            // byte offset in bf16 row

    const float sc0 = scale[fb], sc1 = scale[fb + 1];
    const float sh0 = shift[fb], sh1 = shift[fb + 1];

    // ---- Phase 1: quad-node interleaved gather -> tile ----
    for (int rp = 0; rp < 4; ++rp) {
        const int rowA = (w << 4) + rp;
        const int rowB = rowA + 4;
        const int rowC = rowA + 8;
        const int rowD = rowA + 12;
        const int nA = base + rowA, nB = base + rowB;
        const int nC = base + rowC, nD = base + rowD;
        const bool vA = (nA < N_NODES), vB = (nB < N_NODES);
        const bool vC = (nC < N_NODES), vD = (nD < N_NODES);
        float a0A = 0.f, a1A = 0.f, a0B = 0.f, a1B = 0.f;
        float a0C = 0.f, a1C = 0.f, a0D = 0.f, a1D = 0.f;
        int eA = 0, eEA = 0, eB = 0, eEB = 0;
        int eC = 0, eEC = 0, eD = 0, eED = 0;
        if (vA) { eA = poffs[nA]; eEA = poffs[nA + 1]; }
        if (vB) { eB = poffs[nB]; eEB = poffs[nB + 1]; }
        if (vC) { eC = poffs[nC]; eEC = poffs[nC + 1]; }
        if (vD) { eD = poffs[nD]; eED = poffs[nD + 1]; }

        // quad master loop: 16 edges (4 per node) in flight
        while ((eA < eEA) & (eB < eEB) & (eC < eEC) & (eD < eED)) {
            int4 qA = *(const int4*)(csr + eA);
            int4 qB = *(const int4*)(csr + eB);
            int4 qC = *(const int4*)(csr + eC);
            int4 qD = *(const int4*)(csr + eD);
            if (IN_U8) {
                u32 uA0 = *(const unsigned short*)(x8 + ((size_t)qA.x << 7) + fb);
                u32 uA1 = *(const unsigned short*)(x8 + ((size_t)qA.y << 7) + fb);
                u32 uA2 = *(const unsigned short*)(x8 + ((size_t)qA.z << 7) + fb);
                u32 uA3 = *(const unsigned short*)(x8 + ((size_t)qA.w << 7) + fb);
                u32 uB0 = *(const unsigned short*)(x8 + ((size_t)qB.x << 7) + fb);
                u32 uB1 = *(const unsigned short*)(x8 + ((size_t)qB.y << 7) + fb);
                u32 uB2 = *(const unsigned short*)(x8 + ((size_t)qB.z << 7) + fb);
                u32 uB3 = *(const unsigned short*)(x8 + ((size_t)qB.w << 7) + fb);
                u32 uC0 = *(const unsigned short*)(x8 + ((size_t)qC.x << 7) + fb);
                u32 uC1 = *(const unsigned short*)(x8 + ((size_t)qC.y << 7) + fb);
                u32 uC2 = *(const unsigned short*)(x8 + ((size_t)qC.z << 7) + fb);
                u32 uC3 = *(const unsigned short*)(x8 + ((size_t)qC.w << 7) + fb);
                u32 uD0 = *(const unsigned short*)(x8 + ((size_t)qD.x << 7) + fb);
                u32 uD1 = *(const unsigned short*)(x8 + ((size_t)qD.y << 7) + fb);
                u32 uD2 = *(const unsigned short*)(x8 + ((size_t)qD.z << 7) + fb);
                u32 uD3 = *(const unsigned short*)(x8 + ((size_t)qD.w << 7) + fb);
                float sA0 = xsc[qA.x], sA1 = xsc[qA.y], sA2 = xsc[qA.z], sA3 = xsc[qA.w];
                float sB0 = xsc[qB.x], sB1 = xsc[qB.y], sB2 = xsc[qB.z], sB3 = xsc[qB.w];
                float sC0 = xsc[qC.x], sC1 = xsc[qC.y], sC2 = xsc[qC.z], sC3 = xsc[qC.w];
                float sD0 = xsc[qD.x], sD1 = xsc[qD.y], sD2 = xsc[qD.z], sD3 = xsc[qD.w];
                a0A += sA0 * (float)(uA0 & 0xffu); a1A += sA0 * (float)(uA0 >> 8);
                a0A += sA1 * (float)(uA1 & 0xffu); a1A += sA1 * (float)(uA1 >> 8);
                a0A += sA2 * (float)(uA2 & 0xffu); a1A += sA2 * (float)(uA2 >> 8);
                a0A += sA3 * (float)(uA3 & 0xffu); a1A += sA3 * (float)(uA3 >> 8);
                a0B += sB0 * (float)(uB0 & 0xffu); a1B += sB0 * (float)(uB0 >> 8);
                a0B += sB1 * (float)(uB1 & 0xffu); a1B += sB1 * (float)(uB1 >> 8);
                a0B += sB2 * (float)(uB2 & 0xffu); a1B += sB2 * (float)(uB2 >> 8);
                a0B += sB3 * (float)(uB3 & 0xffu); a1B += sB3 * (float)(uB3 >> 8);
                a0C += sC0 * (float)(uC0 & 0xffu); a1C += sC0 * (float)(uC0 >> 8);
                a0C += sC1 * (float)(uC1 & 0xffu); a1C += sC1 * (float)(uC1 >> 8);
                a0C += sC2 * (float)(uC2 & 0xffu); a1C += sC2 * (float)(uC2 >> 8);
                a0C += sC3 * (float)(uC3 & 0xffu); a1C += sC3 * (float)(uC3 >> 8);
                a0D += sD0 * (float)(uD0 & 0xffu); a1D += sD0 * (float)(uD0 >> 8);
                a0D += sD1 * (float)(uD1 & 0xffu); a1D += sD1 * (float)(uD1 >> 8);
                a0D += sD2 * (float)(uD2 & 0xffu); a1D += sD2 * (float)(uD2 >> 8);
                a0D += sD3 * (float)(uD3 & 0xffu); a1D += sD3 * (float)(uD3 >> 8);
            } else {
                u32 vA0 = *(const u32*)((const u8*)xb + ((size_t)qA.x << 8) + fb2);
                u32 vA1 = *(const u32*)((const u8*)xb + ((size_t)qA.y << 8) + fb2);
                u32 vA2 = *(const u32*)((const u8*)xb + ((size_t)qA.z << 8) + fb2);
                u32 vA3 = *(const u32*)((const u8*)xb + ((size_t)qA.w << 8) + fb2);
                u32 vB0 = *(const u32*)((const u8*)xb + ((size_t)qB.x << 8) + fb2);
                u32 vB1 = *(const u32*)((const u8*)xb + ((size_t)qB.y << 8) + fb2);
                u32 vB2 = *(const u32*)((const u8*)xb + ((size_t)qB.z << 8) + fb2);
                u32 vB3 = *(const u32*)((const u8*)xb + ((size_t)qB.w << 8) + fb2);
                u32 vC0 = *(const u32*)((const u8*)xb + ((size_t)qC.x << 8) + fb2);
                u32 vC1 = *(const u32*)((const u8*)xb + ((size_t)qC.y << 8) + fb2);
                u32 vC2 = *(const u32*)((const u8*)xb + ((size_t)qC.z << 8) + fb2);
                u32 vC3 = *(const u32*)((const u8*)xb + ((size_t)qC.w << 8) + fb2);
                u32 vD0 = *(const u32*)((const u8*)xb + ((size_t)qD.x << 8) + fb2);
                u32 vD1 = *(const u32*)((const u8*)xb + ((size_t)qD.y << 8) + fb2);
                u32 vD2 = *(const u32*)((const u8*)xb + ((size_t)qD.z << 8) + fb2);
                u32 vD3 = *(const u32*)((const u8*)xb + ((size_t)qD.w << 8) + fb2);
                a0A += bflo2f(vA0) + bflo2f(vA1) + bflo2f(vA2) + bflo2f(vA3);
                a1A += bfhi2f(vA0) + bfhi2f(vA1) + bfhi2f(vA2) + bfhi2f(vA3);
                a0B += bflo2f(vB0) + bflo2f(vB1) + bflo2f(vB2) + bflo2f(vB3);
                a1B += bfhi2f(vB0) + bfhi2f(vB1) + bfhi2f(vB2) + bfhi2f(vB3);
                a0C += bflo2f(vC0) + bflo2f(vC1) + bflo2f(vC2) + bflo2f(vC3);
                a1C += bfhi2f(vC0) + bfhi2f(vC1) + bfhi2f(vC2) + bfhi2f(vC3);
                a0D += bflo2f(vD0) + bflo2f(vD1) + bflo2f(vD2) + bflo2f(vD3);
                a1D += bfhi2f(vD0) + bfhi2f(vD1) + bfhi2f(vD2) + bfhi2f(vD3);
            }
            eA += 4; eB += 4; eC += 4; eD += 4;
        }
        // pair drains (8 edges in flight)
        while ((eA < eEA) & (eB < eEB)) {
            gather_step<IN_U8>(xb, x8, xsc, csr, eA, fb, fb2, a0A, a1A);
            gather_step<IN_U8>(xb, x8, xsc, csr, eB, fb, fb2, a0B, a1B);
            eA += 4; eB += 4;
        }
        while ((eC < eEC) & (eD < eED)) {
            gather_step<IN_U8>(xb, x8, xsc, csr, eC, fb, fb2, a0C, a1C);
            gather_step<IN_U8>(xb, x8, xsc, csr, eD, fb, fb2, a0D, a1D);
            eC += 4; eD += 4;
        }
        // single drains
        while (eA < eEA) { gather_step<IN_U8>(xb, x8, xsc, csr, eA, fb, fb2, a0A, a1A); eA += 4; }
        while (eB < eEB) { gather_step<IN_U8>(xb, x8, xsc, csr, eB, fb, fb2, a0B, a1B); eB += 4; }
        while (eC < eEC) { gather_step<IN_U8>(xb, x8, xsc, csr, eC, fb, fb2, a0C, a1C); eC += 4; }
        while (eD < eED) { gather_step<IN_U8>(xb, x8, xsc, csr, eD, fb, fb2, a0D, a1D); eD += 4; }

        finalize_row<IN_U8>(xb, x8, xsc, deg, nA, vA, rowA, a0A, a1A, sc0, sc1, sh0, sh1, fb, fb2, tile);
        finalize_row<IN_U8>(xb, x8, xsc, deg, nB, vB, rowB, a0B, a1B, sc0, sc1, sh0, sh1, fb, fb2, tile);
        finalize_row<IN_U8>(xb, x8, xsc, deg, nC, vC, rowC, a0C, a1C, sc0, sc1, sh0, sh1, fb, fb2, tile);
        finalize_row<IN_U8>(xb, x8, xsc, deg, nD, vD, rowD, a0D, a1D, sc0, sc1, sh0, sh1, fb, fb2, tile);
    }
    __syncthreads();

    // ---- Phase 2: GEMM1 + bias + relu -> tile (reused) ----
    const int q = lane >> 4;
    const int c16 = lane & 15;
    const int arow = (w << 4) + c16;

    bf16x8 afr[4];
#pragma unroll
    for (int ks = 0; ks < 4; ++ks)
        afr[ks] = *(const bf16x8*)(&tile[arow * 136 + ks * 32 + q * 8]);
    __syncthreads();

    f32x4 acc[8];
#pragma unroll
    for (int nt = 0; nt < 8; ++nt) acc[nt] = (f32x4){0.f, 0.f, 0.f, 0.f};
#pragma unroll
    for (int ks = 0; ks < 4; ++ks) {
#pragma unroll
        for (int nt = 0; nt < 8; ++nt) {
            bf16x8 bfr = *(const bf16x8*)(w1s + (((ks << 3) + nt) * 64 + lane) * 8);
            acc[nt] = __builtin_amdgcn_mfma_f32_16x16x32_bf16(afr[ks], bfr, acc[nt], 0, 0, 0);
        }
    }
#pragma unroll
    for (int nt = 0; nt < 8; ++nt) {
        float bias = b1[(nt << 4) + c16];
#pragma unroll
        for (int i = 0; i < 4; ++i) {
            float v = fmaxf(acc[nt][i] + bias, 0.f);
            int row = (w << 4) + (q << 2) + i;
            tile[row * 136 + (nt << 4) + c16] = (bf16_t)v;
        }
    }
    __syncthreads();

    // ---- Phase 3: GEMM2 + bias + relu + BN stats -> tile ----
    bf16x8 afr2[4];
#pragma unroll
    for (int ks = 0; ks < 4; ++ks)
        afr2[ks] = *(const bf16x8*)(&tile[arow * 136 + ks * 32 + q * 8]);
    __syncthreads(); // tile overwritten below

#pragma unroll
    for (int nt = 0; nt < 8; ++nt) acc[nt] = (f32x4){0.f, 0.f, 0.f, 0.f};
#pragma unroll
    for (int ks = 0; ks < 4; ++ks) {
#pragma unroll
        for (int nt = 0; nt < 8; ++nt) {
            bf16x8 bfr = *(const bf16x8*)(w2s + (((ks << 3) + nt) * 64 + lane) * 8);
            acc[nt] = __builtin_amdgcn_mfma_f32_16x16x32_bf16(afr2[ks], bfr, acc[nt], 0, 0, 0);
        }
    }
#pragma unroll
    for (int nt = 0; nt < 8; ++nt) {
        float bias = b2[(nt << 4) + c16];
        float s1 = 0.f, s2 = 0.f;
#pragma unroll
        for (int i = 0; i < 4; ++i) {
            float v = fmaxf(acc[nt][i] + bias, 0.f);
            int row = (w << 4) + (q << 2) + i;
            int node = base + row;
            if (node < N_NODES) {
                s1 += v;
                s2 += v * v;
            }
            tile[row * 136 + (nt << 4) + c16] = (bf16_t)v;
        }
        s1 += __shfl_down(s1, 32); s2 += __shfl_down(s2, 32);
        s1 += __shfl_down(s1, 16); s2 += __shfl_down(s2, 16);
        if (lane < 16) {
            atomicAdd(&stats[(nt << 4) + lane], s1);
            atomicAdd(&stats[DD + (nt << 4) + lane], s2);
        }
    }
    __syncthreads();

    // ---- Phase 4: quantize rows -> uint8 + scale. 4 threads per row. ----
    {
        int row4 = tid >> 2, t4 = tid & 3;
        int node = base + row4;
        if (node < N_NODES) {
            const bf16_t* tp = tile + row4 * 136 + t4 * 32;
            bf16x8 v0 = *(const bf16x8*)(tp);
            bf16x8 v1 = *(const bf16x8*)(tp + 8);
            bf16x8 v2 = *(const bf16x8*)(tp + 16);
            bf16x8 v3 = *(const bf16x8*)(tp + 24);
            float am = 0.f;
#pragma unroll
            for (int k = 0; k < 8; ++k) {
                am = fmaxf(am, (float)v0[k]);
                am = fmaxf(am, (float)v1[k]);
                am = fmaxf(am, (float)v2[k]);
                am = fmaxf(am, (float)v3[k]);
            }
            am = fmaxf(am, __shfl_xor(am, 1));
            am = fmaxf(am, __shfl_xor(am, 2));
            float inv = am > 0.f ? 255.f / am : 0.f;
            if (t4 == 0) ysc[node] = am * (1.f / 255.f);
            u32 u[8];
            u[0] = pack4u((float)v0[0], (float)v0[1], (float)v0[2], (float)v0[3], inv);
            u[1] = pack4u((float)v0[4], (float)v0[5], (float)v0[6], (float)v0[7], inv);
            u[2] = pack4u((float)v1[0], (float)v1[1], (float)v1[2], (float)v1[3], inv);
            u[3] = pack4u((float)v1[4], (float)v1[5], (float)v1[6], (float)v1[7], inv);
            u[4] = pack4u((float)v2[0], (float)v2[1], (float)v2[2], (float)v2[3], inv);
            u[5] = pack4u((float)v2[4], (float)v2[5], (float)v2[6], (float)v2[7], inv);
            u[6] = pack4u((float)v3[0], (float)v3[1], (float)v3[2], (float)v3[3], inv);
            u[7] = pack4u((float)v3[4], (float)v3[5], (float)v3[6], (float)v3[7], inv);
            uint4* yp = (uint4*)(y8 + (size_t)node * DD + t4 * 32);
            yp[0] = make_uint4(u[0], u[1], u[2], u[3]);
            yp[1] = make_uint4(u[4], u[5], u[6], u[7]);
        }
    }
}

// ---------------- pooling + head ----------------

// dequantizing segmented mean-pool, 2 nodes in flight per block
__global__ __launch_bounds__(256) void k_pool2u(
    const u8* __restrict__ y8, const float* __restrict__ ysc,
    const int* __restrict__ gstart,
    const float* __restrict__ scale, const float* __restrict__ shift,
    float* __restrict__ pooled)
{
    __shared__ float part[128];
    int g = blockIdx.x;
    int t = threadIdx.x;
    int f = t & 127, h = t >> 7;
    int s = gstart[g], e = gstart[g + 1];
    float acc = 0.f;
    for (int n = s + h; n < e; n += 2)
        acc += ysc[n] * (float)y8[(size_t)n * DD + f];
    if (h == 1) part[f] = acc;
    __syncthreads();
    if (h == 0) {
        acc += part[f];
        float cnt = (float)(e - s);
        float v = acc * scale[f] + cnt * shift[f];
        pooled[g * DD + f] = v / fmaxf(cnt, 1.0f);
    }
}

__global__ void k_head(const float* __restrict__ pooled,
                       const float* __restrict__ lin1w, const float* __restrict__ lin1b,
                       const float* __restrict__ lin2w, const float* __restrict__ lin2b,
                       float* __restrict__ out) {
    __shared__ float p[DD];
    __shared__ float h[DD];
    int g = blockIdx.x;
    int t = threadIdx.x;
    p[t] = pooled[g * DD + t];
    __syncthreads();
    float a = lin1b[t];
    for (int k = 0; k < DD; ++k) a += p[k] * lin1w[k * DD + t];
    h[t] = fmaxf(a, 0.f);
    __syncthreads();
    if (t < 10) {
        float o = lin2b[t];
        for (int k = 0; k < DD; ++k) o += h[k] * lin2w[k * 10 + t];
        out[g * 10 + t] = o;
    }
}

// ---------------- launch ----------------

extern "C" void kernel_launch(void* const* d_in, const int* in_sizes, int n_in,
                              void* d_out, int out_size, void* d_ws, size_t ws_size,
                              hipStream_t stream) {
    const float* x      = (const float*)d_in[0];
    const int*   ei     = (const int*)d_in[1];
    const int*   batch  = (const int*)d_in[2];
    const float* W1s    = (const float*)d_in[3];
    const float* b1s    = (const float*)d_in[4];
    const float* W2s    = (const float*)d_in[5];
    const float* b2s    = (const float*)d_in[6];
    const float* gammas = (const float*)d_in[7];
    const float* betas  = (const float*)d_in[8];
    const float* lin1w  = (const float*)d_in[9];
    const float* lin1b  = (const float*)d_in[10];
    const float* lin2w  = (const float*)d_in[11];
    const float* lin2b  = (const float*)d_in[12];
    float* out = (float*)d_out;

    char* p = (char*)d_ws;
    size_t off = 0;
    auto alloc = [&](size_t bytes) -> char* {
        char* r = p + off;
        off += (bytes + 255) & ~(size_t)255;
        return r;
    };
    int*    deg    = (int*)alloc(N_NODES * 4);
    float*  stats  = (float*)alloc(3 * 256 * 4);
    size_t zero_bytes = off;
    int*    poffs  = (int*)alloc((N_NODES + 1) * 4);
    int*    cursor = (int*)alloc(N_NODES * 4);
    int*    bsum   = (int*)alloc(128 * 4);
    int*    bbase  = (int*)alloc(128 * 4);
    int*    csr    = (int*)alloc(((size_t)N_EDGES + 4 * N_NODES + 64) * 4); // pad-4 + slack
    bf16_t* xb     = (bf16_t*)alloc((size_t)N_NODES * DD * 2);  // bf16 input; q8b aliases it after L0
    u8*     q8a    = (u8*)alloc((size_t)N_NODES * DD);
    float*  sca    = (float*)alloc(N_NODES * 4);
    float*  scb    = (float*)alloc(N_NODES * 4);
    bf16_t* wshuf  = (bf16_t*)alloc(6 * 16384 * 2);
    float*  ss     = (float*)alloc(4 * 256 * 4);
    int*    gstart = (int*)alloc((N_GRAPHS + 1) * 4);
    float*  pooled = (float*)alloc(N_GRAPHS * DD * 4);
    if (off > ws_size) return;

    // q8b reuses xb's storage: xb is only read by L0; q8b is written by L1 and
    // read by L2 (stream-ordered on one stream, no overlap). Proven in R10.
    u8* q8b = (u8*)xb;

    const int* srcA = ei;
    const int* dstA = ei + N_EDGES;

    k_zero<<<256, 256, 0, stream>>>((float4*)d_ws, (int)(zero_bytes / 16));
    k_hist<<<1024, 256, 0, stream>>>(dstA, deg);
    k_scan1<<<SCAN_B, 1024, 0, stream>>>(deg, bsum);
    k_scan2<<<1, 128, 0, stream>>>(bsum, bbase, poffs);
    k_scan3<<<SCAN_B, 1024, 0, stream>>>(deg, bbase, poffs, cursor);
    k_fill<<<1024, 256, 0, stream>>>(srcA, dstA, cursor, csr);
    k_pad<<<(N_NODES * 4 + 255) / 256, 256, 0, stream>>>(deg, poffs, csr);
    k_cvt<<<1024, 256, 0, stream>>>(x, xb);
    k_shufw<<<(6 * 16384 + 255) / 256, 256, 0, stream>>>(W1s, W2s, wshuf);
    k_aff_init<<<1, 128, 0, stream>>>(ss);
    k_gbounds<<<(N_NODES + 255) / 256, 256, 0, stream>>>(batch, gstart);

    // L0: xb (bf16) -> q8a. L1: q8a -> q8b (aliases xb). L2: q8b -> q8a.
    k_layer<false><<<NTILES, 256, 0, stream>>>(
        xb, q8a, sca, q8a, sca, poffs, csr, deg,
        ss + 0 * 256, ss + 0 * 256 + 128,
        wshuf + 0 * 16384, wshuf + 1 * 16384,
        b1s + 0 * DD, b2s + 0 * DD, stats + 0 * 256);
    k_aff_update<<<1, 128, 0, stream>>>(stats + 0 * 256, gammas + 0 * DD, betas + 0 * DD,
                                        ss + 1 * 256, ss + 1 * 256 + 128);
    k_layer<true><<<NTILES, 256, 0, stream>>>(
        xb, q8a, sca, q8b, scb, poffs, csr, deg,
        ss + 1 * 256, ss + 1 * 256 + 128,
        wshuf + 2 * 16384, wshuf + 3 * 16384,
        b1s + 1 * DD, b2s + 1 * DD, stats + 1 * 256);
    k_aff_update<<<1, 128, 0, stream>>>(stats + 1 * 256, gammas + 1 * DD, betas + 1 * DD,
                                        ss + 2 * 256, ss + 2 * 256 + 128);
    k_layer<true><<<NTILES, 256, 0, stream>>>(
        xb, q8b, scb, q8a, sca, poffs, csr, deg,
        ss + 2 * 256, ss + 2 * 256 + 128,
        wshuf + 4 * 16384, wshuf + 5 * 16384,
        b1s + 2 * DD, b2s + 2 * DD, stats + 2 * 256);
    k_aff_update<<<1, 128, 0, stream>>>(stats + 2 * 256, gammas + 2 * DD, betas + 2 * DD,
                                        ss + 3 * 256, ss + 3 * 256 + 128);

    k_pool2u<<<N_GRAPHS, 256, 0, stream>>>(q8a, sca, gstart,
                                           ss + 3 * 256, ss + 3 * 256 + 128, pooled);
    k_head<<<N_GRAPHS, 128, 0, stream>>>(pooled, lin1w, lin1b, lin2w, lin2b, out);
}

// Round 2
// 1114.472 us; speedup vs baseline: 1.1008x; 1.1008x over previous
//
#include <hip/hip_runtime.h>
#include <hip/hip_bf16.h>

#define N_NODES 100000
#define N_EDGES 1600000
#define DD 128
#define N_GRAPHS 512
#define BN_EPS 1e-5f
#define NTILES 3125            // ceil(100000/32) -- exact: 3125*32 = 100000
#define SCAN_B 98              // ceil(100000/1024)

typedef unsigned int u32;
typedef unsigned char u8;
typedef __bf16 bf16_t;
typedef __bf16 bf16x2 __attribute__((ext_vector_type(2)));
typedef __bf16 bf16x4 __attribute__((ext_vector_type(4)));
typedef __bf16 bf16x8 __attribute__((ext_vector_type(8)));
typedef float f32x4 __attribute__((ext_vector_type(4)));

__device__ __forceinline__ float bflo2f(u32 u) {
    union { u32 i; float f; } x; x.i = u << 16; return x.f;
}
__device__ __forceinline__ float bfhi2f(u32 u) {
    union { u32 i; float f; } x; x.i = u & 0xffff0000u; return x.f;
}
__device__ __forceinline__ u32 pack4u(float v0, float v1, float v2, float v3, float inv) {
    u32 q0 = (u32)fminf(rintf(v0 * inv), 255.f);
    u32 q1 = (u32)fminf(rintf(v1 * inv), 255.f);
    u32 q2 = (u32)fminf(rintf(v2 * inv), 255.f);
    u32 q3 = (u32)fminf(rintf(v3 * inv), 255.f);
    return q0 | (q1 << 8) | (q2 << 16) | (q3 << 24);
}

// ---------------- utility kernels ----------------

__global__ void k_zero(float4* p, int n) {
    float4 z = make_float4(0.f, 0.f, 0.f, 0.f);
    for (int i = blockIdx.x * blockDim.x + threadIdx.x; i < n; i += gridDim.x * blockDim.x)
        p[i] = z;
}

__global__ void k_hist(const int* __restrict__ dst, int* __restrict__ deg) {
    for (int e = blockIdx.x * blockDim.x + threadIdx.x; e < N_EDGES; e += gridDim.x * blockDim.x)
        atomicAdd(&deg[dst[e]], 1);
}

// hierarchical scan of padded degrees ((deg+3)&~3) -> poffs, cursor
__global__ void k_scan1(const int* __restrict__ deg, int* __restrict__ bsum) {
    __shared__ int sh[1024];
    int b = blockIdx.x, t = threadIdx.x;
    int i = b * 1024 + t;
    int pd = (i < N_NODES) ? ((deg[i] + 3) & ~3) : 0;
    sh[t] = pd;
    __syncthreads();
    for (int s = 512; s > 0; s >>= 1) {
        if (t < s) sh[t] += sh[t + s];
        __syncthreads();
    }
    if (t == 0) bsum[b] = sh[0];
}
__global__ void k_scan2(const int* __restrict__ bsum, int* __restrict__ bbase,
                        int* __restrict__ poffs) {
    __shared__ int sh[128];
    int t = threadIdx.x;
    int v = (t < SCAN_B) ? bsum[t] : 0;
    sh[t] = v;
    __syncthreads();
    for (int d = 1; d < 128; d <<= 1) {
        int o = (t >= d) ? sh[t - d] : 0;
        __syncthreads();
        sh[t] += o;
        __syncthreads();
    }
    if (t < SCAN_B) bbase[t] = sh[t] - v;          // exclusive base per block
    if (t == SCAN_B - 1) poffs[N_NODES] = sh[t];   // total padded edges
}
__global__ void k_scan3(const int* __restrict__ deg, const int* __restrict__ bbase,
                        int* __restrict__ poffs, int* __restrict__ cursor) {
    __shared__ int sh[1024];
    int b = blockIdx.x, t = threadIdx.x;
    int i = b * 1024 + t;
    int pd = (i < N_NODES) ? ((deg[i] + 3) & ~3) : 0;
    sh[t] = pd;
    __syncthreads();
    for (int d = 1; d < 1024; d <<= 1) {
        int o = (t >= d) ? sh[t - d] : 0;
        __syncthreads();
        sh[t] += o;
        __syncthreads();
    }
    if (i < N_NODES) {
        int off = bbase[b] + sh[t] - pd;
        poffs[i] = off; cursor[i] = off;
    }
}

__global__ void k_fill(const int* __restrict__ src, const int* __restrict__ dst,
                       int* __restrict__ cursor, int* __restrict__ csr) {
    for (int e = blockIdx.x * blockDim.x + threadIdx.x; e < N_EDGES; e += gridDim.x * blockDim.x) {
        int pos = atomicAdd(&cursor[dst[e]], 1);
        csr[pos] = src[e];
    }
}

// fill pad slots with the DEST node's own index; gather subtracts the
// overcount via the self-term coefficient (1 - #pads). Self line is L1-hot.
__global__ void k_pad(const int* __restrict__ deg, const int* __restrict__ poffs,
                      int* __restrict__ csr) {
    int t = blockIdx.x * blockDim.x + threadIdx.x;
    if (t >= N_NODES * 4) return;
    int n = t >> 2, j = t & 3;
    int s = poffs[n] + deg[n];
    if (s + j < poffs[n + 1]) csr[s + j] = n;
}

__global__ void k_cvt(const float* __restrict__ x, bf16_t* __restrict__ xb) {
    const int n4 = N_NODES * DD / 4;
    const float4* x4 = (const float4*)x;
    bf16x4* o4 = (bf16x4*)xb;
    for (int i = blockIdx.x * blockDim.x + threadIdx.x; i < n4; i += gridDim.x * blockDim.x) {
        float4 v = x4[i];
        bf16x4 o;
        o.x = (bf16_t)v.x; o.y = (bf16_t)v.y; o.z = (bf16_t)v.z; o.w = (bf16_t)v.w;
        o4[i] = o;
    }
}

// Pre-shuffle the 6 weight matrices into exact MFMA B-fragment order (bf16).
__global__ void k_shufw(const float* __restrict__ W1s, const float* __restrict__ W2s,
                        bf16_t* __restrict__ wshuf) {
    int t = blockIdx.x * blockDim.x + threadIdx.x;
    if (t >= 6 * 16384) return;
    int g  = t >> 14;
    int r  = t & 16383;
    int j  = r & 7;
    int L  = (r >> 3) & 63;
    int nt = (r >> 9) & 7;
    int ks = r >> 12;
    int l  = g >> 1;
    const float* src = (g & 1) ? (W2s + l * 16384) : (W1s + l * 16384);
    int k = ks * 32 + (L >> 4) * 8 + j;
    int n = nt * 16 + (L & 15);
    wshuf[t] = (bf16_t)src[k * DD + n];
}

__global__ void k_aff_init(float* __restrict__ ss) {
    int f = threadIdx.x;
    if (f < DD) { ss[f] = 1.0f; ss[DD + f] = 0.0f; }
}

__global__ void k_aff_update(const float* __restrict__ stats, const float* __restrict__ gamma,
                             const float* __restrict__ beta, float* __restrict__ scale,
                             float* __restrict__ shift) {
    int f = threadIdx.x;
    if (f < DD) {
        float mu  = stats[f] * (1.0f / N_NODES);
        float var = stats[DD + f] * (1.0f / N_NODES) - mu * mu;
        float inv = rsqrtf(var + BN_EPS);
        float sc  = gamma[f] * inv;
        scale[f] = sc;
        shift[f] = beta[f] - mu * sc;
    }
}

__global__ void k_gbounds(const int* __restrict__ batch, int* __restrict__ gstart) {
    int i = blockIdx.x * blockDim.x + threadIdx.x;
    if (i >= N_NODES) return;
    int b = batch[i];
    int bp = (i == 0) ? -1 : batch[i - 1];
    for (int g = bp + 1; g <= b; ++g) gstart[g] = i;
    if (i == N_NODES - 1)
        for (int g = b + 1; g <= N_GRAPHS; ++g) gstart[g] = N_NODES;
}

// ---------------- fused GIN layer ----------------
// R13: 32-node tiles, block = 128 (2 waves). Per-wave workload is identical
// to the proven R11 dual-gather (16 rows/wave, dual-node interleave rp/rp+8,
// ~8-10 loads in flight); only block geometry changed. LDS 8.7 KB/block ->
// HW cap 16 blocks/CU = 32 waves (100%); grid 3125 -> ~12 resident
// blocks/CU vs 6.1 before. R12 established throughput ~ resident waves
// (occupancy 53->47 gave exactly -12% perf); this raises waves ~1.4x.
template<bool IN_U8>
__global__ __launch_bounds__(128, 8) void k_layer(
    const bf16_t* __restrict__ xb,
    const u8* __restrict__ x8, const float* __restrict__ xsc,
    u8* __restrict__ y8, float* __restrict__ ysc,
    const int* __restrict__ poffs, const int* __restrict__ csr,
    const int* __restrict__ deg,
    const float* __restrict__ scale, const float* __restrict__ shift,
    const bf16_t* __restrict__ w1s, const bf16_t* __restrict__ w2s,
    const float* __restrict__ b1, const float* __restrict__ b2,
    float* __restrict__ stats)
{
    __shared__ __align__(16) bf16_t tile[32 * 136];

    const int tid  = threadIdx.x;
    const int w    = tid >> 6;           // 0..1
    const int lane = tid & 63;
    const int base = blockIdx.x * 32;
    const int fb   = lane << 1;          // feature pair
    const int fb2  = fb << 1;            // byte offset in bf16 row

    const float sc0 = scale[fb], sc1 = scale[fb + 1];
    const float sh0 = shift[fb], sh1 = shift[fb + 1];

    // ---- Phase 1: dual-node interleaved gather -> tile (R11 structure) ----
    for (int rp = 0; rp < 8; ++rp) {
        const int rowA = (w << 4) + rp;
        const int rowB = rowA + 8;
        const int nA = base + rowA;
        const int nB = base + rowB;
        const bool vA = (nA < N_NODES);
        const bool vB = (nB < N_NODES);
        float a0A = 0.f, a1A = 0.f, a0B = 0.f, a1B = 0.f;
        int eA = 0, eEA = 0, eB = 0, eEB = 0;
        if (vA) { eA = poffs[nA]; eEA = poffs[nA + 1]; }
        if (vB) { eB = poffs[nB]; eEB = poffs[nB + 1]; }

        // dual master loop: 8 edges (4 per node) in flight
        while ((eA < eEA) & (eB < eEB)) {
            int4 qA = *(const int4*)(csr + eA);
            int4 qB = *(const int4*)(csr + eB);
            if (IN_U8) {
                u32 uA0 = *(const unsigned short*)(x8 + ((size_t)qA.x << 7) + fb);
                u32 uA1 = *(const unsigned short*)(x8 + ((size_t)qA.y << 7) + fb);
                u32 uA2 = *(const unsigned short*)(x8 + ((size_t)qA.z << 7) + fb);
                u32 uA3 = *(const unsigned short*)(x8 + ((size_t)qA.w << 7) + fb);
                u32 uB0 = *(const unsigned short*)(x8 + ((size_t)qB.x << 7) + fb);
                u32 uB1 = *(const unsigned short*)(x8 + ((size_t)qB.y << 7) + fb);
                u32 uB2 = *(const unsigned short*)(x8 + ((size_t)qB.z << 7) + fb);
                u32 uB3 = *(const unsigned short*)(x8 + ((size_t)qB.w << 7) + fb);
                float sA0 = xsc[qA.x], sA1 = xsc[qA.y], sA2 = xsc[qA.z], sA3 = xsc[qA.w];
                float sB0 = xsc[qB.x], sB1 = xsc[qB.y], sB2 = xsc[qB.z], sB3 = xsc[qB.w];
                a0A += sA0 * (float)(uA0 & 0xffu); a1A += sA0 * (float)(uA0 >> 8);
                a0A += sA1 * (float)(uA1 & 0xffu); a1A += sA1 * (float)(uA1 >> 8);
                a0A += sA2 * (float)(uA2 & 0xffu); a1A += sA2 * (float)(uA2 >> 8);
                a0A += sA3 * (float)(uA3 & 0xffu); a1A += sA3 * (float)(uA3 >> 8);
                a0B += sB0 * (float)(uB0 & 0xffu); a1B += sB0 * (float)(uB0 >> 8);
                a0B += sB1 * (float)(uB1 & 0xffu); a1B += sB1 * (float)(uB1 >> 8);
                a0B += sB2 * (float)(uB2 & 0xffu); a1B += sB2 * (float)(uB2 >> 8);
                a0B += sB3 * (float)(uB3 & 0xffu); a1B += sB3 * (float)(uB3 >> 8);
            } else {
                u32 vA0 = *(const u32*)((const u8*)xb + ((size_t)qA.x << 8) + fb2);
                u32 vA1 = *(const u32*)((const u8*)xb + ((size_t)qA.y << 8) + fb2);
                u32 vA2 = *(const u32*)((const u8*)xb + ((size_t)qA.z << 8) + fb2);
                u32 vA3 = *(const u32*)((const u8*)xb + ((size_t)qA.w << 8) + fb2);
                u32 vB0 = *(const u32*)((const u8*)xb + ((size_t)qB.x << 8) + fb2);
                u32 vB1 = *(const u32*)((const u8*)xb + ((size_t)qB.y << 8) + fb2);
                u32 vB2 = *(const u32*)((const u8*)xb + ((size_t)qB.z << 8) + fb2);
                u32 vB3 = *(const u32*)((const u8*)xb + ((size_t)qB.w << 8) + fb2);
                a0A += bflo2f(vA0) + bflo2f(vA1) + bflo2f(vA2) + bflo2f(vA3);
                a1A += bfhi2f(vA0) + bfhi2f(vA1) + bfhi2f(vA2) + bfhi2f(vA3);
                a0B += bflo2f(vB0) + bflo2f(vB1) + bflo2f(vB2) + bflo2f(vB3);
                a1B += bfhi2f(vB0) + bfhi2f(vB1) + bfhi2f(vB2) + bfhi2f(vB3);
            }
            eA += 4; eB += 4;
        }
        // drain A
        while (eA < eEA) {
            int4 q = *(const int4*)(csr + eA);
            if (IN_U8) {
                u32 u0 = *(const unsigned short*)(x8 + ((size_t)q.x << 7) + fb);
                u32 u1 = *(const unsigned short*)(x8 + ((size_t)q.y << 7) + fb);
                u32 u2 = *(const unsigned short*)(x8 + ((size_t)q.z << 7) + fb);
                u32 u3 = *(const unsigned short*)(x8 + ((size_t)q.w << 7) + fb);
                float s0 = xsc[q.x], s1 = xsc[q.y], s2 = xsc[q.z], s3 = xsc[q.w];
                a0A += s0 * (float)(u0 & 0xffu); a1A += s0 * (float)(u0 >> 8);
                a0A += s1 * (float)(u1 & 0xffu); a1A += s1 * (float)(u1 >> 8);
                a0A += s2 * (float)(u2 & 0xffu); a1A += s2 * (float)(u2 >> 8);
                a0A += s3 * (float)(u3 & 0xffu); a1A += s3 * (float)(u3 >> 8);
            } else {
                u32 v0 = *(const u32*)((const u8*)xb + ((size_t)q.x << 8) + fb2);
                u32 v1 = *(const u32*)((const u8*)xb + ((size_t)q.y << 8) + fb2);
                u32 v2 = *(const u32*)((const u8*)xb + ((size_t)q.z << 8) + fb2);
                u32 v3 = *(const u32*)((const u8*)xb + ((size_t)q.w << 8) + fb2);
                a0A += bflo2f(v0) + bflo2f(v1) + bflo2f(v2) + bflo2f(v3);
                a1A += bfhi2f(v0) + bfhi2f(v1) + bfhi2f(v2) + bfhi2f(v3);
            }
            eA += 4;
        }
        // drain B
        while (eB < eEB) {
            int4 q = *(const int4*)(csr + eB);
            if (IN_U8) {
                u32 u0 = *(const unsigned short*)(x8 + ((size_t)q.x << 7) + fb);
                u32 u1 = *(const unsigned short*)(x8 + ((size_t)q.y << 7) + fb);
                u32 u2 = *(const unsigned short*)(x8 + ((size_t)q.z << 7) + fb);
                u32 u3 = *(const unsigned short*)(x8 + ((size_t)q.w << 7) + fb);
                float s0 = xsc[q.x], s1 = xsc[q.y], s2 = xsc[q.z], s3 = xsc[q.w];
                a0B += s0 * (float)(u0 & 0xffu); a1B += s0 * (float)(u0 >> 8);
                a0B += s1 * (float)(u1 & 0xffu); a1B += s1 * (float)(u1 >> 8);
                a0B += s2 * (float)(u2 & 0xffu); a1B += s2 * (float)(u2 >> 8);
                a0B += s3 * (float)(u3 & 0xffu); a1B += s3 * (float)(u3 >> 8);
            } else {
                u32 v0 = *(const u32*)((const u8*)xb + ((size_t)q.x << 8) + fb2);
                u32 v1 = *(const u32*)((const u8*)xb + ((size_t)q.y << 8) + fb2);
                u32 v2 = *(const u32*)((const u8*)xb + ((size_t)q.z << 8) + fb2);
                u32 v3 = *(const u32*)((const u8*)xb + ((size_t)q.w << 8) + fb2);
                a0B += bflo2f(v0) + bflo2f(v1) + bflo2f(v2) + bflo2f(v3);
                a1B += bfhi2f(v0) + bfhi2f(v1) + bfhi2f(v2) + bfhi2f(v3);
            }
            eB += 4;
        }
        // finalize A
        if (vA) {
            int dg = deg[nA];
            float selfco = 1.f - (float)(((dg + 3) & ~3) - dg);
            if (IN_U8) {
                u32 sv = *(const unsigned short*)(x8 + ((size_t)nA << 7) + fb);
                float ssv = selfco * xsc[nA];
                a0A += ssv * (float)(sv & 0xffu); a1A += ssv * (float)(sv >> 8);
            } else {
                u32 sv = *(const u32*)((const u8*)xb + ((size_t)nA << 8) + fb2);
                a0A += selfco * bflo2f(sv); a1A += selfco * bfhi2f(sv);
            }
            float cnt = (float)(dg + 1);
            bf16x2 pk;
            pk.x = (bf16_t)(a0A * sc0 + cnt * sh0);
            pk.y = (bf16_t)(a1A * sc1 + cnt * sh1);
            *(bf16x2*)(&tile[rowA * 136 + fb]) = pk;
        } else {
            bf16x2 z; z.x = (bf16_t)0.f; z.y = (bf16_t)0.f;
            *(bf16x2*)(&tile[rowA * 136 + fb]) = z;
        }
        // finalize B
        if (vB) {
            int dg = deg[nB];
            float selfco = 1.f - (float)(((dg + 3) & ~3) - dg);
            if (IN_U8) {
                u32 sv = *(const unsigned short*)(x8 + ((size_t)nB << 7) + fb);
                float ssv = selfco * xsc[nB];
                a0B += ssv * (float)(sv & 0xffu); a1B += ssv * (float)(sv >> 8);
            } else {
                u32 sv = *(const u32*)((const u8*)xb + ((size_t)nB << 8) + fb2);
                a0B += selfco * bflo2f(sv); a1B += selfco * bfhi2f(sv);
            }
            float cnt = (float)(dg + 1);
            bf16x2 pk;
            pk.x = (bf16_t)(a0B * sc0 + cnt * sh0);
            pk.y = (bf16_t)(a1B * sc1 + cnt * sh1);
            *(bf16x2*)(&tile[rowB * 136 + fb]) = pk;
        } else {
            bf16x2 z; z.x = (bf16_t)0.f; z.y = (bf16_t)0.f;
            *(bf16x2*)(&tile[rowB * 136 + fb]) = z;
        }
    }
    __syncthreads();

    // ---- Phase 2: GEMM1 + bias + relu -> tile (reused) ----
    const int q = lane >> 4;
    const int c16 = lane & 15;
    const int arow = (w << 4) + c16;

    bf16x8 afr[4];
#pragma unroll
    for (int ks = 0; ks < 4; ++ks)
        afr[ks] = *(const bf16x8*)(&tile[arow * 136 + ks * 32 + q * 8]);
    __syncthreads();

    f32x4 acc[8];
#pragma unroll
    for (int nt = 0; nt < 8; ++nt) acc[nt] = (f32x4){0.f, 0.f, 0.f, 0.f};
#pragma unroll
    for (int ks = 0; ks < 4; ++ks) {
#pragma unroll
        for (int nt = 0; nt < 8; ++nt) {
            bf16x8 bfr = *(const bf16x8*)(w1s + (((ks << 3) + nt) * 64 + lane) * 8);
            acc[nt] = __builtin_amdgcn_mfma_f32_16x16x32_bf16(afr[ks], bfr, acc[nt], 0, 0, 0);
        }
    }
#pragma unroll
    for (int nt = 0; nt < 8; ++nt) {
        float bias = b1[(nt << 4) + c16];
#pragma unroll
        for (int i = 0; i < 4; ++i) {
            float v = fmaxf(acc[nt][i] + bias, 0.f);
            int row = (w << 4) + (q << 2) + i;
            tile[row * 136 + (nt << 4) + c16] = (bf16_t)v;
        }
    }
    __syncthreads();

    // ---- Phase 3: GEMM2 + bias + relu + BN stats -> tile ----
    bf16x8 afr2[4];
#pragma unroll
    for (int ks = 0; ks < 4; ++ks)
        afr2[ks] = *(const bf16x8*)(&tile[arow * 136 + ks * 32 + q * 8]);
    __syncthreads(); // tile overwritten below

#pragma unroll
    for (int nt = 0; nt < 8; ++nt) acc[nt] = (f32x4){0.f, 0.f, 0.f, 0.f};
#pragma unroll
    for (int ks = 0; ks < 4; ++ks) {
#pragma unroll
        for (int nt = 0; nt < 8; ++nt) {
            bf16x8 bfr = *(const bf16x8*)(w2s + (((ks << 3) + nt) * 64 + lane) * 8);
            acc[nt] = __builtin_amdgcn_mfma_f32_16x16x32_bf16(afr2[ks], bfr, acc[nt], 0, 0, 0);
        }
    }
#pragma unroll
    for (int nt = 0; nt < 8; ++nt) {
        float bias = b2[(nt << 4) + c16];
        float s1 = 0.f, s2 = 0.f;
#pragma unroll
        for (int i = 0; i < 4; ++i) {
            float v = fmaxf(acc[nt][i] + bias, 0.f);
            int row = (w << 4) + (q << 2) + i;
            int node = base + row;
            if (node < N_NODES) {
                s1 += v;
                s2 += v * v;
            }
            tile[row * 136 + (nt << 4) + c16] = (bf16_t)v;
        }
        s1 += __shfl_down(s1, 32); s2 += __shfl_down(s2, 32);
        s1 += __shfl_down(s1, 16); s2 += __shfl_down(s2, 16);
        if (lane < 16) {
            atomicAdd(&stats[(nt << 4) + lane], s1);
            atomicAdd(&stats[DD + (nt << 4) + lane], s2);
        }
    }
    __syncthreads();

    // ---- Phase 4: quantize rows -> uint8 + scale. 4 threads per row. ----
    {
        int row4 = tid >> 2, t4 = tid & 3;   // rows 0..31
        int node = base + row4;
        if (node < N_NODES) {
            const bf16_t* tp = tile + row4 * 136 + t4 * 32;
            bf16x8 v0 = *(const bf16x8*)(tp);
            bf16x8 v1 = *(const bf16x8*)(tp + 8);
            bf16x8 v2 = *(const bf16x8*)(tp + 16);
            bf16x8 v3 = *(const bf16x8*)(tp + 24);
            float am = 0.f;
#pragma unroll
            for (int k = 0; k < 8; ++k) {
                am = fmaxf(am, (float)v0[k]);
                am = fmaxf(am, (float)v1[k]);
                am = fmaxf(am, (float)v2[k]);
                am = fmaxf(am, (float)v3[k]);
            }
            am = fmaxf(am, __shfl_xor(am, 1));
            am = fmaxf(am, __shfl_xor(am, 2));
            float inv = am > 0.f ? 255.f / am : 0.f;
            if (t4 == 0) ysc[node] = am * (1.f / 255.f);
            u32 u[8];
            u[0] = pack4u((float)v0[0], (float)v0[1], (float)v0[2], (float)v0[3], inv);
            u[1] = pack4u((float)v0[4], (float)v0[5], (float)v0[6], (float)v0[7], inv);
            u[2] = pack4u((float)v1[0], (float)v1[1], (float)v1[2], (float)v1[3], inv);
            u[3] = pack4u((float)v1[4], (float)v1[5], (float)v1[6], (float)v1[7], inv);
            u[4] = pack4u((float)v2[0], (float)v2[1], (float)v2[2], (float)v2[3], inv);
            u[5] = pack4u((float)v2[4], (float)v2[5], (float)v2[6], (float)v2[7], inv);
            u[6] = pack4u((float)v3[0], (float)v3[1], (float)v3[2], (float)v3[3], inv);
            u[7] = pack4u((float)v3[4], (float)v3[5], (float)v3[6], (float)v3[7], inv);
            uint4* yp = (uint4*)(y8 + (size_t)node * DD + t4 * 32);
            yp[0] = make_uint4(u[0], u[1], u[2], u[3]);
            yp[1] = make_uint4(u[4], u[5], u[6], u[7]);
        }
    }
}

// ---------------- pooling + head ----------------

// dequantizing segmented mean-pool, 2 nodes in flight per block
__global__ __launch_bounds__(256) void k_pool2u(
    const u8* __restrict__ y8, const float* __restrict__ ysc,
    const int* __restrict__ gstart,
    const float* __restrict__ scale, const float* __restrict__ shift,
    float* __restrict__ pooled)
{
    __shared__ float part[128];
    int g = blockIdx.x;
    int t = threadIdx.x;
    int f = t & 127, h = t >> 7;
    int s = gstart[g], e = gstart[g + 1];
    float acc = 0.f;
    for (int n = s + h; n < e; n += 2)
        acc += ysc[n] * (float)y8[(size_t)n * DD + f];
    if (h == 1) part[f] = acc;
    __syncthreads();
    if (h == 0) {
        acc += part[f];
        float cnt = (float)(e - s);
        float v = acc * scale[f] + cnt * shift[f];
        pooled[g * DD + f] = v / fmaxf(cnt, 1.0f);
    }
}

__global__ void k_head(const float* __restrict__ pooled,
                       const float* __restrict__ lin1w, const float* __restrict__ lin1b,
                       const float* __restrict__ lin2w, const float* __restrict__ lin2b,
                       float* __restrict__ out) {
    __shared__ float p[DD];
    __shared__ float h[DD];
    int g = blockIdx.x;
    int t = threadIdx.x;
    p[t] = pooled[g * DD + t];
    __syncthreads();
    float a = lin1b[t];
    for (int k = 0; k < DD; ++k) a += p[k] * lin1w[k * DD + t];
    h[t] = fmaxf(a, 0.f);
    __syncthreads();
    if (t < 10) {
        float o = lin2b[t];
        for (int k = 0; k < DD; ++k) o += h[k] * lin2w[k * 10 + t];
        out[g * 10 + t] = o;
    }
}

// ---------------- launch ----------------

extern "C" void kernel_launch(void* const* d_in, const int* in_sizes, int n_in,
                              void* d_out, int out_size, void* d_ws, size_t ws_size,
                              hipStream_t stream) {
    const float* x      = (const float*)d_in[0];
    const int*   ei     = (const int*)d_in[1];
    const int*   batch  = (const int*)d_in[2];
    const float* W1s    = (const float*)d_in[3];
    const float* b1s    = (const float*)d_in[4];
    const float* W2s    = (const float*)d_in[5];
    const float* b2s    = (const float*)d_in[6];
    const float* gammas = (const float*)d_in[7];
    const float* betas  = (const float*)d_in[8];
    const float* lin1w  = (const float*)d_in[9];
    const float* lin1b  = (const float*)d_in[10];
    const float* lin2w  = (const float*)d_in[11];
    const float* lin2b  = (const float*)d_in[12];
    float* out = (float*)d_out;

    char* p = (char*)d_ws;
    size_t off = 0;
    auto alloc = [&](size_t bytes) -> char* {
        char* r = p + off;
        off += (bytes + 255) & ~(size_t)255;
        return r;
    };
    int*    deg    = (int*)alloc(N_NODES * 4);
    float*  stats  = (float*)alloc(3 * 256 * 4);
    size_t zero_bytes = off;
    int*    poffs  = (int*)alloc((N_NODES + 1) * 4);
    int*    cursor = (int*)alloc(N_NODES * 4);
    int*    bsum   = (int*)alloc(128 * 4);
    int*    bbase  = (int*)alloc(128 * 4);
    int*    csr    = (int*)alloc(((size_t)N_EDGES + 4 * N_NODES + 64) * 4); // pad-4 + slack
    bf16_t* xb     = (bf16_t*)alloc((size_t)N_NODES * DD * 2);  // bf16 input; q8b aliases it after L0
    u8*     q8a    = (u8*)alloc((size_t)N_NODES * DD);
    float*  sca    = (float*)alloc(N_NODES * 4);
    float*  scb    = (float*)alloc(N_NODES * 4);
    bf16_t* wshuf  = (bf16_t*)alloc(6 * 16384 * 2);
    float*  ss     = (float*)alloc(4 * 256 * 4);
    int*    gstart = (int*)alloc((N_GRAPHS + 1) * 4);
    float*  pooled = (float*)alloc(N_GRAPHS * DD * 4);
    if (off > ws_size) return;

    // q8b reuses xb's storage: xb is only read by L0; q8b is written by L1 and
    // read by L2 (stream-ordered on one stream, no overlap). Proven in R10.
    u8* q8b = (u8*)xb;

    const int* srcA = ei;
    const int* dstA = ei + N_EDGES;

    k_zero<<<256, 256, 0, stream>>>((float4*)d_ws, (int)(zero_bytes / 16));
    k_hist<<<1024, 256, 0, stream>>>(dstA, deg);
    k_scan1<<<SCAN_B, 1024, 0, stream>>>(deg, bsum);
    k_scan2<<<1, 128, 0, stream>>>(bsum, bbase, poffs);
    k_scan3<<<SCAN_B, 1024, 0, stream>>>(deg, bbase, poffs, cursor);
    k_fill<<<1024, 256, 0, stream>>>(srcA, dstA, cursor, csr);
    k_pad<<<(N_NODES * 4 + 255) / 256, 256, 0, stream>>>(deg, poffs, csr);
    k_cvt<<<1024, 256, 0, stream>>>(x, xb);
    k_shufw<<<(6 * 16384 + 255) / 256, 256, 0, stream>>>(W1s, W2s, wshuf);
    k_aff_init<<<1, 128, 0, stream>>>(ss);
    k_gbounds<<<(N_NODES + 255) / 256, 256, 0, stream>>>(batch, gstart);

    // L0: xb (bf16) -> q8a. L1: q8a -> q8b (aliases xb). L2: q8b -> q8a.
    k_layer<false><<<NTILES, 128, 0, stream>>>(
        xb, q8a, sca, q8a, sca, poffs, csr, deg,
        ss + 0 * 256, ss + 0 * 256 + 128,
        wshuf + 0 * 16384, wshuf + 1 * 16384,
        b1s + 0 * DD, b2s + 0 * DD, stats + 0 * 256);
    k_aff_update<<<1, 128, 0, stream>>>(stats + 0 * 256, gammas + 0 * DD, betas + 0 * DD,
                                        ss + 1 * 256, ss + 1 * 256 + 128);
    k_layer<true><<<NTILES, 128, 0, stream>>>(
        xb, q8a, sca, q8b, scb, poffs, csr, deg,
        ss + 1 * 256, ss + 1 * 256 + 128,
        wshuf + 2 * 16384, wshuf + 3 * 16384,
        b1s + 1 * DD, b2s + 1 * DD, stats + 1 * 256);
    k_aff_update<<<1, 128, 0, stream>>>(stats + 1 * 256, gammas + 1 * DD, betas + 1 * DD,
                                        ss + 2 * 256, ss + 2 * 256 + 128);
    k_layer<true><<<NTILES, 128, 0, stream>>>(
        xb, q8b, scb, q8a, sca, poffs, csr, deg,
        ss + 2 * 256, ss + 2 * 256 + 128,
        wshuf + 4 * 16384, wshuf + 5 * 16384,
        b1s + 2 * DD, b2s + 2 * DD, stats + 2 * 256);
    k_aff_update<<<1, 128, 0, stream>>>(stats + 2 * 256, gammas + 2 * DD, betas + 2 * DD,
                                        ss + 3 * 256, ss + 3 * 256 + 128);

    k_pool2u<<<N_GRAPHS, 256, 0, stream>>>(q8a, sca, gstart,
                                           ss + 3 * 256, ss + 3 * 256 + 128, pooled);
    k_head<<<N_GRAPHS, 128, 0, stream>>>(pooled, lin1w, lin1b, lin2w, lin2b, out);
}

// Round 3
// 1112.000 us; speedup vs baseline: 1.1032x; 1.0022x over previous
//
#include <hip/hip_runtime.h>
#include <hip/hip_bf16.h>

#define N_NODES 100000
#define N_EDGES 1600000
#define DD 128
#define N_GRAPHS 512
#define BN_EPS 1e-5f
#define NTILES 3125            // 3125*32 == 100000 exactly: no partial tiles
#define SCAN_B 98              // ceil(100000/1024)

typedef unsigned int u32;
typedef unsigned char u8;
typedef __bf16 bf16_t;
typedef __bf16 bf16x2 __attribute__((ext_vector_type(2)));
typedef __bf16 bf16x4 __attribute__((ext_vector_type(4)));
typedef __bf16 bf16x8 __attribute__((ext_vector_type(8)));
typedef float f32x4 __attribute__((ext_vector_type(4)));

__device__ __forceinline__ float bflo2f(u32 u) {
    union { u32 i; float f; } x; x.i = u << 16; return x.f;
}
__device__ __forceinline__ float bfhi2f(u32 u) {
    union { u32 i; float f; } x; x.i = u & 0xffff0000u; return x.f;
}
__device__ __forceinline__ u32 pack4u(float v0, float v1, float v2, float v3, float inv) {
    u32 q0 = (u32)fminf(rintf(v0 * inv), 255.f);
    u32 q1 = (u32)fminf(rintf(v1 * inv), 255.f);
    u32 q2 = (u32)fminf(rintf(v2 * inv), 255.f);
    u32 q3 = (u32)fminf(rintf(v3 * inv), 255.f);
    return q0 | (q1 << 8) | (q2 << 16) | (q3 << 24);
}

// ---------------- utility kernels ----------------

__global__ void k_zero(float4* p, int n) {
    float4 z = make_float4(0.f, 0.f, 0.f, 0.f);
    for (int i = blockIdx.x * blockDim.x + threadIdx.x; i < n; i += gridDim.x * blockDim.x)
        p[i] = z;
}

__global__ void k_hist(const int* __restrict__ dst, int* __restrict__ deg) {
    for (int e = blockIdx.x * blockDim.x + threadIdx.x; e < N_EDGES; e += gridDim.x * blockDim.x)
        atomicAdd(&deg[dst[e]], 1);
}

// hierarchical scan of padded degrees ((deg+3)&~3) -> poffs, cursor
__global__ void k_scan1(const int* __restrict__ deg, int* __restrict__ bsum) {
    __shared__ int sh[1024];
    int b = blockIdx.x, t = threadIdx.x;
    int i = b * 1024 + t;
    int pd = (i < N_NODES) ? ((deg[i] + 3) & ~3) : 0;
    sh[t] = pd;
    __syncthreads();
    for (int s = 512; s > 0; s >>= 1) {
        if (t < s) sh[t] += sh[t + s];
        __syncthreads();
    }
    if (t == 0) bsum[b] = sh[0];
}
__global__ void k_scan2(const int* __restrict__ bsum, int* __restrict__ bbase,
                        int* __restrict__ poffs) {
    __shared__ int sh[128];
    int t = threadIdx.x;
    int v = (t < SCAN_B) ? bsum[t] : 0;
    sh[t] = v;
    __syncthreads();
    for (int d = 1; d < 128; d <<= 1) {
        int o = (t >= d) ? sh[t - d] : 0;
        __syncthreads();
        sh[t] += o;
        __syncthreads();
    }
    if (t < SCAN_B) bbase[t] = sh[t] - v;          // exclusive base per block
    if (t == SCAN_B - 1) poffs[N_NODES] = sh[t];   // total padded edges
}
__global__ void k_scan3(const int* __restrict__ deg, const int* __restrict__ bbase,
                        int* __restrict__ poffs, int* __restrict__ cursor) {
    __shared__ int sh[1024];
    int b = blockIdx.x, t = threadIdx.x;
    int i = b * 1024 + t;
    int pd = (i < N_NODES) ? ((deg[i] + 3) & ~3) : 0;
    sh[t] = pd;
    __syncthreads();
    for (int d = 1; d < 1024; d <<= 1) {
        int o = (t >= d) ? sh[t - d] : 0;
        __syncthreads();
        sh[t] += o;
        __syncthreads();
    }
    if (i < N_NODES) {
        int off = bbase[b] + sh[t] - pd;
        poffs[i] = off; cursor[i] = off;
    }
}

__global__ void k_fill(const int* __restrict__ src, const int* __restrict__ dst,
                       int* __restrict__ cursor, int* __restrict__ csr) {
    for (int e = blockIdx.x * blockDim.x + threadIdx.x; e < N_EDGES; e += gridDim.x * blockDim.x) {
        int pos = atomicAdd(&cursor[dst[e]], 1);
        csr[pos] = src[e];
    }
}

// fill pad slots with the DEST node's own index; gather subtracts the
// overcount via the self-term coefficient (1 - #pads). Self line is L1-hot.
__global__ void k_pad(const int* __restrict__ deg, const int* __restrict__ poffs,
                      int* __restrict__ csr) {
    int t = blockIdx.x * blockDim.x + threadIdx.x;
    if (t >= N_NODES * 4) return;
    int n = t >> 2, j = t & 3;
    int s = poffs[n] + deg[n];
    if (s + j < poffs[n + 1]) csr[s + j] = n;
}

__global__ void k_cvt(const float* __restrict__ x, bf16_t* __restrict__ xb) {
    const int n4 = N_NODES * DD / 4;
    const float4* x4 = (const float4*)x;
    bf16x4* o4 = (bf16x4*)xb;
    for (int i = blockIdx.x * blockDim.x + threadIdx.x; i < n4; i += gridDim.x * blockDim.x) {
        float4 v = x4[i];
        bf16x4 o;
        o.x = (bf16_t)v.x; o.y = (bf16_t)v.y; o.z = (bf16_t)v.z; o.w = (bf16_t)v.w;
        o4[i] = o;
    }
}

// Pre-shuffle the 6 weight matrices into exact MFMA B-fragment order (bf16).
__global__ void k_shufw(const float* __restrict__ W1s, const float* __restrict__ W2s,
                        bf16_t* __restrict__ wshuf) {
    int t = blockIdx.x * blockDim.x + threadIdx.x;
    if (t >= 6 * 16384) return;
    int g  = t >> 14;
    int r  = t & 16383;
    int j  = r & 7;
    int L  = (r >> 3) & 63;
    int nt = (r >> 9) & 7;
    int ks = r >> 12;
    int l  = g >> 1;
    const float* src = (g & 1) ? (W2s + l * 16384) : (W1s + l * 16384);
    int k = ks * 32 + (L >> 4) * 8 + j;
    int n = nt * 16 + (L & 15);
    wshuf[t] = (bf16_t)src[k * DD + n];
}

__global__ void k_aff_init(float* __restrict__ ss) {
    int f = threadIdx.x;
    if (f < DD) { ss[f] = 1.0f; ss[DD + f] = 0.0f; }
}

__global__ void k_aff_update(const float* __restrict__ stats, const float* __restrict__ gamma,
                             const float* __restrict__ beta, float* __restrict__ scale,
                             float* __restrict__ shift) {
    int f = threadIdx.x;
    if (f < DD) {
        float mu  = stats[f] * (1.0f / N_NODES);
        float var = stats[DD + f] * (1.0f / N_NODES) - mu * mu;
        float inv = rsqrtf(var + BN_EPS);
        float sc  = gamma[f] * inv;
        scale[f] = sc;
        shift[f] = beta[f] - mu * sc;
    }
}

__global__ void k_gbounds(const int* __restrict__ batch, int* __restrict__ gstart) {
    int i = blockIdx.x * blockDim.x + threadIdx.x;
    if (i >= N_NODES) return;
    int b = batch[i];
    int bp = (i == 0) ? -1 : batch[i - 1];
    for (int g = bp + 1; g <= b; ++g) gstart[g] = i;
    if (i == N_NODES - 1)
        for (int g = b + 1; g <= N_GRAPHS; ++g) gstart[g] = N_NODES;
}

// ---------------- gather helpers (quarter-split: 4 edges / instruction) ----
// lane = (q4, l16); lane covers features l16*8 .. l16*8+7 of edge csr[e+q4].
// bf16 row: dwordx4 (16B) per lane; u8 row: dwordx2 (8B) per lane.

template<bool IN_U8>
__device__ __forceinline__ void load_row8(
    const u8* __restrict__ xg, int r, int l16, float (&v)[8])
{
    if (IN_U8) {
        uint2 d = *(const uint2*)(xg + ((size_t)r << 7) + (l16 << 3));
        v[0] = (float)(d.x & 0xffu);
        v[1] = (float)((d.x >> 8) & 0xffu);
        v[2] = (float)((d.x >> 16) & 0xffu);
        v[3] = (float)(d.x >> 24);
        v[4] = (float)(d.y & 0xffu);
        v[5] = (float)((d.y >> 8) & 0xffu);
        v[6] = (float)((d.y >> 16) & 0xffu);
        v[7] = (float)(d.y >> 24);
    } else {
        uint4 d = *(const uint4*)(xg + ((size_t)r << 8) + (l16 << 4));
        v[0] = bflo2f(d.x); v[1] = bfhi2f(d.x);
        v[2] = bflo2f(d.y); v[3] = bfhi2f(d.y);
        v[4] = bflo2f(d.z); v[5] = bfhi2f(d.z);
        v[6] = bflo2f(d.w); v[7] = bfhi2f(d.w);
    }
}

template<bool IN_U8>
__device__ __forceinline__ void acc_group(
    const u8* __restrict__ xg, const float* __restrict__ xsc,
    int r, int l16, float (&a)[8])
{
    float v[8];
    load_row8<IN_U8>(xg, r, l16, v);
    if (IN_U8) {
        float s = xsc[r];
#pragma unroll
        for (int j = 0; j < 8; ++j) a[j] += s * v[j];
    } else {
#pragma unroll
        for (int j = 0; j < 8; ++j) a[j] += v[j];
    }
}

// ---------------- fused GIN layer ----------------
// R14: 32-node tiles, block = 128 (2 waves), dual-node interleave kept from
// R11, but the gather is quarter-split: one row-load instruction covers 4
// edges (16 lanes per row, 8 features per lane). Per dual-node iteration:
// 6 load instructions (u8) / 4 (bf16) vs 18/10 before, at identical sector
// traffic and identical edges-in-flight. Rationale: R13 showed u8 and bf16
// layers take IDENTICAL time despite 2x byte difference -> the gather is
// bound by memory-instruction count, not bytes/waves/unroll (R12/R13 nulls).
// csr group index is a per-lane dword load (csr[e+q4]) and is software-
// pipelined so each iteration carries one row latency only.
template<bool IN_U8>
__global__ __launch_bounds__(128, 8) void k_layer(
    const bf16_t* __restrict__ xb,
    const u8* __restrict__ x8, const float* __restrict__ xsc,
    u8* __restrict__ y8, float* __restrict__ ysc,
    const int* __restrict__ poffs, const int* __restrict__ csr,
    const int* __restrict__ deg,
    const float* __restrict__ scale, const float* __restrict__ shift,
    const bf16_t* __restrict__ w1s, const bf16_t* __restrict__ w2s,
    const float* __restrict__ b1, const float* __restrict__ b2,
    float* __restrict__ stats)
{
    __shared__ __align__(16) bf16_t tile[32 * 136];

    const int tid  = threadIdx.x;
    const int w    = tid >> 6;           // 0..1
    const int lane = tid & 63;
    const int base = blockIdx.x * 32;
    const int q4   = lane >> 4;          // quarter: which edge of the group
    const int l16  = lane & 15;          // feature octet within the row

    const u8* xg = IN_U8 ? x8 : (const u8*)xb;

    // ---- Phase 1: dual-node quarter-split gather -> tile ----
    for (int rp = 0; rp < 8; ++rp) {
        const int rowA = (w << 4) + rp;  // rows 0..7 / 16..23
        const int rowB = rowA + 8;       // rows 8..15 / 24..31
        const int nA = base + rowA;
        const int nB = base + rowB;      // always < N_NODES (exact tiling)

        float aA[8] = {0.f, 0.f, 0.f, 0.f, 0.f, 0.f, 0.f, 0.f};
        float aB[8] = {0.f, 0.f, 0.f, 0.f, 0.f, 0.f, 0.f, 0.f};

        int eA = poffs[nA], eEA = poffs[nA + 1];
        int eB = poffs[nB], eEB = poffs[nB + 1];

        // current group's edge for this quarter (slack-safe over-read)
        int rA = csr[eA + q4];
        int rB = csr[eB + q4];

        // dual master loop: 8 edges in flight via 2 row-load instructions
        while ((eA < eEA) & (eB < eEB)) {
            int rA2 = csr[eA + 4 + q4];   // prefetch next groups (csr has slack)
            int rB2 = csr[eB + 4 + q4];
            acc_group<IN_U8>(xg, xsc, rA, l16, aA);
            acc_group<IN_U8>(xg, xsc, rB, l16, aB);
            rA = rA2; rB = rB2; eA += 4; eB += 4;
        }
        // drains (rA/rB already hold csr[e+q4] for the current position)
        while (eA < eEA) {
            acc_group<IN_U8>(xg, xsc, rA, l16, aA);
            eA += 4; rA = csr[eA + q4];
        }
        while (eB < eEB) {
            acc_group<IN_U8>(xg, xsc, rB, l16, aB);
            eB += 4; rB = csr[eB + q4];
        }

        // self terms: one load instruction covers both selves (quarters 0/1)
        const int dgA = deg[nA], dgB = deg[nB];
        const float scoA = 1.f - (float)(((dgA + 3) & ~3) - dgA);
        const float scoB = 1.f - (float)(((dgB + 3) & ~3) - dgB);
        {
            int rs = (q4 & 1) ? nB : nA;
            float v[8];
            load_row8<IN_U8>(xg, rs, l16, v);
            float coA = (q4 == 0) ? scoA : 0.f;
            float coB = (q4 == 1) ? scoB : 0.f;
            if (IN_U8) {
                float s = xsc[rs];
                coA *= s; coB *= s;
            }
#pragma unroll
            for (int j = 0; j < 8; ++j) {
                aA[j] += coA * v[j];
                aB[j] += coB * v[j];
            }
        }

        // combine quarters: lanes l, l^16, l^32, l^48 hold same features
#pragma unroll
        for (int j = 0; j < 8; ++j) {
            aA[j] += __shfl_xor(aA[j], 16);
            aA[j] += __shfl_xor(aA[j], 32);
            aB[j] += __shfl_xor(aB[j], 16);
            aB[j] += __shfl_xor(aB[j], 32);
        }

        // BN-affine + write: lanes 0-15 write row A, lanes 16-31 write row B
        if (q4 < 2) {
            const bool selA = (q4 == 0);
            const float4 s0 = *(const float4*)(scale + (l16 << 3));
            const float4 s1 = *(const float4*)(scale + (l16 << 3) + 4);
            const float4 t0 = *(const float4*)(shift + (l16 << 3));
            const float4 t1 = *(const float4*)(shift + (l16 << 3) + 4);
            const float sarr[8] = {s0.x, s0.y, s0.z, s0.w, s1.x, s1.y, s1.z, s1.w};
            const float tarr[8] = {t0.x, t0.y, t0.z, t0.w, t1.x, t1.y, t1.z, t1.w};
            const float cnt = (float)((selA ? dgA : dgB) + 1);
            const int   row = selA ? rowA : rowB;
            bf16x8 pk;
#pragma unroll
            for (int j = 0; j < 8; ++j) {
                float av = selA ? aA[j] : aB[j];
                pk[j] = (bf16_t)(av * sarr[j] + cnt * tarr[j]);
            }
            *(bf16x8*)(&tile[row * 136 + (l16 << 3)]) = pk;
        }
    }
    __syncthreads();

    // ---- Phase 2: GEMM1 + bias + relu -> tile (reused) ----
    const int q = lane >> 4;
    const int c16 = lane & 15;
    const int arow = (w << 4) + c16;

    bf16x8 afr[4];
#pragma unroll
    for (int ks = 0; ks < 4; ++ks)
        afr[ks] = *(const bf16x8*)(&tile[arow * 136 + ks * 32 + q * 8]);
    __syncthreads();

    f32x4 acc[8];
#pragma unroll
    for (int nt = 0; nt < 8; ++nt) acc[nt] = (f32x4){0.f, 0.f, 0.f, 0.f};
#pragma unroll
    for (int ks = 0; ks < 4; ++ks) {
#pragma unroll
        for (int nt = 0; nt < 8; ++nt) {
            bf16x8 bfr = *(const bf16x8*)(w1s + (((ks << 3) + nt) * 64 + lane) * 8);
            acc[nt] = __builtin_amdgcn_mfma_f32_16x16x32_bf16(afr[ks], bfr, acc[nt], 0, 0, 0);
        }
    }
#pragma unroll
    for (int nt = 0; nt < 8; ++nt) {
        float bias = b1[(nt << 4) + c16];
#pragma unroll
        for (int i = 0; i < 4; ++i) {
            float v = fmaxf(acc[nt][i] + bias, 0.f);
            int row = (w << 4) + (q << 2) + i;
            tile[row * 136 + (nt << 4) + c16] = (bf16_t)v;
        }
    }
    __syncthreads();

    // ---- Phase 3: GEMM2 + bias + relu + BN stats -> tile ----
    bf16x8 afr2[4];
#pragma unroll
    for (int ks = 0; ks < 4; ++ks)
        afr2[ks] = *(const bf16x8*)(&tile[arow * 136 + ks * 32 + q * 8]);
    __syncthreads(); // tile overwritten below

#pragma unroll
    for (int nt = 0; nt < 8; ++nt) acc[nt] = (f32x4){0.f, 0.f, 0.f, 0.f};
#pragma unroll
    for (int ks = 0; ks < 4; ++ks) {
#pragma unroll
        for (int nt = 0; nt < 8; ++nt) {
            bf16x8 bfr = *(const bf16x8*)(w2s + (((ks << 3) + nt) * 64 + lane) * 8);
            acc[nt] = __builtin_amdgcn_mfma_f32_16x16x32_bf16(afr2[ks], bfr, acc[nt], 0, 0, 0);
        }
    }
#pragma unroll
    for (int nt = 0; nt < 8; ++nt) {
        float bias = b2[(nt << 4) + c16];
        float s1 = 0.f, s2 = 0.f;
#pragma unroll
        for (int i = 0; i < 4; ++i) {
            float v = fmaxf(acc[nt][i] + bias, 0.f);
            int row = (w << 4) + (q << 2) + i;
            s1 += v;
            s2 += v * v;
            tile[row * 136 + (nt << 4) + c16] = (bf16_t)v;
        }
        s1 += __shfl_down(s1, 32); s2 += __shfl_down(s2, 32);
        s1 += __shfl_down(s1, 16); s2 += __shfl_down(s2, 16);
        if (lane < 16) {
            atomicAdd(&stats[(nt << 4) + lane], s1);
            atomicAdd(&stats[DD + (nt << 4) + lane], s2);
        }
    }
    __syncthreads();

    // ---- Phase 4: quantize rows -> uint8 + scale. 4 threads per row. ----
    {
        int row4 = tid >> 2, t4 = tid & 3;   // rows 0..31
        int node = base + row4;
        const bf16_t* tp = tile + row4 * 136 + t4 * 32;
        bf16x8 v0 = *(const bf16x8*)(tp);
        bf16x8 v1 = *(const bf16x8*)(tp + 8);
        bf16x8 v2 = *(const bf16x8*)(tp + 16);
        bf16x8 v3 = *(const bf16x8*)(tp + 24);
        float am = 0.f;
#pragma unroll
        for (int k = 0; k < 8; ++k) {
            am = fmaxf(am, (float)v0[k]);
            am = fmaxf(am, (float)v1[k]);
            am = fmaxf(am, (float)v2[k]);
            am = fmaxf(am, (float)v3[k]);
        }
        am = fmaxf(am, __shfl_xor(am, 1));
        am = fmaxf(am, __shfl_xor(am, 2));
        float inv = am > 0.f ? 255.f / am : 0.f;
        if (t4 == 0) ysc[node] = am * (1.f / 255.f);
        u32 u[8];
        u[0] = pack4u((float)v0[0], (float)v0[1], (float)v0[2], (float)v0[3], inv);
        u[1] = pack4u((float)v0[4], (float)v0[5], (float)v0[6], (float)v0[7], inv);
        u[2] = pack4u((float)v1[0], (float)v1[1], (float)v1[2], (float)v1[3], inv);
        u[3] = pack4u((float)v1[4], (float)v1[5], (float)v1[6], (float)v1[7], inv);
        u[4] = pack4u((float)v2[0], (float)v2[1], (float)v2[2], (float)v2[3], inv);
        u[5] = pack4u((float)v2[4], (float)v2[5], (float)v2[6], (float)v2[7], inv);
        u[6] = pack4u((float)v3[0], (float)v3[1], (float)v3[2], (float)v3[3], inv);
        u[7] = pack4u((float)v3[4], (float)v3[5], (float)v3[6], (float)v3[7], inv);
        uint4* yp = (uint4*)(y8 + (size_t)node * DD + t4 * 32);
        yp[0] = make_uint4(u[0], u[1], u[2], u[3]);
        yp[1] = make_uint4(u[4], u[5], u[6], u[7]);
    }
}

// ---------------- pooling + head ----------------

// dequantizing segmented mean-pool, 2 nodes in flight per block
__global__ __launch_bounds__(256) void k_pool2u(
    const u8* __restrict__ y8, const float* __restrict__ ysc,
    const int* __restrict__ gstart,
    const float* __restrict__ scale, const float* __restrict__ shift,
    float* __restrict__ pooled)
{
    __shared__ float part[128];
    int g = blockIdx.x;
    int t = threadIdx.x;
    int f = t & 127, h = t >> 7;
    int s = gstart[g], e = gstart[g + 1];
    float acc = 0.f;
    for (int n = s + h; n < e; n += 2)
        acc += ysc[n] * (float)y8[(size_t)n * DD + f];
    if (h == 1) part[f] = acc;
    __syncthreads();
    if (h == 0) {
        acc += part[f];
        float cnt = (float)(e - s);
        float v = acc * scale[f] + cnt * shift[f];
        pooled[g * DD + f] = v / fmaxf(cnt, 1.0f);
    }
}

__global__ void k_head(const float* __restrict__ pooled,
                       const float* __restrict__ lin1w, const float* __restrict__ lin1b,
                       const float* __restrict__ lin2w, const float* __restrict__ lin2b,
                       float* __restrict__ out) {
    __shared__ float p[DD];
    __shared__ float h[DD];
    int g = blockIdx.x;
    int t = threadIdx.x;
    p[t] = pooled[g * DD + t];
    __syncthreads();
    float a = lin1b[t];
    for (int k = 0; k < DD; ++k) a += p[k] * lin1w[k * DD + t];
    h[t] = fmaxf(a, 0.f);
    __syncthreads();
    if (t < 10) {
        float o = lin2b[t];
        for (int k = 0; k < DD; ++k) o += h[k] * lin2w[k * 10 + t];
        out[g * 10 + t] = o;
    }
}

// ---------------- launch ----------------

extern "C" void kernel_launch(void* const* d_in, const int* in_sizes, int n_in,
                              void* d_out, int out_size, void* d_ws, size_t ws_size,
                              hipStream_t stream) {
    const float* x      = (const float*)d_in[0];
    const int*   ei     = (const int*)d_in[1];
    const int*   batch  = (const int*)d_in[2];
    const float* W1s    = (const float*)d_in[3];
    const float* b1s    = (const float*)d_in[4];
    const float* W2s    = (const float*)d_in[5];
    const float* b2s    = (const float*)d_in[6];
    const float* gammas = (const float*)d_in[7];
    const float* betas  = (const float*)d_in[8];
    const float* lin1w  = (const float*)d_in[9];
    const float* lin1b  = (const float*)d_in[10];
    const float* lin2w  = (const float*)d_in[11];
    const float* lin2b  = (const float*)d_in[12];
    float* out = (float*)d_out;

    char* p = (char*)d_ws;
    size_t off = 0;
    auto alloc = [&](size_t bytes) -> char* {
        char* r = p + off;
        off += (bytes + 255) & ~(size_t)255;
        return r;
    };
    int*    deg    = (int*)alloc(N_NODES * 4);
    float*  stats  = (float*)alloc(3 * 256 * 4);
    size_t zero_bytes = off;
    int*    poffs  = (int*)alloc((N_NODES + 1) * 4);
    int*    cursor = (int*)alloc(N_NODES * 4);
    int*    bsum   = (int*)alloc(128 * 4);
    int*    bbase  = (int*)alloc(128 * 4);
    int*    csr    = (int*)alloc(((size_t)N_EDGES + 4 * N_NODES + 64) * 4); // pad-4 + slack
    bf16_t* xb     = (bf16_t*)alloc((size_t)N_NODES * DD * 2);  // bf16 input; q8b aliases it after L0
    u8*     q8a    = (u8*)alloc((size_t)N_NODES * DD);
    float*  sca    = (float*)alloc(N_NODES * 4);
    float*  scb    = (float*)alloc(N_NODES * 4);
    bf16_t* wshuf  = (bf16_t*)alloc(6 * 16384 * 2);
    float*  ss     = (float*)alloc(4 * 256 * 4);
    int*    gstart = (int*)alloc((N_GRAPHS + 1) * 4);
    float*  pooled = (float*)alloc(N_GRAPHS * DD * 4);
    if (off > ws_size) return;

    // q8b reuses xb's storage: xb is only read by L0; q8b is written by L1 and
    // read by L2 (stream-ordered on one stream, no overlap). Proven in R10.
    u8* q8b = (u8*)xb;

    const int* srcA = ei;
    const int* dstA = ei + N_EDGES;

    k_zero<<<256, 256, 0, stream>>>((float4*)d_ws, (int)(zero_bytes / 16));
    k_hist<<<1024, 256, 0, stream>>>(dstA, deg);
    k_scan1<<<SCAN_B, 1024, 0, stream>>>(deg, bsum);
    k_scan2<<<1, 128, 0, stream>>>(bsum, bbase, poffs);
    k_scan3<<<SCAN_B, 1024, 0, stream>>>(deg, bbase, poffs, cursor);
    k_fill<<<1024, 256, 0, stream>>>(srcA, dstA, cursor, csr);
    k_pad<<<(N_NODES * 4 + 255) / 256, 256, 0, stream>>>(deg, poffs, csr);
    k_cvt<<<1024, 256, 0, stream>>>(x, xb);
    k_shufw<<<(6 * 16384 + 255) / 256, 256, 0, stream>>>(W1s, W2s, wshuf);
    k_aff_init<<<1, 128, 0, stream>>>(ss);
    k_gbounds<<<(N_NODES + 255) / 256, 256, 0, stream>>>(batch, gstart);

    // L0: xb (bf16) -> q8a. L1: q8a -> q8b (aliases xb). L2: q8b -> q8a.
    k_layer<false><<<NTILES, 128, 0, stream>>>(
        xb, q8a, sca, q8a, sca, poffs, csr, deg,
        ss + 0 * 256, ss + 0 * 256 + 128,
        wshuf + 0 * 16384, wshuf + 1 * 16384,
        b1s + 0 * DD, b2s + 0 * DD, stats + 0 * 256);
    k_aff_update<<<1, 128, 0, stream>>>(stats + 0 * 256, gammas + 0 * DD, betas + 0 * DD,
                                        ss + 1 * 256, ss + 1 * 256 + 128);
    k_layer<true><<<NTILES, 128, 0, stream>>>(
        xb, q8a, sca, q8b, scb, poffs, csr, deg,
        ss + 1 * 256, ss + 1 * 256 + 128,
        wshuf + 2 * 16384, wshuf + 3 * 16384,
        b1s + 1 * DD, b2s + 1 * DD, stats + 1 * 256);
    k_aff_update<<<1, 128, 0, stream>>>(stats + 1 * 256, gammas + 1 * DD, betas + 1 * DD,
                                        ss + 2 * 256, ss + 2 * 256 + 128);
    k_layer<true><<<NTILES, 128, 0, stream>>>(
        xb, q8b, scb, q8a, sca, poffs, csr, deg,
        ss + 2 * 256, ss + 2 * 256 + 128,
        wshuf + 4 * 16384, wshuf + 5 * 16384,
        b1s + 2 * DD, b2s + 2 * DD, stats + 2 * 256);
    k_aff_update<<<1, 128, 0, stream>>>(stats + 2 * 256, gammas + 2 * DD, betas + 2 * DD,
                                        ss + 3 * 256, ss + 3 * 256 + 128);

    k_pool2u<<<N_GRAPHS, 256, 0, stream>>>(q8a, sca, gstart,
                                           ss + 3 * 256, ss + 3 * 256 + 128, pooled);
    k_head<<<N_GRAPHS, 128, 0, stream>>>(pooled, lin1w, lin1b, lin2w, lin2b, out);
}

// Round 4
// 678.529 us; speedup vs baseline: 1.8080x; 1.6388x over previous
//
#include <hip/hip_runtime.h>
#include <hip/hip_bf16.h>

#define N_NODES 100000
#define N_EDGES 1600000
#define DD 128
#define N_GRAPHS 512
#define BN_EPS 1e-5f
#define NTILES 3125            // 3125*32 == 100000 exactly: no partial tiles
#define SCAN_B 98              // ceil(100000/1024)
#define RED_B 25               // 3125 = 25 * 125

typedef unsigned int u32;
typedef unsigned char u8;
typedef __bf16 bf16_t;
typedef __bf16 bf16x2 __attribute__((ext_vector_type(2)));
typedef __bf16 bf16x4 __attribute__((ext_vector_type(4)));
typedef __bf16 bf16x8 __attribute__((ext_vector_type(8)));
typedef float f32x4 __attribute__((ext_vector_type(4)));

__device__ __forceinline__ float bflo2f(u32 u) {
    union { u32 i; float f; } x; x.i = u << 16; return x.f;
}
__device__ __forceinline__ float bfhi2f(u32 u) {
    union { u32 i; float f; } x; x.i = u & 0xffff0000u; return x.f;
}
__device__ __forceinline__ u32 pack4u(float v0, float v1, float v2, float v3, float inv) {
    u32 q0 = (u32)fminf(rintf(v0 * inv), 255.f);
    u32 q1 = (u32)fminf(rintf(v1 * inv), 255.f);
    u32 q2 = (u32)fminf(rintf(v2 * inv), 255.f);
    u32 q3 = (u32)fminf(rintf(v3 * inv), 255.f);
    return q0 | (q1 << 8) | (q2 << 16) | (q3 << 24);
}

// ---------------- utility kernels ----------------

__global__ void k_zero(float4* p, int n) {
    float4 z = make_float4(0.f, 0.f, 0.f, 0.f);
    for (int i = blockIdx.x * blockDim.x + threadIdx.x; i < n; i += gridDim.x * blockDim.x)
        p[i] = z;
}

__global__ void k_hist(const int* __restrict__ dst, int* __restrict__ deg) {
    for (int e = blockIdx.x * blockDim.x + threadIdx.x; e < N_EDGES; e += gridDim.x * blockDim.x)
        atomicAdd(&deg[dst[e]], 1);
}

// hierarchical scan of padded degrees ((deg+3)&~3) -> poffs, cursor
__global__ void k_scan1(const int* __restrict__ deg, int* __restrict__ bsum) {
    __shared__ int sh[1024];
    int b = blockIdx.x, t = threadIdx.x;
    int i = b * 1024 + t;
    int pd = (i < N_NODES) ? ((deg[i] + 3) & ~3) : 0;
    sh[t] = pd;
    __syncthreads();
    for (int s = 512; s > 0; s >>= 1) {
        if (t < s) sh[t] += sh[t + s];
        __syncthreads();
    }
    if (t == 0) bsum[b] = sh[0];
}
__global__ void k_scan2(const int* __restrict__ bsum, int* __restrict__ bbase,
                        int* __restrict__ poffs) {
    __shared__ int sh[128];
    int t = threadIdx.x;
    int v = (t < SCAN_B) ? bsum[t] : 0;
    sh[t] = v;
    __syncthreads();
    for (int d = 1; d < 128; d <<= 1) {
        int o = (t >= d) ? sh[t - d] : 0;
        __syncthreads();
        sh[t] += o;
        __syncthreads();
    }
    if (t < SCAN_B) bbase[t] = sh[t] - v;          // exclusive base per block
    if (t == SCAN_B - 1) poffs[N_NODES] = sh[t];   // total padded edges
}
__global__ void k_scan3(const int* __restrict__ deg, const int* __restrict__ bbase,
                        int* __restrict__ poffs, int* __restrict__ cursor) {
    __shared__ int sh[1024];
    int b = blockIdx.x, t = threadIdx.x;
    int i = b * 1024 + t;
    int pd = (i < N_NODES) ? ((deg[i] + 3) & ~3) : 0;
    sh[t] = pd;
    __syncthreads();
    for (int d = 1; d < 1024; d <<= 1) {
        int o = (t >= d) ? sh[t - d] : 0;
        __syncthreads();
        sh[t] += o;
        __syncthreads();
    }
    if (i < N_NODES) {
        int off = bbase[b] + sh[t] - pd;
        poffs[i] = off; cursor[i] = off;
    }
}

__global__ void k_fill(const int* __restrict__ src, const int* __restrict__ dst,
                       int* __restrict__ cursor, int* __restrict__ csr) {
    for (int e = blockIdx.x * blockDim.x + threadIdx.x; e < N_EDGES; e += gridDim.x * blockDim.x) {
        int pos = atomicAdd(&cursor[dst[e]], 1);
        csr[pos] = src[e];
    }
}

// fill pad slots with the DEST node's own index; gather subtracts the
// overcount via the self-term coefficient (1 - #pads). Self line is L1-hot.
__global__ void k_pad(const int* __restrict__ deg, const int* __restrict__ poffs,
                      int* __restrict__ csr) {
    int t = blockIdx.x * blockDim.x + threadIdx.x;
    if (t >= N_NODES * 4) return;
    int n = t >> 2, j = t & 3;
    int s = poffs[n] + deg[n];
    if (s + j < poffs[n + 1]) csr[s + j] = n;
}

__global__ void k_cvt(const float* __restrict__ x, bf16_t* __restrict__ xb) {
    const int n4 = N_NODES * DD / 4;
    const float4* x4 = (const float4*)x;
    bf16x4* o4 = (bf16x4*)xb;
    for (int i = blockIdx.x * blockDim.x + threadIdx.x; i < n4; i += gridDim.x * blockDim.x) {
        float4 v = x4[i];
        bf16x4 o;
        o.x = (bf16_t)v.x; o.y = (bf16_t)v.y; o.z = (bf16_t)v.z; o.w = (bf16_t)v.w;
        o4[i] = o;
    }
}

// Pre-shuffle the 6 weight matrices into exact MFMA B-fragment order (bf16).
__global__ void k_shufw(const float* __restrict__ W1s, const float* __restrict__ W2s,
                        bf16_t* __restrict__ wshuf) {
    int t = blockIdx.x * blockDim.x + threadIdx.x;
    if (t >= 6 * 16384) return;
    int g  = t >> 14;
    int r  = t & 16383;
    int j  = r & 7;
    int L  = (r >> 3) & 63;
    int nt = (r >> 9) & 7;
    int ks = r >> 12;
    int l  = g >> 1;
    const float* src = (g & 1) ? (W2s + l * 16384) : (W1s + l * 16384);
    int k = ks * 32 + (L >> 4) * 8 + j;
    int n = nt * 16 + (L & 15);
    wshuf[t] = (bf16_t)src[k * DD + n];
}

__global__ void k_aff_init(float* __restrict__ ss) {
    int f = threadIdx.x;
    if (f < DD) { ss[f] = 1.0f; ss[DD + f] = 0.0f; }
}

// stage-2 reduction of per-block partial stats: 25 blocks x 125 rows
__global__ void k_red(const float* __restrict__ pstats, float* __restrict__ red) {
    int b = blockIdx.x;            // 0..24
    int t = threadIdx.x;           // 0..255
    const float* p = pstats + (size_t)b * 125 * 256 + t;
    float acc = 0.f;
    for (int i = 0; i < 125; ++i) acc += p[i * 256];
    red[b * 256 + t] = acc;
}

__global__ void k_aff_update(const float* __restrict__ red, const float* __restrict__ gamma,
                             const float* __restrict__ beta, float* __restrict__ scale,
                             float* __restrict__ shift) {
    int f = threadIdx.x;
    if (f < DD) {
        float s = 0.f, q = 0.f;
        for (int i = 0; i < RED_B; ++i) {
            s += red[i * 256 + f];
            q += red[i * 256 + 128 + f];
        }
        float mu  = s * (1.0f / N_NODES);
        float var = q * (1.0f / N_NODES) - mu * mu;
        float inv = rsqrtf(var + BN_EPS);
        float sc  = gamma[f] * inv;
        scale[f] = sc;
        shift[f] = beta[f] - mu * sc;
    }
}

__global__ void k_gbounds(const int* __restrict__ batch, int* __restrict__ gstart) {
    int i = blockIdx.x * blockDim.x + threadIdx.x;
    if (i >= N_NODES) return;
    int b = batch[i];
    int bp = (i == 0) ? -1 : batch[i - 1];
    for (int g = bp + 1; g <= b; ++g) gstart[g] = i;
    if (i == N_NODES - 1)
        for (int g = b + 1; g <= N_GRAPHS; ++g) gstart[g] = N_NODES;
}

// ---------------- gather helpers (quarter-split: 4 edges / instruction) ----
// lane = (q4, l16); lane covers features l16*8 .. l16*8+7 of edge csr[e+q4].
// bf16 row: dwordx4 (16B) per lane; u8 row: dwordx2 (8B) per lane.

template<bool IN_U8>
__device__ __forceinline__ void load_row8(
    const u8* __restrict__ xg, int r, int l16, float (&v)[8])
{
    if (IN_U8) {
        uint2 d = *(const uint2*)(xg + ((size_t)r << 7) + (l16 << 3));
        v[0] = (float)(d.x & 0xffu);
        v[1] = (float)((d.x >> 8) & 0xffu);
        v[2] = (float)((d.x >> 16) & 0xffu);
        v[3] = (float)(d.x >> 24);
        v[4] = (float)(d.y & 0xffu);
        v[5] = (float)((d.y >> 8) & 0xffu);
        v[6] = (float)((d.y >> 16) & 0xffu);
        v[7] = (float)(d.y >> 24);
    } else {
        uint4 d = *(const uint4*)(xg + ((size_t)r << 8) + (l16 << 4));
        v[0] = bflo2f(d.x); v[1] = bfhi2f(d.x);
        v[2] = bflo2f(d.y); v[3] = bfhi2f(d.y);
        v[4] = bflo2f(d.z); v[5] = bfhi2f(d.z);
        v[6] = bflo2f(d.w); v[7] = bfhi2f(d.w);
    }
}

template<bool IN_U8>
__device__ __forceinline__ void acc_group(
    const u8* __restrict__ xg, const float* __restrict__ xsc,
    int r, int l16, float (&a)[8])
{
    float v[8];
    load_row8<IN_U8>(xg, r, l16, v);
    if (IN_U8) {
        float s = xsc[r];
#pragma unroll
        for (int j = 0; j < 8; ++j) a[j] += s * v[j];
    } else {
#pragma unroll
        for (int j = 0; j < 8; ++j) a[j] += v[j];
    }
}

// ---------------- gather kernel (phase 1, split out for attribution) ------
// R15: k_layer split into k_gather (aggregation -> xt in global) and k_mlp
// (GEMM/quantize). Rationale: R12/R13/R14 nulls show the 250us/layer is
// invariant to waves, outstanding loads, instruction count, and bytes; the
// split gives per-phase rocprof attribution. Stats atomics (1.6M same-
// address fp32 RMW/layer; the WRITE_SIZE=63MB vs 13MB actual-output anomaly)
// are replaced by plain-store partials + tree reduction.
template<bool IN_U8>
__global__ __launch_bounds__(128, 8) void k_gather(
    const bf16_t* __restrict__ xb,
    const u8* __restrict__ x8, const float* __restrict__ xsc,
    const int* __restrict__ poffs, const int* __restrict__ csr,
    const int* __restrict__ deg,
    const float* __restrict__ scale, const float* __restrict__ shift,
    bf16_t* __restrict__ xt)
{
    const int tid  = threadIdx.x;
    const int w    = tid >> 6;           // 0..1
    const int lane = tid & 63;
    const int base = blockIdx.x * 32;
    const int q4   = lane >> 4;          // quarter: which edge of the group
    const int l16  = lane & 15;          // feature octet within the row

    const u8* xg = IN_U8 ? x8 : (const u8*)xb;

    for (int rp = 0; rp < 8; ++rp) {
        const int rowA = (w << 4) + rp;  // rows 0..7 / 16..23
        const int rowB = rowA + 8;       // rows 8..15 / 24..31
        const int nA = base + rowA;
        const int nB = base + rowB;      // always < N_NODES (exact tiling)

        float aA[8] = {0.f, 0.f, 0.f, 0.f, 0.f, 0.f, 0.f, 0.f};
        float aB[8] = {0.f, 0.f, 0.f, 0.f, 0.f, 0.f, 0.f, 0.f};

        int eA = poffs[nA], eEA = poffs[nA + 1];
        int eB = poffs[nB], eEB = poffs[nB + 1];

        int rA = csr[eA + q4];
        int rB = csr[eB + q4];

        while ((eA < eEA) & (eB < eEB)) {
            int rA2 = csr[eA + 4 + q4];   // prefetch next groups (csr has slack)
            int rB2 = csr[eB + 4 + q4];
            acc_group<IN_U8>(xg, xsc, rA, l16, aA);
            acc_group<IN_U8>(xg, xsc, rB, l16, aB);
            rA = rA2; rB = rB2; eA += 4; eB += 4;
        }
        while (eA < eEA) {
            acc_group<IN_U8>(xg, xsc, rA, l16, aA);
            eA += 4; rA = csr[eA + q4];
        }
        while (eB < eEB) {
            acc_group<IN_U8>(xg, xsc, rB, l16, aB);
            eB += 4; rB = csr[eB + q4];
        }

        // self terms: one load instruction covers both selves (quarters 0/1)
        const int dgA = deg[nA], dgB = deg[nB];
        const float scoA = 1.f - (float)(((dgA + 3) & ~3) - dgA);
        const float scoB = 1.f - (float)(((dgB + 3) & ~3) - dgB);
        {
            int rs = (q4 & 1) ? nB : nA;
            float v[8];
            load_row8<IN_U8>(xg, rs, l16, v);
            float coA = (q4 == 0) ? scoA : 0.f;
            float coB = (q4 == 1) ? scoB : 0.f;
            if (IN_U8) {
                float s = xsc[rs];
                coA *= s; coB *= s;
            }
#pragma unroll
            for (int j = 0; j < 8; ++j) {
                aA[j] += coA * v[j];
                aB[j] += coB * v[j];
            }
        }

        // combine quarters: lanes l, l^16, l^32, l^48 hold same features
#pragma unroll
        for (int j = 0; j < 8; ++j) {
            aA[j] += __shfl_xor(aA[j], 16);
            aA[j] += __shfl_xor(aA[j], 32);
            aB[j] += __shfl_xor(aB[j], 16);
            aB[j] += __shfl_xor(aB[j], 32);
        }

        // BN-affine + write: lanes 0-15 write row A, lanes 16-31 write row B
        if (q4 < 2) {
            const bool selA = (q4 == 0);
            const float4 s0 = *(const float4*)(scale + (l16 << 3));
            const float4 s1 = *(const float4*)(scale + (l16 << 3) + 4);
            const float4 t0 = *(const float4*)(shift + (l16 << 3));
            const float4 t1 = *(const float4*)(shift + (l16 << 3) + 4);
            const float sarr[8] = {s0.x, s0.y, s0.z, s0.w, s1.x, s1.y, s1.z, s1.w};
            const float tarr[8] = {t0.x, t0.y, t0.z, t0.w, t1.x, t1.y, t1.z, t1.w};
            const int   node = selA ? nA : nB;
            const float cnt = (float)((selA ? dgA : dgB) + 1);
            bf16x8 pk;
#pragma unroll
            for (int j = 0; j < 8; ++j) {
                float av = selA ? aA[j] : aB[j];
                pk[j] = (bf16_t)(av * sarr[j] + cnt * tarr[j]);
            }
            *(bf16x8*)(xt + (size_t)node * DD + (l16 << 3)) = pk;
        }
    }
}

// ---------------- MLP kernel (phases 2-4) ----------------
__global__ __launch_bounds__(128, 8) void k_mlp(
    const bf16_t* __restrict__ xt,
    u8* __restrict__ y8, float* __restrict__ ysc,
    const bf16_t* __restrict__ w1s, const bf16_t* __restrict__ w2s,
    const float* __restrict__ b1, const float* __restrict__ b2,
    float* __restrict__ pstats)
{
    __shared__ __align__(16) bf16_t tile[32 * 136];
    __shared__ float swsum[2][128];
    __shared__ float swsq[2][128];

    const int tid  = threadIdx.x;
    const int w    = tid >> 6;
    const int lane = tid & 63;
    const int base = blockIdx.x * 32;

    const int q = lane >> 4;
    const int c16 = lane & 15;
    const int arow = (w << 4) + c16;

    // ---- Phase 2: GEMM1 + bias + relu -> tile ----
    // A-fragments straight from global xt (coalesced 16B/lane)
    bf16x8 afr[4];
#pragma unroll
    for (int ks = 0; ks < 4; ++ks)
        afr[ks] = *(const bf16x8*)(xt + (size_t)(base + arow) * DD + ks * 32 + q * 8);

    f32x4 acc[8];
#pragma unroll
    for (int nt = 0; nt < 8; ++nt) acc[nt] = (f32x4){0.f, 0.f, 0.f, 0.f};
#pragma unroll
    for (int ks = 0; ks < 4; ++ks) {
#pragma unroll
        for (int nt = 0; nt < 8; ++nt) {
            bf16x8 bfr = *(const bf16x8*)(w1s + (((ks << 3) + nt) * 64 + lane) * 8);
            acc[nt] = __builtin_amdgcn_mfma_f32_16x16x32_bf16(afr[ks], bfr, acc[nt], 0, 0, 0);
        }
    }
#pragma unroll
    for (int nt = 0; nt < 8; ++nt) {
        float bias = b1[(nt << 4) + c16];
#pragma unroll
        for (int i = 0; i < 4; ++i) {
            float v = fmaxf(acc[nt][i] + bias, 0.f);
            int row = (w << 4) + (q << 2) + i;
            tile[row * 136 + (nt << 4) + c16] = (bf16_t)v;
        }
    }
    __syncthreads();

    // ---- Phase 3: GEMM2 + bias + relu + BN partials -> tile ----
    bf16x8 afr2[4];
#pragma unroll
    for (int ks = 0; ks < 4; ++ks)
        afr2[ks] = *(const bf16x8*)(&tile[arow * 136 + ks * 32 + q * 8]);
    __syncthreads(); // tile overwritten below

#pragma unroll
    for (int nt = 0; nt < 8; ++nt) acc[nt] = (f32x4){0.f, 0.f, 0.f, 0.f};
#pragma unroll
    for (int ks = 0; ks < 4; ++ks) {
#pragma unroll
        for (int nt = 0; nt < 8; ++nt) {
            bf16x8 bfr = *(const bf16x8*)(w2s + (((ks << 3) + nt) * 64 + lane) * 8);
            acc[nt] = __builtin_amdgcn_mfma_f32_16x16x32_bf16(afr2[ks], bfr, acc[nt], 0, 0, 0);
        }
    }
#pragma unroll
    for (int nt = 0; nt < 8; ++nt) {
        float bias = b2[(nt << 4) + c16];
        float s1 = 0.f, s2 = 0.f;
#pragma unroll
        for (int i = 0; i < 4; ++i) {
            float v = fmaxf(acc[nt][i] + bias, 0.f);
            int row = (w << 4) + (q << 2) + i;
            s1 += v;
            s2 += v * v;
            tile[row * 136 + (nt << 4) + c16] = (bf16_t)v;
        }
        s1 += __shfl_down(s1, 32); s2 += __shfl_down(s2, 32);
        s1 += __shfl_down(s1, 16); s2 += __shfl_down(s2, 16);
        if (lane < 16) {
            swsum[w][(nt << 4) + lane] = s1;
            swsq[w][(nt << 4) + lane] = s2;
        }
    }
    __syncthreads();

    // per-block partial stats: plain coalesced stores (no atomics)
    {
        float ps = swsum[0][tid & 127] + swsum[1][tid & 127];
        float pq = swsq[0][tid & 127] + swsq[1][tid & 127];
        float* pb = pstats + (size_t)blockIdx.x * 256;
        pb[tid] = ps;          // tid in 0..127
        pb[128 + tid] = pq;
    }

    // ---- Phase 4: quantize rows -> uint8 + scale. 4 threads per row. ----
    {
        int row4 = tid >> 2, t4 = tid & 3;   // rows 0..31
        int node = base + row4;
        const bf16_t* tp = tile + row4 * 136 + t4 * 32;
        bf16x8 v0 = *(const bf16x8*)(tp);
        bf16x8 v1 = *(const bf16x8*)(tp + 8);
        bf16x8 v2 = *(const bf16x8*)(tp + 16);
        bf16x8 v3 = *(const bf16x8*)(tp + 24);
        float am = 0.f;
#pragma unroll
        for (int k = 0; k < 8; ++k) {
            am = fmaxf(am, (float)v0[k]);
            am = fmaxf(am, (float)v1[k]);
            am = fmaxf(am, (float)v2[k]);
            am = fmaxf(am, (float)v3[k]);
        }
        am = fmaxf(am, __shfl_xor(am, 1));
        am = fmaxf(am, __shfl_xor(am, 2));
        float inv = am > 0.f ? 255.f / am : 0.f;
        if (t4 == 0) ysc[node] = am * (1.f / 255.f);
        u32 u[8];
        u[0] = pack4u((float)v0[0], (float)v0[1], (float)v0[2], (float)v0[3], inv);
        u[1] = pack4u((float)v0[4], (float)v0[5], (float)v0[6], (float)v0[7], inv);
        u[2] = pack4u((float)v1[0], (float)v1[1], (float)v1[2], (float)v1[3], inv);
        u[3] = pack4u((float)v1[4], (float)v1[5], (float)v1[6], (float)v1[7], inv);
        u[4] = pack4u((float)v2[0], (float)v2[1], (float)v2[2], (float)v2[3], inv);
        u[5] = pack4u((float)v2[4], (float)v2[5], (float)v2[6], (float)v2[7], inv);
        u[6] = pack4u((float)v3[0], (float)v3[1], (float)v3[2], (float)v3[3], inv);
        u[7] = pack4u((float)v3[4], (float)v3[5], (float)v3[6], (float)v3[7], inv);
        uint4* yp = (uint4*)(y8 + (size_t)node * DD + t4 * 32);
        yp[0] = make_uint4(u[0], u[1], u[2], u[3]);
        yp[1] = make_uint4(u[4], u[5], u[6], u[7]);
    }
}

// ---------------- pooling + head ----------------

// dequantizing segmented mean-pool, 2 nodes in flight per block
__global__ __launch_bounds__(256) void k_pool2u(
    const u8* __restrict__ y8, const float* __restrict__ ysc,
    const int* __restrict__ gstart,
    const float* __restrict__ scale, const float* __restrict__ shift,
    float* __restrict__ pooled)
{
    __shared__ float part[128];
    int g = blockIdx.x;
    int t = threadIdx.x;
    int f = t & 127, h = t >> 7;
    int s = gstart[g], e = gstart[g + 1];
    float acc = 0.f;
    for (int n = s + h; n < e; n += 2)
        acc += ysc[n] * (float)y8[(size_t)n * DD + f];
    if (h == 1) part[f] = acc;
    __syncthreads();
    if (h == 0) {
        acc += part[f];
        float cnt = (float)(e - s);
        float v = acc * scale[f] + cnt * shift[f];
        pooled[g * DD + f] = v / fmaxf(cnt, 1.0f);
    }
}

__global__ void k_head(const float* __restrict__ pooled,
                       const float* __restrict__ lin1w, const float* __restrict__ lin1b,
                       const float* __restrict__ lin2w, const float* __restrict__ lin2b,
                       float* __restrict__ out) {
    __shared__ float p[DD];
    __shared__ float h[DD];
    int g = blockIdx.x;
    int t = threadIdx.x;
    p[t] = pooled[g * DD + t];
    __syncthreads();
    float a = lin1b[t];
    for (int k = 0; k < DD; ++k) a += p[k] * lin1w[k * DD + t];
    h[t] = fmaxf(a, 0.f);
    __syncthreads();
    if (t < 10) {
        float o = lin2b[t];
        for (int k = 0; k < DD; ++k) o += h[k] * lin2w[k * 10 + t];
        out[g * 10 + t] = o;
    }
}

// ---------------- launch ----------------

extern "C" void kernel_launch(void* const* d_in, const int* in_sizes, int n_in,
                              void* d_out, int out_size, void* d_ws, size_t ws_size,
                              hipStream_t stream) {
    const float* x      = (const float*)d_in[0];
    const int*   ei     = (const int*)d_in[1];
    const int*   batch  = (const int*)d_in[2];
    const float* W1s    = (const float*)d_in[3];
    const float* b1s    = (const float*)d_in[4];
    const float* W2s    = (const float*)d_in[5];
    const float* b2s    = (const float*)d_in[6];
    const float* gammas = (const float*)d_in[7];
    const float* betas  = (const float*)d_in[8];
    const float* lin1w  = (const float*)d_in[9];
    const float* lin1b  = (const float*)d_in[10];
    const float* lin2w  = (const float*)d_in[11];
    const float* lin2b  = (const float*)d_in[12];
    float* out = (float*)d_out;

    char* p = (char*)d_ws;
    size_t off = 0;
    auto alloc = [&](size_t bytes) -> char* {
        char* r = p + off;
        off += (bytes + 255) & ~(size_t)255;
        return r;
    };
    int*    deg    = (int*)alloc(N_NODES * 4);
    size_t zero_bytes = off;
    int*    poffs  = (int*)alloc((N_NODES + 1) * 4);
    int*    cursor = (int*)alloc(N_NODES * 4);
    int*    bsum   = (int*)alloc(128 * 4);
    int*    bbase  = (int*)alloc(128 * 4);
    int*    csr    = (int*)alloc(((size_t)N_EDGES + 4 * N_NODES + 64) * 4); // pad-4 + slack
    bf16_t* xb     = (bf16_t*)alloc((size_t)N_NODES * DD * 2);  // bf16 input; q8b aliases it after L0
    u8*     q8a    = (u8*)alloc((size_t)N_NODES * DD);
    float*  sca    = (float*)alloc(N_NODES * 4);
    float*  scb    = (float*)alloc(N_NODES * 4);
    bf16_t* wshuf  = (bf16_t*)alloc(6 * 16384 * 2);
    float*  ss     = (float*)alloc(4 * 256 * 4);
    int*    gstart = (int*)alloc((N_GRAPHS + 1) * 4);
    float*  pooled = (float*)alloc(N_GRAPHS * DD * 4);
    bf16_t* xt     = (bf16_t*)alloc((size_t)N_NODES * DD * 2);   // aggregated rows
    float*  pstats = (float*)alloc((size_t)NTILES * 256 * 4);    // per-block partials
    float*  red    = (float*)alloc(RED_B * 256 * 4);             // stage-2 partials
    if (off > ws_size) return;

    // q8b reuses xb's storage: xb is only read by L0; q8b is written by L1 and
    // read by L2 (stream-ordered on one stream, no overlap). Proven in R10.
    u8* q8b = (u8*)xb;

    const int* srcA = ei;
    const int* dstA = ei + N_EDGES;

    k_zero<<<256, 256, 0, stream>>>((float4*)d_ws, (int)(zero_bytes / 16));
    k_hist<<<1024, 256, 0, stream>>>(dstA, deg);
    k_scan1<<<SCAN_B, 1024, 0, stream>>>(deg, bsum);
    k_scan2<<<1, 128, 0, stream>>>(bsum, bbase, poffs);
    k_scan3<<<SCAN_B, 1024, 0, stream>>>(deg, bbase, poffs, cursor);
    k_fill<<<1024, 256, 0, stream>>>(srcA, dstA, cursor, csr);
    k_pad<<<(N_NODES * 4 + 255) / 256, 256, 0, stream>>>(deg, poffs, csr);
    k_cvt<<<1024, 256, 0, stream>>>(x, xb);
    k_shufw<<<(6 * 16384 + 255) / 256, 256, 0, stream>>>(W1s, W2s, wshuf);
    k_aff_init<<<1, 128, 0, stream>>>(ss);
    k_gbounds<<<(N_NODES + 255) / 256, 256, 0, stream>>>(batch, gstart);

    // L0: xb (bf16) -> q8a. L1: q8a -> q8b (aliases xb). L2: q8b -> q8a.
    k_gather<false><<<NTILES, 128, 0, stream>>>(
        xb, q8a, sca, poffs, csr, deg,
        ss + 0 * 256, ss + 0 * 256 + 128, xt);
    k_mlp<<<NTILES, 128, 0, stream>>>(
        xt, q8a, sca,
        wshuf + 0 * 16384, wshuf + 1 * 16384,
        b1s + 0 * DD, b2s + 0 * DD, pstats);
    k_red<<<RED_B, 256, 0, stream>>>(pstats, red);
    k_aff_update<<<1, 128, 0, stream>>>(red, gammas + 0 * DD, betas + 0 * DD,
                                        ss + 1 * 256, ss + 1 * 256 + 128);

    k_gather<true><<<NTILES, 128, 0, stream>>>(
        xb, q8a, sca, poffs, csr, deg,
        ss + 1 * 256, ss + 1 * 256 + 128, xt);
    k_mlp<<<NTILES, 128, 0, stream>>>(
        xt, q8b, scb,
        wshuf + 2 * 16384, wshuf + 3 * 16384,
        b1s + 1 * DD, b2s + 1 * DD, pstats);
    k_red<<<RED_B, 256, 0, stream>>>(pstats, red);
    k_aff_update<<<1, 128, 0, stream>>>(red, gammas + 1 * DD, betas + 1 * DD,
                                        ss + 2 * 256, ss + 2 * 256 + 128);

    k_gather<true><<<NTILES, 128, 0, stream>>>(
        xb, q8b, scb, poffs, csr, deg,
        ss + 2 * 256, ss + 2 * 256 + 128, xt);
    k_mlp<<<NTILES, 128, 0, stream>>>(
        xt, q8a, sca,
        wshuf + 4 * 16384, wshuf + 5 * 16384,
        b1s + 2 * DD, b2s + 2 * DD, pstats);
    k_red<<<RED_B, 256, 0, stream>>>(pstats, red);
    k_aff_update<<<1, 128, 0, stream>>>(red, gammas + 2 * DD, betas + 2 * DD,
                                        ss + 3 * 256, ss + 3 * 256 + 128);

    k_pool2u<<<N_GRAPHS, 256, 0, stream>>>(q8a, sca, gstart,
                                           ss + 3 * 256, ss + 3 * 256 + 128, pooled);
    k_head<<<N_GRAPHS, 128, 0, stream>>>(pooled, lin1w, lin1b, lin2w, lin2b, out);
}

// Round 5
// 611.121 us; speedup vs baseline: 2.0075x; 1.1103x over previous
//
#include <hip/hip_runtime.h>
#include <hip/hip_bf16.h>

#define N_NODES 100000
#define N_EDGES 1600000
#define DD 128
#define N_GRAPHS 512
#define BN_EPS 1e-5f
#define NTILES 3125            // 3125*32 == 100000 exactly: no partial tiles
#define SCAN_B 98              // ceil(100000/1024)
#define RED_B 25               // 3125 = 25 * 125
#define PART_N 12500           // N_NODES / 8 (per-XCD node slice)

typedef unsigned int u32;
typedef unsigned char u8;
typedef __bf16 bf16_t;
typedef __bf16 bf16x2 __attribute__((ext_vector_type(2)));
typedef __bf16 bf16x4 __attribute__((ext_vector_type(4)));
typedef __bf16 bf16x8 __attribute__((ext_vector_type(8)));
typedef float f32x4 __attribute__((ext_vector_type(4)));

__device__ __forceinline__ float bflo2f(u32 u) {
    union { u32 i; float f; } x; x.i = u << 16; return x.f;
}
__device__ __forceinline__ float bfhi2f(u32 u) {
    union { u32 i; float f; } x; x.i = u & 0xffff0000u; return x.f;
}
__device__ __forceinline__ u32 pack4u(float v0, float v1, float v2, float v3, float inv) {
    u32 q0 = (u32)fminf(rintf(v0 * inv), 255.f);
    u32 q1 = (u32)fminf(rintf(v1 * inv), 255.f);
    u32 q2 = (u32)fminf(rintf(v2 * inv), 255.f);
    u32 q3 = (u32)fminf(rintf(v3 * inv), 255.f);
    return q0 | (q1 << 8) | (q2 << 16) | (q3 << 24);
}

// ---------------- utility kernels ----------------

__global__ void k_zero(float4* p, int n) {
    float4 z = make_float4(0.f, 0.f, 0.f, 0.f);
    for (int i = blockIdx.x * blockDim.x + threadIdx.x; i < n; i += gridDim.x * blockDim.x)
        p[i] = z;
}

// R16: XCD-partitioned histogram. Blocks with blockIdx&7==p (one XCD under
// round-robin dispatch) own dst range [p*12500,(p+1)*12500): deg lines are
// single-XCD -> atomics resolve in that XCD's L2 instead of ping-ponging
// through HBM. Each cohort scans the full edge list (8x reads, L3-served).
__global__ void k_hist8(const int* __restrict__ dst, int* __restrict__ deg) {
    const int part = blockIdx.x & 7;
    const int lo = part * PART_N, hi = lo + PART_N;
    const int start = (blockIdx.x >> 3) * blockDim.x + threadIdx.x;
    const int stride = (gridDim.x >> 3) * blockDim.x;
    for (int e = start; e < N_EDGES; e += stride) {
        int d = dst[e];
        if (d >= lo && d < hi) atomicAdd(&deg[d], 1);
    }
}

// hierarchical scan of padded degrees ((deg+3)&~3) -> poffs, cursor
__global__ void k_scan1(const int* __restrict__ deg, int* __restrict__ bsum) {
    __shared__ int sh[1024];
    int b = blockIdx.x, t = threadIdx.x;
    int i = b * 1024 + t;
    int pd = (i < N_NODES) ? ((deg[i] + 3) & ~3) : 0;
    sh[t] = pd;
    __syncthreads();
    for (int s = 512; s > 0; s >>= 1) {
        if (t < s) sh[t] += sh[t + s];
        __syncthreads();
    }
    if (t == 0) bsum[b] = sh[0];
}
__global__ void k_scan2(const int* __restrict__ bsum, int* __restrict__ bbase,
                        int* __restrict__ poffs) {
    __shared__ int sh[128];
    int t = threadIdx.x;
    int v = (t < SCAN_B) ? bsum[t] : 0;
    sh[t] = v;
    __syncthreads();
    for (int d = 1; d < 128; d <<= 1) {
        int o = (t >= d) ? sh[t - d] : 0;
        __syncthreads();
        sh[t] += o;
        __syncthreads();
    }
    if (t < SCAN_B) bbase[t] = sh[t] - v;          // exclusive base per block
    if (t == SCAN_B - 1) poffs[N_NODES] = sh[t];   // total padded edges
}
__global__ void k_scan3(const int* __restrict__ deg, const int* __restrict__ bbase,
                        int* __restrict__ poffs, int* __restrict__ cursor) {
    __shared__ int sh[1024];
    int b = blockIdx.x, t = threadIdx.x;
    int i = b * 1024 + t;
    int pd = (i < N_NODES) ? ((deg[i] + 3) & ~3) : 0;
    sh[t] = pd;
    __syncthreads();
    for (int d = 1; d < 1024; d <<= 1) {
        int o = (t >= d) ? sh[t - d] : 0;
        __syncthreads();
        sh[t] += o;
        __syncthreads();
    }
    if (i < N_NODES) {
        int off = bbase[b] + sh[t] - pd;
        poffs[i] = off; cursor[i] = off;
    }
}

// R16: XCD-partitioned fill. poffs is monotone in node id, so each dst
// slice owns a CONTIGUOUS ~800KB csr region -> all scattered csr stores and
// cursor atomics for that region stay in one XCD's L2; lines accumulate all
// 16 slots before writeback (WRITE_SIZE 103MB -> ~csr size).
__global__ void k_fill8(const int* __restrict__ src, const int* __restrict__ dst,
                        int* __restrict__ cursor, int* __restrict__ csr) {
    const int part = blockIdx.x & 7;
    const int lo = part * PART_N, hi = lo + PART_N;
    const int start = (blockIdx.x >> 3) * blockDim.x + threadIdx.x;
    const int stride = (gridDim.x >> 3) * blockDim.x;
    for (int e = start; e < N_EDGES; e += stride) {
        int d = dst[e];
        if (d >= lo && d < hi) {
            int pos = atomicAdd(&cursor[d], 1);
            csr[pos] = src[e];
        }
    }
}

// fill pad slots with the DEST node's own index; gather subtracts the
// overcount via the self-term coefficient (1 - #pads). Self line is L1-hot.
__global__ void k_pad(const int* __restrict__ deg, const int* __restrict__ poffs,
                      int* __restrict__ csr) {
    int t = blockIdx.x * blockDim.x + threadIdx.x;
    if (t >= N_NODES * 4) return;
    int n = t >> 2, j = t & 3;
    int s = poffs[n] + deg[n];
    if (s + j < poffs[n + 1]) csr[s + j] = n;
}

__global__ void k_cvt(const float* __restrict__ x, bf16_t* __restrict__ xb) {
    const int n4 = N_NODES * DD / 4;
    const float4* x4 = (const float4*)x;
    bf16x4* o4 = (bf16x4*)xb;
    for (int i = blockIdx.x * blockDim.x + threadIdx.x; i < n4; i += gridDim.x * blockDim.x) {
        float4 v = x4[i];
        bf16x4 o;
        o.x = (bf16_t)v.x; o.y = (bf16_t)v.y; o.z = (bf16_t)v.z; o.w = (bf16_t)v.w;
        o4[i] = o;
    }
}

// Pre-shuffle the 6 weight matrices into exact MFMA B-fragment order (bf16).
__global__ void k_shufw(const float* __restrict__ W1s, const float* __restrict__ W2s,
                        bf16_t* __restrict__ wshuf) {
    int t = blockIdx.x * blockDim.x + threadIdx.x;
    if (t >= 6 * 16384) return;
    int g  = t >> 14;
    int r  = t & 16383;
    int j  = r & 7;
    int L  = (r >> 3) & 63;
    int nt = (r >> 9) & 7;
    int ks = r >> 12;
    int l  = g >> 1;
    const float* src = (g & 1) ? (W2s + l * 16384) : (W1s + l * 16384);
    int k = ks * 32 + (L >> 4) * 8 + j;
    int n = nt * 16 + (L & 15);
    wshuf[t] = (bf16_t)src[k * DD + n];
}

__global__ void k_aff_init(float* __restrict__ ss) {
    int f = threadIdx.x;
    if (f < DD) { ss[f] = 1.0f; ss[DD + f] = 0.0f; }
}

// stage-2 reduction of per-block partial stats: 25 blocks x 125 rows
__global__ void k_red(const float* __restrict__ pstats, float* __restrict__ red) {
    int b = blockIdx.x;            // 0..24
    int t = threadIdx.x;           // 0..255
    const float* p = pstats + (size_t)b * 125 * 256 + t;
    float acc = 0.f;
    for (int i = 0; i < 125; ++i) acc += p[i * 256];
    red[b * 256 + t] = acc;
}

__global__ void k_aff_update(const float* __restrict__ red, const float* __restrict__ gamma,
                             const float* __restrict__ beta, float* __restrict__ scale,
                             float* __restrict__ shift) {
    int f = threadIdx.x;
    if (f < DD) {
        float s = 0.f, q = 0.f;
        for (int i = 0; i < RED_B; ++i) {
            s += red[i * 256 + f];
            q += red[i * 256 + 128 + f];
        }
        float mu  = s * (1.0f / N_NODES);
        float var = q * (1.0f / N_NODES) - mu * mu;
        float inv = rsqrtf(var + BN_EPS);
        float sc  = gamma[f] * inv;
        scale[f] = sc;
        shift[f] = beta[f] - mu * sc;
    }
}

__global__ void k_gbounds(const int* __restrict__ batch, int* __restrict__ gstart) {
    int i = blockIdx.x * blockDim.x + threadIdx.x;
    if (i >= N_NODES) return;
    int b = batch[i];
    int bp = (i == 0) ? -1 : batch[i - 1];
    for (int g = bp + 1; g <= b; ++g) gstart[g] = i;
    if (i == N_NODES - 1)
        for (int g = b + 1; g <= N_GRAPHS; ++g) gstart[g] = N_NODES;
}

// ---------------- gather helpers (quarter-split: 4 edges / instruction) ----
// lane = (q4, l16); lane covers features l16*8 .. l16*8+7 of edge csr[e+q4].
// bf16 row: dwordx4 (16B) per lane; u8 row: dwordx2 (8B) per lane.

template<bool IN_U8>
__device__ __forceinline__ void load_row8(
    const u8* __restrict__ xg, int r, int l16, float (&v)[8])
{
    if (IN_U8) {
        uint2 d = *(const uint2*)(xg + ((size_t)r << 7) + (l16 << 3));
        v[0] = (float)(d.x & 0xffu);
        v[1] = (float)((d.x >> 8) & 0xffu);
        v[2] = (float)((d.x >> 16) & 0xffu);
        v[3] = (float)(d.x >> 24);
        v[4] = (float)(d.y & 0xffu);
        v[5] = (float)((d.y >> 8) & 0xffu);
        v[6] = (float)((d.y >> 16) & 0xffu);
        v[7] = (float)(d.y >> 24);
    } else {
        uint4 d = *(const uint4*)(xg + ((size_t)r << 8) + (l16 << 4));
        v[0] = bflo2f(d.x); v[1] = bfhi2f(d.x);
        v[2] = bflo2f(d.y); v[3] = bfhi2f(d.y);
        v[4] = bflo2f(d.z); v[5] = bfhi2f(d.z);
        v[6] = bflo2f(d.w); v[7] = bfhi2f(d.w);
    }
}

template<bool IN_U8>
__device__ __forceinline__ void acc_group(
    const u8* __restrict__ xg, const float* __restrict__ xsc,
    int r, int l16, float (&a)[8])
{
    float v[8];
    load_row8<IN_U8>(xg, r, l16, v);
    if (IN_U8) {
        float s = xsc[r];
#pragma unroll
        for (int j = 0; j < 8; ++j) a[j] += s * v[j];
    } else {
#pragma unroll
        for (int j = 0; j < 8; ++j) a[j] += v[j];
    }
}

// ---------------- gather kernel (phase 1) ----------------
template<bool IN_U8>
__global__ __launch_bounds__(128, 8) void k_gather(
    const bf16_t* __restrict__ xb,
    const u8* __restrict__ x8, const float* __restrict__ xsc,
    const int* __restrict__ poffs, const int* __restrict__ csr,
    const int* __restrict__ deg,
    const float* __restrict__ scale, const float* __restrict__ shift,
    bf16_t* __restrict__ xt)
{
    const int tid  = threadIdx.x;
    const int w    = tid >> 6;           // 0..1
    const int lane = tid & 63;
    const int base = blockIdx.x * 32;
    const int q4   = lane >> 4;          // quarter: which edge of the group
    const int l16  = lane & 15;          // feature octet within the row

    const u8* xg = IN_U8 ? x8 : (const u8*)xb;

    for (int rp = 0; rp < 8; ++rp) {
        const int rowA = (w << 4) + rp;  // rows 0..7 / 16..23
        const int rowB = rowA + 8;       // rows 8..15 / 24..31
        const int nA = base + rowA;
        const int nB = base + rowB;      // always < N_NODES (exact tiling)

        float aA[8] = {0.f, 0.f, 0.f, 0.f, 0.f, 0.f, 0.f, 0.f};
        float aB[8] = {0.f, 0.f, 0.f, 0.f, 0.f, 0.f, 0.f, 0.f};

        int eA = poffs[nA], eEA = poffs[nA + 1];
        int eB = poffs[nB], eEB = poffs[nB + 1];

        int rA = csr[eA + q4];
        int rB = csr[eB + q4];

        while ((eA < eEA) & (eB < eEB)) {
            int rA2 = csr[eA + 4 + q4];   // prefetch next groups (csr has slack)
            int rB2 = csr[eB + 4 + q4];
            acc_group<IN_U8>(xg, xsc, rA, l16, aA);
            acc_group<IN_U8>(xg, xsc, rB, l16, aB);
            rA = rA2; rB = rB2; eA += 4; eB += 4;
        }
        while (eA < eEA) {
            acc_group<IN_U8>(xg, xsc, rA, l16, aA);
            eA += 4; rA = csr[eA + q4];
        }
        while (eB < eEB) {
            acc_group<IN_U8>(xg, xsc, rB, l16, aB);
            eB += 4; rB = csr[eB + q4];
        }

        // self terms: one load instruction covers both selves (quarters 0/1)
        const int dgA = deg[nA], dgB = deg[nB];
        const float scoA = 1.f - (float)(((dgA + 3) & ~3) - dgA);
        const float scoB = 1.f - (float)(((dgB + 3) & ~3) - dgB);
        {
            int rs = (q4 & 1) ? nB : nA;
            float v[8];
            load_row8<IN_U8>(xg, rs, l16, v);
            float coA = (q4 == 0) ? scoA : 0.f;
            float coB = (q4 == 1) ? scoB : 0.f;
            if (IN_U8) {
                float s = xsc[rs];
                coA *= s; coB *= s;
            }
#pragma unroll
            for (int j = 0; j < 8; ++j) {
                aA[j] += coA * v[j];
                aB[j] += coB * v[j];
            }
        }

        // combine quarters: lanes l, l^16, l^32, l^48 hold same features
#pragma unroll
        for (int j = 0; j < 8; ++j) {
            aA[j] += __shfl_xor(aA[j], 16);
            aA[j] += __shfl_xor(aA[j], 32);
            aB[j] += __shfl_xor(aB[j], 16);
            aB[j] += __shfl_xor(aB[j], 32);
        }

        // BN-affine + write: lanes 0-15 write row A, lanes 16-31 write row B
        if (q4 < 2) {
            const bool selA = (q4 == 0);
            const float4 s0 = *(const float4*)(scale + (l16 << 3));
            const float4 s1 = *(const float4*)(scale + (l16 << 3) + 4);
            const float4 t0 = *(const float4*)(shift + (l16 << 3));
            const float4 t1 = *(const float4*)(shift + (l16 << 3) + 4);
            const float sarr[8] = {s0.x, s0.y, s0.z, s0.w, s1.x, s1.y, s1.z, s1.w};
            const float tarr[8] = {t0.x, t0.y, t0.z, t0.w, t1.x, t1.y, t1.z, t1.w};
            const int   node = selA ? nA : nB;
            const float cnt = (float)((selA ? dgA : dgB) + 1);
            bf16x8 pk;
#pragma unroll
            for (int j = 0; j < 8; ++j) {
                float av = selA ? aA[j] : aB[j];
                pk[j] = (bf16_t)(av * sarr[j] + cnt * tarr[j]);
            }
            *(bf16x8*)(xt + (size_t)node * DD + (l16 << 3)) = pk;
        }
    }
}

// ---------------- MLP kernel (phases 2-4) ----------------
__global__ __launch_bounds__(128, 8) void k_mlp(
    const bf16_t* __restrict__ xt,
    u8* __restrict__ y8, float* __restrict__ ysc,
    const bf16_t* __restrict__ w1s, const bf16_t* __restrict__ w2s,
    const float* __restrict__ b1, const float* __restrict__ b2,
    float* __restrict__ pstats)
{
    __shared__ __align__(16) bf16_t tile[32 * 136];
    __shared__ float swsum[2][128];
    __shared__ float swsq[2][128];

    const int tid  = threadIdx.x;
    const int w    = tid >> 6;
    const int lane = tid & 63;
    const int base = blockIdx.x * 32;

    const int q = lane >> 4;
    const int c16 = lane & 15;
    const int arow = (w << 4) + c16;

    // ---- Phase 2: GEMM1 + bias + relu -> tile ----
    // A-fragments straight from global xt (coalesced 16B/lane)
    bf16x8 afr[4];
#pragma unroll
    for (int ks = 0; ks < 4; ++ks)
        afr[ks] = *(const bf16x8*)(xt + (size_t)(base + arow) * DD + ks * 32 + q * 8);

    f32x4 acc[8];
#pragma unroll
    for (int nt = 0; nt < 8; ++nt) acc[nt] = (f32x4){0.f, 0.f, 0.f, 0.f};
#pragma unroll
    for (int ks = 0; ks < 4; ++ks) {
#pragma unroll
        for (int nt = 0; nt < 8; ++nt) {
            bf16x8 bfr = *(const bf16x8*)(w1s + (((ks << 3) + nt) * 64 + lane) * 8);
            acc[nt] = __builtin_amdgcn_mfma_f32_16x16x32_bf16(afr[ks], bfr, acc[nt], 0, 0, 0);
        }
    }
#pragma unroll
    for (int nt = 0; nt < 8; ++nt) {
        float bias = b1[(nt << 4) + c16];
#pragma unroll
        for (int i = 0; i < 4; ++i) {
            float v = fmaxf(acc[nt][i] + bias, 0.f);
            int row = (w << 4) + (q << 2) + i;
            tile[row * 136 + (nt << 4) + c16] = (bf16_t)v;
        }
    }
    __syncthreads();

    // ---- Phase 3: GEMM2 + bias + relu + BN partials -> tile ----
    bf16x8 afr2[4];
#pragma unroll
    for (int ks = 0; ks < 4; ++ks)
        afr2[ks] = *(const bf16x8*)(&tile[arow * 136 + ks * 32 + q * 8]);
    __syncthreads(); // tile overwritten below

#pragma unroll
    for (int nt = 0; nt < 8; ++nt) acc[nt] = (f32x4){0.f, 0.f, 0.f, 0.f};
#pragma unroll
    for (int ks = 0; ks < 4; ++ks) {
#pragma unroll
        for (int nt = 0; nt < 8; ++nt) {
            bf16x8 bfr = *(const bf16x8*)(w2s + (((ks << 3) + nt) * 64 + lane) * 8);
            acc[nt] = __builtin_amdgcn_mfma_f32_16x16x32_bf16(afr2[ks], bfr, acc[nt], 0, 0, 0);
        }
    }
#pragma unroll
    for (int nt = 0; nt < 8; ++nt) {
        float bias = b2[(nt << 4) + c16];
        float s1 = 0.f, s2 = 0.f;
#pragma unroll
        for (int i = 0; i < 4; ++i) {
            float v = fmaxf(acc[nt][i] + bias, 0.f);
            int row = (w << 4) + (q << 2) + i;
            s1 += v;
            s2 += v * v;
            tile[row * 136 + (nt << 4) + c16] = (bf16_t)v;
        }
        s1 += __shfl_down(s1, 32); s2 += __shfl_down(s2, 32);
        s1 += __shfl_down(s1, 16); s2 += __shfl_down(s2, 16);
        if (lane < 16) {
            swsum[w][(nt << 4) + lane] = s1;
            swsq[w][(nt << 4) + lane] = s2;
        }
    }
    __syncthreads();

    // per-block partial stats: plain coalesced stores (no atomics)
    {
        float ps = swsum[0][tid & 127] + swsum[1][tid & 127];
        float pq = swsq[0][tid & 127] + swsq[1][tid & 127];
        float* pb = pstats + (size_t)blockIdx.x * 256;
        pb[tid] = ps;          // tid in 0..127
        pb[128 + tid] = pq;
    }

    // ---- Phase 4: quantize rows -> uint8 + scale. 4 threads per row. ----
    {
        int row4 = tid >> 2, t4 = tid & 3;   // rows 0..31
        int node = base + row4;
        const bf16_t* tp = tile + row4 * 136 + t4 * 32;
        bf16x8 v0 = *(const bf16x8*)(tp);
        bf16x8 v1 = *(const bf16x8*)(tp + 8);
        bf16x8 v2 = *(const bf16x8*)(tp + 16);
        bf16x8 v3 = *(const bf16x8*)(tp + 24);
        float am = 0.f;
#pragma unroll
        for (int k = 0; k < 8; ++k) {
            am = fmaxf(am, (float)v0[k]);
            am = fmaxf(am, (float)v1[k]);
            am = fmaxf(am, (float)v2[k]);
            am = fmaxf(am, (float)v3[k]);
        }
        am = fmaxf(am, __shfl_xor(am, 1));
        am = fmaxf(am, __shfl_xor(am, 2));
        float inv = am > 0.f ? 255.f / am : 0.f;
        if (t4 == 0) ysc[node] = am * (1.f / 255.f);
        u32 u[8];
        u[0] = pack4u((float)v0[0], (float)v0[1], (float)v0[2], (float)v0[3], inv);
        u[1] = pack4u((float)v0[4], (float)v0[5], (float)v0[6], (float)v0[7], inv);
        u[2] = pack4u((float)v1[0], (float)v1[1], (float)v1[2], (float)v1[3], inv);
        u[3] = pack4u((float)v1[4], (float)v1[5], (float)v1[6], (float)v1[7], inv);
        u[4] = pack4u((float)v2[0], (float)v2[1], (float)v2[2], (float)v2[3], inv);
        u[5] = pack4u((float)v2[4], (float)v2[5], (float)v2[6], (float)v2[7], inv);
        u[6] = pack4u((float)v3[0], (float)v3[1], (float)v3[2], (float)v3[3], inv);
        u[7] = pack4u((float)v3[4], (float)v3[5], (float)v3[6], (float)v3[7], inv);
        uint4* yp = (uint4*)(y8 + (size_t)node * DD + t4 * 32);
        yp[0] = make_uint4(u[0], u[1], u[2], u[3]);
        yp[1] = make_uint4(u[4], u[5], u[6], u[7]);
    }
}

// ---------------- pooling + head ----------------

// dequantizing segmented mean-pool, 2 nodes in flight per block
__global__ __launch_bounds__(256) void k_pool2u(
    const u8* __restrict__ y8, const float* __restrict__ ysc,
    const int* __restrict__ gstart,
    const float* __restrict__ scale, const float* __restrict__ shift,
    float* __restrict__ pooled)
{
    __shared__ float part[128];
    int g = blockIdx.x;
    int t = threadIdx.x;
    int f = t & 127, h = t >> 7;
    int s = gstart[g], e = gstart[g + 1];
    float acc = 0.f;
    for (int n = s + h; n < e; n += 2)
        acc += ysc[n] * (float)y8[(size_t)n * DD + f];
    if (h == 1) part[f] = acc;
    __syncthreads();
    if (h == 0) {
        acc += part[f];
        float cnt = (float)(e - s);
        float v = acc * scale[f] + cnt * shift[f];
        pooled[g * DD + f] = v / fmaxf(cnt, 1.0f);
    }
}

__global__ void k_head(const float* __restrict__ pooled,
                       const float* __restrict__ lin1w, const float* __restrict__ lin1b,
                       const float* __restrict__ lin2w, const float* __restrict__ lin2b,
                       float* __restrict__ out) {
    __shared__ float p[DD];
    __shared__ float h[DD];
    int g = blockIdx.x;
    int t = threadIdx.x;
    p[t] = pooled[g * DD + t];
    __syncthreads();
    float a = lin1b[t];
    for (int k = 0; k < DD; ++k) a += p[k] * lin1w[k * DD + t];
    h[t] = fmaxf(a, 0.f);
    __syncthreads();
    if (t < 10) {
        float o = lin2b[t];
        for (int k = 0; k < DD; ++k) o += h[k] * lin2w[k * 10 + t];
        out[g * 10 + t] = o;
    }
}

// ---------------- launch ----------------

extern "C" void kernel_launch(void* const* d_in, const int* in_sizes, int n_in,
                              void* d_out, int out_size, void* d_ws, size_t ws_size,
                              hipStream_t stream) {
    const float* x      = (const float*)d_in[0];
    const int*   ei     = (const int*)d_in[1];
    const int*   batch  = (const int*)d_in[2];
    const float* W1s    = (const float*)d_in[3];
    const float* b1s    = (const float*)d_in[4];
    const float* W2s    = (const float*)d_in[5];
    const float* b2s    = (const float*)d_in[6];
    const float* gammas = (const float*)d_in[7];
    const float* betas  = (const float*)d_in[8];
    const float* lin1w  = (const float*)d_in[9];
    const float* lin1b  = (const float*)d_in[10];
    const float* lin2w  = (const float*)d_in[11];
    const float* lin2b  = (const float*)d_in[12];
    float* out = (float*)d_out;

    char* p = (char*)d_ws;
    size_t off = 0;
    auto alloc = [&](size_t bytes) -> char* {
        char* r = p + off;
        off += (bytes + 255) & ~(size_t)255;
        return r;
    };
    int*    deg    = (int*)alloc(N_NODES * 4);
    size_t zero_bytes = off;
    int*    poffs  = (int*)alloc((N_NODES + 1) * 4);
    int*    cursor = (int*)alloc(N_NODES * 4);
    int*    bsum   = (int*)alloc(128 * 4);
    int*    bbase  = (int*)alloc(128 * 4);
    int*    csr    = (int*)alloc(((size_t)N_EDGES + 4 * N_NODES + 64) * 4); // pad-4 + slack
    bf16_t* xb     = (bf16_t*)alloc((size_t)N_NODES * DD * 2);  // bf16 input; q8b aliases it after L0
    u8*     q8a    = (u8*)alloc((size_t)N_NODES * DD);
    float*  sca    = (float*)alloc(N_NODES * 4);
    float*  scb    = (float*)alloc(N_NODES * 4);
    bf16_t* wshuf  = (bf16_t*)alloc(6 * 16384 * 2);
    float*  ss     = (float*)alloc(4 * 256 * 4);
    int*    gstart = (int*)alloc((N_GRAPHS + 1) * 4);
    float*  pooled = (float*)alloc(N_GRAPHS * DD * 4);
    bf16_t* xt     = (bf16_t*)alloc((size_t)N_NODES * DD * 2);   // aggregated rows
    float*  pstats = (float*)alloc((size_t)NTILES * 256 * 4);    // per-block partials
    float*  red    = (float*)alloc(RED_B * 256 * 4);             // stage-2 partials
    if (off > ws_size) return;

    // q8b reuses xb's storage: xb is only read by L0; q8b is written by L1 and
    // read by L2 (stream-ordered on one stream, no overlap). Proven in R10.
    u8* q8b = (u8*)xb;

    const int* srcA = ei;
    const int* dstA = ei + N_EDGES;

    k_zero<<<256, 256, 0, stream>>>((float4*)d_ws, (int)(zero_bytes / 16));
    k_hist8<<<1024, 256, 0, stream>>>(dstA, deg);
    k_scan1<<<SCAN_B, 1024, 0, stream>>>(deg, bsum);
    k_scan2<<<1, 128, 0, stream>>>(bsum, bbase, poffs);
    k_scan3<<<SCAN_B, 1024, 0, stream>>>(deg, bbase, poffs, cursor);
    k_fill8<<<1024, 256, 0, stream>>>(srcA, dstA, cursor, csr);
    k_pad<<<(N_NODES * 4 + 255) / 256, 256, 0, stream>>>(deg, poffs, csr);
    k_cvt<<<1024, 256, 0, stream>>>(x, xb);
    k_shufw<<<(6 * 16384 + 255) / 256, 256, 0, stream>>>(W1s, W2s, wshuf);
    k_aff_init<<<1, 128, 0, stream>>>(ss);
    k_gbounds<<<(N_NODES + 255) / 256, 256, 0, stream>>>(batch, gstart);

    // L0: xb (bf16) -> q8a. L1: q8a -> q8b (aliases xb). L2: q8b -> q8a.
    k_gather<false><<<NTILES, 128, 0, stream>>>(
        xb, q8a, sca, poffs, csr, deg,
        ss + 0 * 256, ss + 0 * 256 + 128, xt);
    k_mlp<<<NTILES, 128, 0, stream>>>(
        xt, q8a, sca,
        wshuf + 0 * 16384, wshuf + 1 * 16384,
        b1s + 0 * DD, b2s + 0 * DD, pstats);
    k_red<<<RED_B, 256, 0, stream>>>(pstats, red);
    k_aff_update<<<1, 128, 0, stream>>>(red, gammas + 0 * DD, betas + 0 * DD,
                                        ss + 1 * 256, ss + 1 * 256 + 128);

    k_gather<true><<<NTILES, 128, 0, stream>>>(
        xb, q8a, sca, poffs, csr, deg,
        ss + 1 * 256, ss + 1 * 256 + 128, xt);
    k_mlp<<<NTILES, 128, 0, stream>>>(
        xt, q8b, scb,
        wshuf + 2 * 16384, wshuf + 3 * 16384,
        b1s + 1 * DD, b2s + 1 * DD, pstats);
    k_red<<<RED_B, 256, 0, stream>>>(pstats, red);
    k_aff_update<<<1, 128, 0, stream>>>(red, gammas + 1 * DD, betas + 1 * DD,
                                        ss + 2 * 256, ss + 2 * 256 + 128);

    k_gather<true><<<NTILES, 128, 0, stream>>>(
        xb, q8b, scb, poffs, csr, deg,
        ss + 2 * 256, ss + 2 * 256 + 128, xt);
    k_mlp<<<NTILES, 128, 0, stream>>>(
        xt, q8a, sca,
        wshuf + 4 * 16384, wshuf + 5 * 16384,
        b1s + 2 * DD, b2s + 2 * DD, pstats);
    k_red<<<RED_B, 256, 0, stream>>>(pstats, red);
    k_aff_update<<<1, 128, 0, stream>>>(red, gammas + 2 * DD, betas + 2 * DD,
                                        ss + 3 * 256, ss + 3 * 256 + 128);

    k_pool2u<<<N_GRAPHS, 256, 0, stream>>>(q8a, sca, gstart,
                                           ss + 3 * 256, ss + 3 * 256 + 128, pooled);
    k_head<<<N_GRAPHS, 128, 0, stream>>>(pooled, lin1w, lin1b, lin2w, lin2b, out);
}

// Round 6
// 599.100 us; speedup vs baseline: 2.0478x; 1.0201x over previous
//
#include <hip/hip_runtime.h>
#include <hip/hip_bf16.h>

#define N_NODES 100000
#define N_EDGES 1600000
#define DD 128
#define N_GRAPHS 512
#define BN_EPS 1e-5f
#define NTILES 3125            // 3125*32 == 100000 exactly: no partial tiles
#define SCAN_B 98              // ceil(100000/1024)
#define RED_B 25               // 3125 = 25 * 125
#define PART_N 12500           // N_NODES / 8 (per-XCD node slice)

typedef unsigned int u32;
typedef unsigned char u8;
typedef __bf16 bf16_t;
typedef __bf16 bf16x2 __attribute__((ext_vector_type(2)));
typedef __bf16 bf16x4 __attribute__((ext_vector_type(4)));
typedef __bf16 bf16x8 __attribute__((ext_vector_type(8)));
typedef float f32x4 __attribute__((ext_vector_type(4)));

__device__ __forceinline__ float bflo2f(u32 u) {
    union { u32 i; float f; } x; x.i = u << 16; return x.f;
}
__device__ __forceinline__ float bfhi2f(u32 u) {
    union { u32 i; float f; } x; x.i = u & 0xffff0000u; return x.f;
}
__device__ __forceinline__ u32 pack4u(float v0, float v1, float v2, float v3, float inv) {
    u32 q0 = (u32)fminf(rintf(v0 * inv), 255.f);
    u32 q1 = (u32)fminf(rintf(v1 * inv), 255.f);
    u32 q2 = (u32)fminf(rintf(v2 * inv), 255.f);
    u32 q3 = (u32)fminf(rintf(v3 * inv), 255.f);
    return q0 | (q1 << 8) | (q2 << 16) | (q3 << 24);
}

// ---------------- utility kernels ----------------

__global__ void k_zero(float4* p, int n) {
    float4 z = make_float4(0.f, 0.f, 0.f, 0.f);
    for (int i = blockIdx.x * blockDim.x + threadIdx.x; i < n; i += gridDim.x * blockDim.x)
        p[i] = z;
}

// R16/R17: XCD-partitioned histogram with NON-TEMPORAL edge reads: the
// streaming dst scan must not evict the deg lines being accumulated in L2.
__global__ void k_hist8(const int* __restrict__ dst, int* __restrict__ deg) {
    const int part = blockIdx.x & 7;
    const int lo = part * PART_N, hi = lo + PART_N;
    const int start = (blockIdx.x >> 3) * blockDim.x + threadIdx.x;
    const int stride = (gridDim.x >> 3) * blockDim.x;
    for (int e = start; e < N_EDGES; e += stride) {
        int d = __builtin_nontemporal_load(dst + e);
        if (d >= lo && d < hi) atomicAdd(&deg[d], 1);
    }
}

// hierarchical scan of padded degrees ((deg+3)&~3) -> poffs, cursor
__global__ void k_scan1(const int* __restrict__ deg, int* __restrict__ bsum) {
    __shared__ int sh[1024];
    int b = blockIdx.x, t = threadIdx.x;
    int i = b * 1024 + t;
    int pd = (i < N_NODES) ? ((deg[i] + 3) & ~3) : 0;
    sh[t] = pd;
    __syncthreads();
    for (int s = 512; s > 0; s >>= 1) {
        if (t < s) sh[t] += sh[t + s];
        __syncthreads();
    }
    if (t == 0) bsum[b] = sh[0];
}
__global__ void k_scan2(const int* __restrict__ bsum, int* __restrict__ bbase,
                        int* __restrict__ poffs) {
    __shared__ int sh[128];
    int t = threadIdx.x;
    int v = (t < SCAN_B) ? bsum[t] : 0;
    sh[t] = v;
    __syncthreads();
    for (int d = 1; d < 128; d <<= 1) {
        int o = (t >= d) ? sh[t - d] : 0;
        __syncthreads();
        sh[t] += o;
        __syncthreads();
    }
    if (t < SCAN_B) bbase[t] = sh[t] - v;          // exclusive base per block
    if (t == SCAN_B - 1) poffs[N_NODES] = sh[t];   // total padded edges
}
__global__ void k_scan3(const int* __restrict__ deg, const int* __restrict__ bbase,
                        int* __restrict__ poffs, int* __restrict__ cursor) {
    __shared__ int sh[1024];
    int b = blockIdx.x, t = threadIdx.x;
    int i = b * 1024 + t;
    int pd = (i < N_NODES) ? ((deg[i] + 3) & ~3) : 0;
    sh[t] = pd;
    __syncthreads();
    for (int d = 1; d < 1024; d <<= 1) {
        int o = (t >= d) ? sh[t - d] : 0;
        __syncthreads();
        sh[t] += o;
        __syncthreads();
    }
    if (i < N_NODES) {
        int off = bbase[b] + sh[t] - pd;
        poffs[i] = off; cursor[i] = off;
    }
}

// R17: XCD-partitioned fill with NON-TEMPORAL dst/src reads. The streaming
// scan (12.8MB/cohort/pass) was evicting partially-filled csr lines from the
// 4MB per-XCD L2 (R16: WRITE_SIZE still 73MB for an 8MB csr). nt loads keep
// the dirty csr/cursor lines resident until all 16 slots accumulate.
__global__ void k_fill8(const int* __restrict__ src, const int* __restrict__ dst,
                        int* __restrict__ cursor, int* __restrict__ csr) {
    const int part = blockIdx.x & 7;
    const int lo = part * PART_N, hi = lo + PART_N;
    const int start = (blockIdx.x >> 3) * blockDim.x + threadIdx.x;
    const int stride = (gridDim.x >> 3) * blockDim.x;
    for (int e = start; e < N_EDGES; e += stride) {
        int d = __builtin_nontemporal_load(dst + e);
        if (d >= lo && d < hi) {
            int s = __builtin_nontemporal_load(src + e);
            int pos = atomicAdd(&cursor[d], 1);
            csr[pos] = s;
        }
    }
}

// fill pad slots with the DEST node's own index; gather subtracts the
// overcount via the self-term coefficient (1 - #pads). Self line is L1-hot.
__global__ void k_pad(const int* __restrict__ deg, const int* __restrict__ poffs,
                      int* __restrict__ csr) {
    int t = blockIdx.x * blockDim.x + threadIdx.x;
    if (t >= N_NODES * 4) return;
    int n = t >> 2, j = t & 3;
    int s = poffs[n] + deg[n];
    if (s + j < poffs[n + 1]) csr[s + j] = n;
}

__global__ void k_cvt(const float* __restrict__ x, bf16_t* __restrict__ xb) {
    const int n4 = N_NODES * DD / 4;
    const float4* x4 = (const float4*)x;
    bf16x4* o4 = (bf16x4*)xb;
    for (int i = blockIdx.x * blockDim.x + threadIdx.x; i < n4; i += gridDim.x * blockDim.x) {
        float4 v = x4[i];
        bf16x4 o;
        o.x = (bf16_t)v.x; o.y = (bf16_t)v.y; o.z = (bf16_t)v.z; o.w = (bf16_t)v.w;
        o4[i] = o;
    }
}

// Pre-shuffle the 6 weight matrices into exact MFMA B-fragment order (bf16).
__global__ void k_shufw(const float* __restrict__ W1s, const float* __restrict__ W2s,
                        bf16_t* __restrict__ wshuf) {
    int t = blockIdx.x * blockDim.x + threadIdx.x;
    if (t >= 6 * 16384) return;
    int g  = t >> 14;
    int r  = t & 16383;
    int j  = r & 7;
    int L  = (r >> 3) & 63;
    int nt = (r >> 9) & 7;
    int ks = r >> 12;
    int l  = g >> 1;
    const float* src = (g & 1) ? (W2s + l * 16384) : (W1s + l * 16384);
    int k = ks * 32 + (L >> 4) * 8 + j;
    int n = nt * 16 + (L & 15);
    wshuf[t] = (bf16_t)src[k * DD + n];
}

__global__ void k_aff_init(float* __restrict__ ss) {
    int f = threadIdx.x;
    if (f < DD) { ss[f] = 1.0f; ss[DD + f] = 0.0f; }
}

// stage-2 reduction of per-block partial stats: 25 blocks x 125 rows
__global__ void k_red(const float* __restrict__ pstats, float* __restrict__ red) {
    int b = blockIdx.x;            // 0..24
    int t = threadIdx.x;           // 0..255
    const float* p = pstats + (size_t)b * 125 * 256 + t;
    float acc = 0.f;
    for (int i = 0; i < 125; ++i) acc += p[i * 256];
    red[b * 256 + t] = acc;
}

__global__ void k_aff_update(const float* __restrict__ red, const float* __restrict__ gamma,
                             const float* __restrict__ beta, float* __restrict__ scale,
                             float* __restrict__ shift) {
    int f = threadIdx.x;
    if (f < DD) {
        float s = 0.f, q = 0.f;
        for (int i = 0; i < RED_B; ++i) {
            s += red[i * 256 + f];
            q += red[i * 256 + 128 + f];
        }
        float mu  = s * (1.0f / N_NODES);
        float var = q * (1.0f / N_NODES) - mu * mu;
        float inv = rsqrtf(var + BN_EPS);
        float sc  = gamma[f] * inv;
        scale[f] = sc;
        shift[f] = beta[f] - mu * sc;
    }
}

__global__ void k_gbounds(const int* __restrict__ batch, int* __restrict__ gstart) {
    int i = blockIdx.x * blockDim.x + threadIdx.x;
    if (i >= N_NODES) return;
    int b = batch[i];
    int bp = (i == 0) ? -1 : batch[i - 1];
    for (int g = bp + 1; g <= b; ++g) gstart[g] = i;
    if (i == N_NODES - 1)
        for (int g = b + 1; g <= N_GRAPHS; ++g) gstart[g] = N_NODES;
}

// ---------------- gather helpers (quarter-split: 4 edges / instruction) ----
// lane = (q4, l16); lane covers features l16*8 .. l16*8+7 of edge csr[e+q4].
// bf16 row: dwordx4 (16B) per lane; u8 row: dwordx2 (8B) per lane.

template<bool IN_U8>
__device__ __forceinline__ void load_row8(
    const u8* __restrict__ xg, int r, int l16, float (&v)[8])
{
    if (IN_U8) {
        uint2 d = *(const uint2*)(xg + ((size_t)r << 7) + (l16 << 3));
        v[0] = (float)(d.x & 0xffu);
        v[1] = (float)((d.x >> 8) & 0xffu);
        v[2] = (float)((d.x >> 16) & 0xffu);
        v[3] = (float)(d.x >> 24);
        v[4] = (float)(d.y & 0xffu);
        v[5] = (float)((d.y >> 8) & 0xffu);
        v[6] = (float)((d.y >> 16) & 0xffu);
        v[7] = (float)(d.y >> 24);
    } else {
        uint4 d = *(const uint4*)(xg + ((size_t)r << 8) + (l16 << 4));
        v[0] = bflo2f(d.x); v[1] = bfhi2f(d.x);
        v[2] = bflo2f(d.y); v[3] = bfhi2f(d.y);
        v[4] = bflo2f(d.z); v[5] = bfhi2f(d.z);
        v[6] = bflo2f(d.w); v[7] = bfhi2f(d.w);
    }
}

template<bool IN_U8>
__device__ __forceinline__ void acc_group(
    const u8* __restrict__ xg, const float* __restrict__ xsc,
    int r, int l16, float (&a)[8])
{
    float v[8];
    load_row8<IN_U8>(xg, r, l16, v);
    if (IN_U8) {
        float s = xsc[r];
#pragma unroll
        for (int j = 0; j < 8; ++j) a[j] += s * v[j];
    } else {
#pragma unroll
        for (int j = 0; j < 8; ++j) a[j] += v[j];
    }
}

// ---------------- fused GIN layer (R17: gather + MLP refused, no atomics) --
// Phase 1 writes aggregated rows to the LDS tile directly (no xt round-trip,
// one launch less per layer). Phases 2-4 as in R15/R16's k_mlp; BN partials
// via plain per-block stores (pstats) + tree reduction.
template<bool IN_U8>
__global__ __launch_bounds__(128, 8) void k_layer(
    const bf16_t* __restrict__ xb,
    const u8* __restrict__ x8, const float* __restrict__ xsc,
    u8* __restrict__ y8, float* __restrict__ ysc,
    const int* __restrict__ poffs, const int* __restrict__ csr,
    const int* __restrict__ deg,
    const float* __restrict__ scale, const float* __restrict__ shift,
    const bf16_t* __restrict__ w1s, const bf16_t* __restrict__ w2s,
    const float* __restrict__ b1, const float* __restrict__ b2,
    float* __restrict__ pstats)
{
    __shared__ __align__(16) bf16_t tile[32 * 136];
    __shared__ float swsum[2][128];
    __shared__ float swsq[2][128];

    const int tid  = threadIdx.x;
    const int w    = tid >> 6;           // 0..1
    const int lane = tid & 63;
    const int base = blockIdx.x * 32;
    const int q4   = lane >> 4;          // quarter: which edge of the group
    const int l16  = lane & 15;          // feature octet within the row

    const u8* xg = IN_U8 ? x8 : (const u8*)xb;

    // ---- Phase 1: dual-node quarter-split gather -> LDS tile ----
    for (int rp = 0; rp < 8; ++rp) {
        const int rowA = (w << 4) + rp;  // rows 0..7 / 16..23
        const int rowB = rowA + 8;       // rows 8..15 / 24..31
        const int nA = base + rowA;
        const int nB = base + rowB;      // always < N_NODES (exact tiling)

        float aA[8] = {0.f, 0.f, 0.f, 0.f, 0.f, 0.f, 0.f, 0.f};
        float aB[8] = {0.f, 0.f, 0.f, 0.f, 0.f, 0.f, 0.f, 0.f};

        int eA = poffs[nA], eEA = poffs[nA + 1];
        int eB = poffs[nB], eEB = poffs[nB + 1];

        int rA = csr[eA + q4];
        int rB = csr[eB + q4];

        while ((eA < eEA) & (eB < eEB)) {
            int rA2 = csr[eA + 4 + q4];   // prefetch next groups (csr has slack)
            int rB2 = csr[eB + 4 + q4];
            acc_group<IN_U8>(xg, xsc, rA, l16, aA);
            acc_group<IN_U8>(xg, xsc, rB, l16, aB);
            rA = rA2; rB = rB2; eA += 4; eB += 4;
        }
        while (eA < eEA) {
            acc_group<IN_U8>(xg, xsc, rA, l16, aA);
            eA += 4; rA = csr[eA + q4];
        }
        while (eB < eEB) {
            acc_group<IN_U8>(xg, xsc, rB, l16, aB);
            eB += 4; rB = csr[eB + q4];
        }

        // self terms: one load instruction covers both selves (quarters 0/1)
        const int dgA = deg[nA], dgB = deg[nB];
        const float scoA = 1.f - (float)(((dgA + 3) & ~3) - dgA);
        const float scoB = 1.f - (float)(((dgB + 3) & ~3) - dgB);
        {
            int rs = (q4 & 1) ? nB : nA;
            float v[8];
            load_row8<IN_U8>(xg, rs, l16, v);
            float coA = (q4 == 0) ? scoA : 0.f;
            float coB = (q4 == 1) ? scoB : 0.f;
            if (IN_U8) {
                float s = xsc[rs];
                coA *= s; coB *= s;
            }
#pragma unroll
            for (int j = 0; j < 8; ++j) {
                aA[j] += coA * v[j];
                aB[j] += coB * v[j];
            }
        }

        // combine quarters: lanes l, l^16, l^32, l^48 hold same features
#pragma unroll
        for (int j = 0; j < 8; ++j) {
            aA[j] += __shfl_xor(aA[j], 16);
            aA[j] += __shfl_xor(aA[j], 32);
            aB[j] += __shfl_xor(aB[j], 16);
            aB[j] += __shfl_xor(aB[j], 32);
        }

        // BN-affine + write: lanes 0-15 write row A, lanes 16-31 write row B
        if (q4 < 2) {
            const bool selA = (q4 == 0);
            const float4 s0 = *(const float4*)(scale + (l16 << 3));
            const float4 s1 = *(const float4*)(scale + (l16 << 3) + 4);
            const float4 t0 = *(const float4*)(shift + (l16 << 3));
            const float4 t1 = *(const float4*)(shift + (l16 << 3) + 4);
            const float sarr[8] = {s0.x, s0.y, s0.z, s0.w, s1.x, s1.y, s1.z, s1.w};
            const float tarr[8] = {t0.x, t0.y, t0.z, t0.w, t1.x, t1.y, t1.z, t1.w};
            const float cnt = (float)((selA ? dgA : dgB) + 1);
            const int   row = selA ? rowA : rowB;
            bf16x8 pk;
#pragma unroll
            for (int j = 0; j < 8; ++j) {
                float av = selA ? aA[j] : aB[j];
                pk[j] = (bf16_t)(av * sarr[j] + cnt * tarr[j]);
            }
            *(bf16x8*)(&tile[row * 136 + (l16 << 3)]) = pk;
        }
    }
    __syncthreads();

    // ---- Phase 2: GEMM1 + bias + relu -> tile (reused) ----
    const int q = lane >> 4;
    const int c16 = lane & 15;
    const int arow = (w << 4) + c16;

    bf16x8 afr[4];
#pragma unroll
    for (int ks = 0; ks < 4; ++ks)
        afr[ks] = *(const bf16x8*)(&tile[arow * 136 + ks * 32 + q * 8]);
    __syncthreads();

    f32x4 acc[8];
#pragma unroll
    for (int nt = 0; nt < 8; ++nt) acc[nt] = (f32x4){0.f, 0.f, 0.f, 0.f};
#pragma unroll
    for (int ks = 0; ks < 4; ++ks) {
#pragma unroll
        for (int nt = 0; nt < 8; ++nt) {
            bf16x8 bfr = *(const bf16x8*)(w1s + (((ks << 3) + nt) * 64 + lane) * 8);
            acc[nt] = __builtin_amdgcn_mfma_f32_16x16x32_bf16(afr[ks], bfr, acc[nt], 0, 0, 0);
        }
    }
#pragma unroll
    for (int nt = 0; nt < 8; ++nt) {
        float bias = b1[(nt << 4) + c16];
#pragma unroll
        for (int i = 0; i < 4; ++i) {
            float v = fmaxf(acc[nt][i] + bias, 0.f);
            int row = (w << 4) + (q << 2) + i;
            tile[row * 136 + (nt << 4) + c16] = (bf16_t)v;
        }
    }
    __syncthreads();

    // ---- Phase 3: GEMM2 + bias + relu + BN partials -> tile ----
    bf16x8 afr2[4];
#pragma unroll
    for (int ks = 0; ks < 4; ++ks)
        afr2[ks] = *(const bf16x8*)(&tile[arow * 136 + ks * 32 + q * 8]);
    __syncthreads(); // tile overwritten below

#pragma unroll
    for (int nt = 0; nt < 8; ++nt) acc[nt] = (f32x4){0.f, 0.f, 0.f, 0.f};
#pragma unroll
    for (int ks = 0; ks < 4; ++ks) {
#pragma unroll
        for (int nt = 0; nt < 8; ++nt) {
            bf16x8 bfr = *(const bf16x8*)(w2s + (((ks << 3) + nt) * 64 + lane) * 8);
            acc[nt] = __builtin_amdgcn_mfma_f32_16x16x32_bf16(afr2[ks], bfr, acc[nt], 0, 0, 0);
        }
    }
#pragma unroll
    for (int nt = 0; nt < 8; ++nt) {
        float bias = b2[(nt << 4) + c16];
        float s1 = 0.f, s2 = 0.f;
#pragma unroll
        for (int i = 0; i < 4; ++i) {
            float v = fmaxf(acc[nt][i] + bias, 0.f);
            int row = (w << 4) + (q << 2) + i;
            s1 += v;
            s2 += v * v;
            tile[row * 136 + (nt << 4) + c16] = (bf16_t)v;
        }
        s1 += __shfl_down(s1, 32); s2 += __shfl_down(s2, 32);
        s1 += __shfl_down(s1, 16); s2 += __shfl_down(s2, 16);
        if (lane < 16) {
            swsum[w][(nt << 4) + lane] = s1;
            swsq[w][(nt << 4) + lane] = s2;
        }
    }
    __syncthreads();

    // per-block partial stats: plain coalesced stores (no atomics)
    {
        float ps = swsum[0][tid & 127] + swsum[1][tid & 127];
        float pq = swsq[0][tid & 127] + swsq[1][tid & 127];
        float* pb = pstats + (size_t)blockIdx.x * 256;
        pb[tid] = ps;          // tid in 0..127
        pb[128 + tid] = pq;
    }

    // ---- Phase 4: quantize rows -> uint8 + scale. 4 threads per row. ----
    {
        int row4 = tid >> 2, t4 = tid & 3;   // rows 0..31
        int node = base + row4;
        const bf16_t* tp = tile + row4 * 136 + t4 * 32;
        bf16x8 v0 = *(const bf16x8*)(tp);
        bf16x8 v1 = *(const bf16x8*)(tp + 8);
        bf16x8 v2 = *(const bf16x8*)(tp + 16);
        bf16x8 v3 = *(const bf16x8*)(tp + 24);
        float am = 0.f;
#pragma unroll
        for (int k = 0; k < 8; ++k) {
            am = fmaxf(am, (float)v0[k]);
            am = fmaxf(am, (float)v1[k]);
            am = fmaxf(am, (float)v2[k]);
            am = fmaxf(am, (float)v3[k]);
        }
        am = fmaxf(am, __shfl_xor(am, 1));
        am = fmaxf(am, __shfl_xor(am, 2));
        float inv = am > 0.f ? 255.f / am : 0.f;
        if (t4 == 0) ysc[node] = am * (1.f / 255.f);
        u32 u[8];
        u[0] = pack4u((float)v0[0], (float)v0[1], (float)v0[2], (float)v0[3], inv);
        u[1] = pack4u((float)v0[4], (float)v0[5], (float)v0[6], (float)v0[7], inv);
        u[2] = pack4u((float)v1[0], (float)v1[1], (float)v1[2], (float)v1[3], inv);
        u[3] = pack4u((float)v1[4], (float)v1[5], (float)v1[6], (float)v1[7], inv);
        u[4] = pack4u((float)v2[0], (float)v2[1], (float)v2[2], (float)v2[3], inv);
        u[5] = pack4u((float)v2[4], (float)v2[5], (float)v2[6], (float)v2[7], inv);
        u[6] = pack4u((float)v3[0], (float)v3[1], (float)v3[2], (float)v3[3], inv);
        u[7] = pack4u((float)v3[4], (float)v3[5], (float)v3[6], (float)v3[7], inv);
        uint4* yp = (uint4*)(y8 + (size_t)node * DD + t4 * 32);
        yp[0] = make_uint4(u[0], u[1], u[2], u[3]);
        yp[1] = make_uint4(u[4], u[5], u[6], u[7]);
    }
}

// ---------------- pooling + head ----------------

// dequantizing segmented mean-pool, 2 nodes in flight per block
__global__ __launch_bounds__(256) void k_pool2u(
    const u8* __restrict__ y8, const float* __restrict__ ysc,
    const int* __restrict__ gstart,
    const float* __restrict__ scale, const float* __restrict__ shift,
    float* __restrict__ pooled)
{
    __shared__ float part[128];
    int g = blockIdx.x;
    int t = threadIdx.x;
    int f = t & 127, h = t >> 7;
    int s = gstart[g], e = gstart[g + 1];
    float acc = 0.f;
    for (int n = s + h; n < e; n += 2)
        acc += ysc[n] * (float)y8[(size_t)n * DD + f];
    if (h == 1) part[f] = acc;
    __syncthreads();
    if (h == 0) {
        acc += part[f];
        float cnt = (float)(e - s);
        float v = acc * scale[f] + cnt * shift[f];
        pooled[g * DD + f] = v / fmaxf(cnt, 1.0f);
    }
}

__global__ void k_head(const float* __restrict__ pooled,
                       const float* __restrict__ lin1w, const float* __restrict__ lin1b,
                       const float* __restrict__ lin2w, const float* __restrict__ lin2b,
                       float* __restrict__ out) {
    __shared__ float p[DD];
    __shared__ float h[DD];
    int g = blockIdx.x;
    int t = threadIdx.x;
    p[t] = pooled[g * DD + t];
    __syncthreads();
    float a = lin1b[t];
    for (int k = 0; k < DD; ++k) a += p[k] * lin1w[k * DD + t];
    h[t] = fmaxf(a, 0.f);
    __syncthreads();
    if (t < 10) {
        float o = lin2b[t];
        for (int k = 0; k < DD; ++k) o += h[k] * lin2w[k * 10 + t];
        out[g * 10 + t] = o;
    }
}

// ---------------- launch ----------------

extern "C" void kernel_launch(void* const* d_in, const int* in_sizes, int n_in,
                              void* d_out, int out_size, void* d_ws, size_t ws_size,
                              hipStream_t stream) {
    const float* x      = (const float*)d_in[0];
    const int*   ei     = (const int*)d_in[1];
    const int*   batch  = (const int*)d_in[2];
    const float* W1s    = (const float*)d_in[3];
    const float* b1s    = (const float*)d_in[4];
    const float* W2s    = (const float*)d_in[5];
    const float* b2s    = (const float*)d_in[6];
    const float* gammas = (const float*)d_in[7];
    const float* betas  = (const float*)d_in[8];
    const float* lin1w  = (const float*)d_in[9];
    const float* lin1b  = (const float*)d_in[10];
    const float* lin2w  = (const float*)d_in[11];
    const float* lin2b  = (const float*)d_in[12];
    float* out = (float*)d_out;

    char* p = (char*)d_ws;
    size_t off = 0;
    auto alloc = [&](size_t bytes) -> char* {
        char* r = p + off;
        off += (bytes + 255) & ~(size_t)255;
        return r;
    };
    int*    deg    = (int*)alloc(N_NODES * 4);
    size_t zero_bytes = off;
    int*    poffs  = (int*)alloc((N_NODES + 1) * 4);
    int*    cursor = (int*)alloc(N_NODES * 4);
    int*    bsum   = (int*)alloc(128 * 4);
    int*    bbase  = (int*)alloc(128 * 4);
    int*    csr    = (int*)alloc(((size_t)N_EDGES + 4 * N_NODES + 64) * 4); // pad-4 + slack
    bf16_t* xb     = (bf16_t*)alloc((size_t)N_NODES * DD * 2);  // bf16 input; q8b aliases it after L0
    u8*     q8a    = (u8*)alloc((size_t)N_NODES * DD);
    float*  sca    = (float*)alloc(N_NODES * 4);
    float*  scb    = (float*)alloc(N_NODES * 4);
    bf16_t* wshuf  = (bf16_t*)alloc(6 * 16384 * 2);
    float*  ss     = (float*)alloc(4 * 256 * 4);
    int*    gstart = (int*)alloc((N_GRAPHS + 1) * 4);
    float*  pooled = (float*)alloc(N_GRAPHS * DD * 4);
    float*  pstats = (float*)alloc((size_t)NTILES * 256 * 4);    // per-block partials
    float*  red    = (float*)alloc(RED_B * 256 * 4);             // stage-2 partials
    if (off > ws_size) return;

    // q8b reuses xb's storage: xb is only read by L0; q8b is written by L1 and
    // read by L2 (stream-ordered on one stream, no overlap). Proven in R10.
    u8* q8b = (u8*)xb;

    const int* srcA = ei;
    const int* dstA = ei + N_EDGES;

    k_zero<<<256, 256, 0, stream>>>((float4*)d_ws, (int)(zero_bytes / 16));
    k_hist8<<<1024, 256, 0, stream>>>(dstA, deg);
    k_scan1<<<SCAN_B, 1024, 0, stream>>>(deg, bsum);
    k_scan2<<<1, 128, 0, stream>>>(bsum, bbase, poffs);
    k_scan3<<<SCAN_B, 1024, 0, stream>>>(deg, bbase, poffs, cursor);
    k_fill8<<<1024, 256, 0, stream>>>(srcA, dstA, cursor, csr);
    k_pad<<<(N_NODES * 4 + 255) / 256, 256, 0, stream>>>(deg, poffs, csr);
    k_cvt<<<1024, 256, 0, stream>>>(x, xb);
    k_shufw<<<(6 * 16384 + 255) / 256, 256, 0, stream>>>(W1s, W2s, wshuf);
    k_aff_init<<<1, 128, 0, stream>>>(ss);
    k_gbounds<<<(N_NODES + 255) / 256, 256, 0, stream>>>(batch, gstart);

    // L0: xb (bf16) -> q8a. L1: q8a -> q8b (aliases xb). L2: q8b -> q8a.
    k_layer<false><<<NTILES, 128, 0, stream>>>(
        xb, q8a, sca, q8a, sca, poffs, csr, deg,
        ss + 0 * 256, ss + 0 * 256 + 128,
        wshuf + 0 * 16384, wshuf + 1 * 16384,
        b1s + 0 * DD, b2s + 0 * DD, pstats);
    k_red<<<RED_B, 256, 0, stream>>>(pstats, red);
    k_aff_update<<<1, 128, 0, stream>>>(red, gammas + 0 * DD, betas + 0 * DD,
                                        ss + 1 * 256, ss + 1 * 256 + 128);

    k_layer<true><<<NTILES, 128, 0, stream>>>(
        xb, q8a, sca, q8b, scb, poffs, csr, deg,
        ss + 1 * 256, ss + 1 * 256 + 128,
        wshuf + 2 * 16384, wshuf + 3 * 16384,
        b1s + 1 * DD, b2s + 1 * DD, pstats);
    k_red<<<RED_B, 256, 0, stream>>>(pstats, red);
    k_aff_update<<<1, 128, 0, stream>>>(red, gammas + 1 * DD, betas + 1 * DD,
                                        ss + 2 * 256, ss + 2 * 256 + 128);

    k_layer<true><<<NTILES, 128, 0, stream>>>(
        xb, q8b, scb, q8a, sca, poffs, csr, deg,
        ss + 2 * 256, ss + 2 * 256 + 128,
        wshuf + 4 * 16384, wshuf + 5 * 16384,
        b1s + 2 * DD, b2s + 2 * DD, pstats);
    k_red<<<RED_B, 256, 0, stream>>>(pstats, red);
    k_aff_update<<<1, 128, 0, stream>>>(red, gammas + 2 * DD, betas + 2 * DD,
                                        ss + 3 * 256, ss + 3 * 256 + 128);

    k_pool2u<<<N_GRAPHS, 256, 0, stream>>>(q8a, sca, gstart,
                                           ss + 3 * 256, ss + 3 * 256 + 128, pooled);
    k_head<<<N_GRAPHS, 128, 0, stream>>>(pooled, lin1w, lin1b, lin2w, lin2b, out);
}

// Round 7
// 596.862 us; speedup vs baseline: 2.0554x; 1.0037x over previous
//
#include <hip/hip_runtime.h>
#include <hip/hip_bf16.h>

#define N_NODES 100000
#define N_EDGES 1600000
#define DD 128
#define N_GRAPHS 512
#define BN_EPS 1e-5f
#define NTILES 3125            // 3125*32 == 100000 exactly: no partial tiles
#define SCAN_B 98              // ceil(100000/1024)
#define RED_B 25               // 3125 = 25 * 125
#define PART_N 12500           // N_NODES / 8 (per-XCD node slice)

typedef unsigned int u32;
typedef unsigned char u8;
typedef __bf16 bf16_t;
typedef __bf16 bf16x2 __attribute__((ext_vector_type(2)));
typedef __bf16 bf16x4 __attribute__((ext_vector_type(4)));
typedef __bf16 bf16x8 __attribute__((ext_vector_type(8)));
typedef float f32x4 __attribute__((ext_vector_type(4)));

__device__ __forceinline__ u32 pack4u(float v0, float v1, float v2, float v3, float inv) {
    u32 q0 = (u32)fminf(rintf(v0 * inv), 255.f);
    u32 q1 = (u32)fminf(rintf(v1 * inv), 255.f);
    u32 q2 = (u32)fminf(rintf(v2 * inv), 255.f);
    u32 q3 = (u32)fminf(rintf(v3 * inv), 255.f);
    return q0 | (q1 << 8) | (q2 << 16) | (q3 << 24);
}

// ---------------- utility kernels ----------------

__global__ void k_zero(float4* p, int n) {
    float4 z = make_float4(0.f, 0.f, 0.f, 0.f);
    for (int i = blockIdx.x * blockDim.x + threadIdx.x; i < n; i += gridDim.x * blockDim.x)
        p[i] = z;
}

// R16/R17: XCD-partitioned histogram with NON-TEMPORAL edge reads: the
// streaming dst scan must not evict the deg lines being accumulated in L2.
__global__ void k_hist8(const int* __restrict__ dst, int* __restrict__ deg) {
    const int part = blockIdx.x & 7;
    const int lo = part * PART_N, hi = lo + PART_N;
    const int start = (blockIdx.x >> 3) * blockDim.x + threadIdx.x;
    const int stride = (gridDim.x >> 3) * blockDim.x;
    for (int e = start; e < N_EDGES; e += stride) {
        int d = __builtin_nontemporal_load(dst + e);
        if (d >= lo && d < hi) atomicAdd(&deg[d], 1);
    }
}

// hierarchical scan of padded degrees ((deg+3)&~3) -> poffs, cursor
__global__ void k_scan1(const int* __restrict__ deg, int* __restrict__ bsum) {
    __shared__ int sh[1024];
    int b = blockIdx.x, t = threadIdx.x;
    int i = b * 1024 + t;
    int pd = (i < N_NODES) ? ((deg[i] + 3) & ~3) : 0;
    sh[t] = pd;
    __syncthreads();
    for (int s = 512; s > 0; s >>= 1) {
        if (t < s) sh[t] += sh[t + s];
        __syncthreads();
    }
    if (t == 0) bsum[b] = sh[0];
}
__global__ void k_scan2(const int* __restrict__ bsum, int* __restrict__ bbase,
                        int* __restrict__ poffs) {
    __shared__ int sh[128];
    int t = threadIdx.x;
    int v = (t < SCAN_B) ? bsum[t] : 0;
    sh[t] = v;
    __syncthreads();
    for (int d = 1; d < 128; d <<= 1) {
        int o = (t >= d) ? sh[t - d] : 0;
        __syncthreads();
        sh[t] += o;
        __syncthreads();
    }
    if (t < SCAN_B) bbase[t] = sh[t] - v;          // exclusive base per block
    if (t == SCAN_B - 1) poffs[N_NODES] = sh[t];   // total padded edges
}
__global__ void k_scan3(const int* __restrict__ deg, const int* __restrict__ bbase,
                        int* __restrict__ poffs, int* __restrict__ cursor) {
    __shared__ int sh[1024];
    int b = blockIdx.x, t = threadIdx.x;
    int i = b * 1024 + t;
    int pd = (i < N_NODES) ? ((deg[i] + 3) & ~3) : 0;
    sh[t] = pd;
    __syncthreads();
    for (int d = 1; d < 1024; d <<= 1) {
        int o = (t >= d) ? sh[t - d] : 0;
        __syncthreads();
        sh[t] += o;
        __syncthreads();
    }
    if (i < N_NODES) {
        int off = bbase[b] + sh[t] - pd;
        poffs[i] = off; cursor[i] = off;
    }
}

// R17: XCD-partitioned fill with NON-TEMPORAL dst/src reads. The streaming
// scan must not evict partially-filled csr lines from the 4MB per-XCD L2.
__global__ void k_fill8(const int* __restrict__ src, const int* __restrict__ dst,
                        int* __restrict__ cursor, int* __restrict__ csr) {
    const int part = blockIdx.x & 7;
    const int lo = part * PART_N, hi = lo + PART_N;
    const int start = (blockIdx.x >> 3) * blockDim.x + threadIdx.x;
    const int stride = (gridDim.x >> 3) * blockDim.x;
    for (int e = start; e < N_EDGES; e += stride) {
        int d = __builtin_nontemporal_load(dst + e);
        if (d >= lo && d < hi) {
            int s = __builtin_nontemporal_load(src + e);
            int pos = atomicAdd(&cursor[d], 1);
            csr[pos] = s;
        }
    }
}

// fill pad slots with the DEST node's own index; gather subtracts the
// overcount via the self-term coefficient (1 - #pads). Self line is L1-hot.
__global__ void k_pad(const int* __restrict__ deg, const int* __restrict__ poffs,
                      int* __restrict__ csr) {
    int t = blockIdx.x * blockDim.x + threadIdx.x;
    if (t >= N_NODES * 4) return;
    int n = t >> 2, j = t & 3;
    int s = poffs[n] + deg[n];
    if (s + j < poffs[n + 1]) csr[s + j] = n;
}

// R18: quantize the fp32 input to SIGNED i8 with per-row scale (127 levels).
// All three layers then gather 128B rows (L0 was the last 256B-row gather:
// FETCH 210MB = 8 XCDs x whole 25.6MB bf16 array; i8 halves it).
// One wave per row: lane covers features (2*lane, 2*lane+1).
__global__ __launch_bounds__(256) void k_cvt8(const float* __restrict__ x,
                                              u8* __restrict__ x8,
                                              float* __restrict__ xsc) {
    int wid  = (blockIdx.x * blockDim.x + threadIdx.x) >> 6;
    int lane = threadIdx.x & 63;
    int nw   = (gridDim.x * blockDim.x) >> 6;
    for (int row = wid; row < N_NODES; row += nw) {
        float2 v = *(const float2*)(x + (size_t)row * DD + lane * 2);
        float am = fmaxf(fabsf(v.x), fabsf(v.y));
#pragma unroll
        for (int o = 32; o > 0; o >>= 1) am = fmaxf(am, __shfl_xor(am, o));
        float inv = am > 0.f ? 127.f / am : 0.f;
        int q0 = (int)rintf(fminf(fmaxf(v.x * inv, -127.f), 127.f));
        int q1 = (int)rintf(fminf(fmaxf(v.y * inv, -127.f), 127.f));
        u32 pk = ((u32)(q0 & 0xff)) | (((u32)(q1 & 0xff)) << 8);
        *(unsigned short*)(x8 + (size_t)row * DD + lane * 2) = (unsigned short)pk;
        if (lane == 0) xsc[row] = am * (1.f / 127.f);
    }
}

// Pre-shuffle the 6 weight matrices into exact MFMA B-fragment order (bf16).
__global__ void k_shufw(const float* __restrict__ W1s, const float* __restrict__ W2s,
                        bf16_t* __restrict__ wshuf) {
    int t = blockIdx.x * blockDim.x + threadIdx.x;
    if (t >= 6 * 16384) return;
    int g  = t >> 14;
    int r  = t & 16383;
    int j  = r & 7;
    int L  = (r >> 3) & 63;
    int nt = (r >> 9) & 7;
    int ks = r >> 12;
    int l  = g >> 1;
    const float* src = (g & 1) ? (W2s + l * 16384) : (W1s + l * 16384);
    int k = ks * 32 + (L >> 4) * 8 + j;
    int n = nt * 16 + (L & 15);
    wshuf[t] = (bf16_t)src[k * DD + n];
}

__global__ void k_aff_init(float* __restrict__ ss) {
    int f = threadIdx.x;
    if (f < DD) { ss[f] = 1.0f; ss[DD + f] = 0.0f; }
}

// stage-2 reduction of per-block partial stats: 25 blocks x 125 rows
__global__ void k_red(const float* __restrict__ pstats, float* __restrict__ red) {
    int b = blockIdx.x;            // 0..24
    int t = threadIdx.x;           // 0..255
    const float* p = pstats + (size_t)b * 125 * 256 + t;
    float acc = 0.f;
    for (int i = 0; i < 125; ++i) acc += p[i * 256];
    red[b * 256 + t] = acc;
}

__global__ void k_aff_update(const float* __restrict__ red, const float* __restrict__ gamma,
                             const float* __restrict__ beta, float* __restrict__ scale,
                             float* __restrict__ shift) {
    int f = threadIdx.x;
    if (f < DD) {
        float s = 0.f, q = 0.f;
        for (int i = 0; i < RED_B; ++i) {
            s += red[i * 256 + f];
            q += red[i * 256 + 128 + f];
        }
        float mu  = s * (1.0f / N_NODES);
        float var = q * (1.0f / N_NODES) - mu * mu;
        float inv = rsqrtf(var + BN_EPS);
        float sc  = gamma[f] * inv;
        scale[f] = sc;
        shift[f] = beta[f] - mu * sc;
    }
}

__global__ void k_gbounds(const int* __restrict__ batch, int* __restrict__ gstart) {
    int i = blockIdx.x * blockDim.x + threadIdx.x;
    if (i >= N_NODES) return;
    int b = batch[i];
    int bp = (i == 0) ? -1 : batch[i - 1];
    for (int g = bp + 1; g <= b; ++g) gstart[g] = i;
    if (i == N_NODES - 1)
        for (int g = b + 1; g <= N_GRAPHS; ++g) gstart[g] = N_NODES;
}

// ---------------- gather helpers (quarter-split: 4 edges / instruction) ----
// lane = (q4, l16); lane covers features l16*8 .. l16*8+7 of edge csr[e+q4].
// All rows are 128B quantized (i8 input for L0, u8 activations for L1/L2):
// uint2 (8B) per lane. SIGNED selects sign-extension on decode.

template<bool SIGNED>
__device__ __forceinline__ void load_row8(
    const u8* __restrict__ xg, int r, int l16, float (&v)[8])
{
    uint2 d = *(const uint2*)(xg + ((size_t)r << 7) + (l16 << 3));
    if (SIGNED) {
        v[0] = (float)(int)(signed char)(d.x & 0xffu);
        v[1] = (float)(int)(signed char)((d.x >> 8) & 0xffu);
        v[2] = (float)(int)(signed char)((d.x >> 16) & 0xffu);
        v[3] = (float)(int)(signed char)(d.x >> 24);
        v[4] = (float)(int)(signed char)(d.y & 0xffu);
        v[5] = (float)(int)(signed char)((d.y >> 8) & 0xffu);
        v[6] = (float)(int)(signed char)((d.y >> 16) & 0xffu);
        v[7] = (float)(int)(signed char)(d.y >> 24);
    } else {
        v[0] = (float)(d.x & 0xffu);
        v[1] = (float)((d.x >> 8) & 0xffu);
        v[2] = (float)((d.x >> 16) & 0xffu);
        v[3] = (float)(d.x >> 24);
        v[4] = (float)(d.y & 0xffu);
        v[5] = (float)((d.y >> 8) & 0xffu);
        v[6] = (float)((d.y >> 16) & 0xffu);
        v[7] = (float)(d.y >> 24);
    }
}

template<bool SIGNED>
__device__ __forceinline__ void acc_group(
    const u8* __restrict__ xg, const float* __restrict__ xsc,
    int r, int l16, float (&a)[8])
{
    float v[8];
    load_row8<SIGNED>(xg, r, l16, v);
    float s = xsc[r];
#pragma unroll
    for (int j = 0; j < 8; ++j) a[j] += s * v[j];
}

// ---------------- fused GIN layer ----------------
// R18: single quantized gather path (i8 for L0, u8 for L1/L2), 128B rows.
// Phases 2-4 unchanged; BN partials via plain per-block stores + reduction.
template<bool SIGNED>
__global__ __launch_bounds__(128, 8) void k_layer(
    const u8* __restrict__ x8, const float* __restrict__ xsc,
    u8* __restrict__ y8, float* __restrict__ ysc,
    const int* __restrict__ poffs, const int* __restrict__ csr,
    const int* __restrict__ deg,
    const float* __restrict__ scale, const float* __restrict__ shift,
    const bf16_t* __restrict__ w1s, const bf16_t* __restrict__ w2s,
    const float* __restrict__ b1, const float* __restrict__ b2,
    float* __restrict__ pstats)
{
    __shared__ __align__(16) bf16_t tile[32 * 136];
    __shared__ float swsum[2][128];
    __shared__ float swsq[2][128];

    const int tid  = threadIdx.x;
    const int w    = tid >> 6;           // 0..1
    const int lane = tid & 63;
    const int base = blockIdx.x * 32;
    const int q4   = lane >> 4;          // quarter: which edge of the group
    const int l16  = lane & 15;          // feature octet within the row

    // ---- Phase 1: dual-node quarter-split gather -> LDS tile ----
    for (int rp = 0; rp < 8; ++rp) {
        const int rowA = (w << 4) + rp;  // rows 0..7 / 16..23
        const int rowB = rowA + 8;       // rows 8..15 / 24..31
        const int nA = base + rowA;
        const int nB = base + rowB;      // always < N_NODES (exact tiling)

        float aA[8] = {0.f, 0.f, 0.f, 0.f, 0.f, 0.f, 0.f, 0.f};
        float aB[8] = {0.f, 0.f, 0.f, 0.f, 0.f, 0.f, 0.f, 0.f};

        int eA = poffs[nA], eEA = poffs[nA + 1];
        int eB = poffs[nB], eEB = poffs[nB + 1];

        int rA = csr[eA + q4];
        int rB = csr[eB + q4];

        while ((eA < eEA) & (eB < eEB)) {
            int rA2 = csr[eA + 4 + q4];   // prefetch next groups (csr has slack)
            int rB2 = csr[eB + 4 + q4];
            acc_group<SIGNED>(x8, xsc, rA, l16, aA);
            acc_group<SIGNED>(x8, xsc, rB, l16, aB);
            rA = rA2; rB = rB2; eA += 4; eB += 4;
        }
        while (eA < eEA) {
            acc_group<SIGNED>(x8, xsc, rA, l16, aA);
            eA += 4; rA = csr[eA + q4];
        }
        while (eB < eEB) {
            acc_group<SIGNED>(x8, xsc, rB, l16, aB);
            eB += 4; rB = csr[eB + q4];
        }

        // self terms: one load instruction covers both selves (quarters 0/1)
        const int dgA = deg[nA], dgB = deg[nB];
        const float scoA = 1.f - (float)(((dgA + 3) & ~3) - dgA);
        const float scoB = 1.f - (float)(((dgB + 3) & ~3) - dgB);
        {
            int rs = (q4 & 1) ? nB : nA;
            float v[8];
            load_row8<SIGNED>(x8, rs, l16, v);
            float s = xsc[rs];
            float coA = (q4 == 0) ? scoA * s : 0.f;
            float coB = (q4 == 1) ? scoB * s : 0.f;
#pragma unroll
            for (int j = 0; j < 8; ++j) {
                aA[j] += coA * v[j];
                aB[j] += coB * v[j];
            }
        }

        // combine quarters: lanes l, l^16, l^32, l^48 hold same features
#pragma unroll
        for (int j = 0; j < 8; ++j) {
            aA[j] += __shfl_xor(aA[j], 16);
            aA[j] += __shfl_xor(aA[j], 32);
            aB[j] += __shfl_xor(aB[j], 16);
            aB[j] += __shfl_xor(aB[j], 32);
        }

        // BN-affine + write: lanes 0-15 write row A, lanes 16-31 write row B
        if (q4 < 2) {
            const bool selA = (q4 == 0);
            const float4 s0 = *(const float4*)(scale + (l16 << 3));
            const float4 s1 = *(const float4*)(scale + (l16 << 3) + 4);
            const float4 t0 = *(const float4*)(shift + (l16 << 3));
            const float4 t1 = *(const float4*)(shift + (l16 << 3) + 4);
            const float sarr[8] = {s0.x, s0.y, s0.z, s0.w, s1.x, s1.y, s1.z, s1.w};
            const float tarr[8] = {t0.x, t0.y, t0.z, t0.w, t1.x, t1.y, t1.z, t1.w};
            const float cnt = (float)((selA ? dgA : dgB) + 1);
            const int   row = selA ? rowA : rowB;
            bf16x8 pk;
#pragma unroll
            for (int j = 0; j < 8; ++j) {
                float av = selA ? aA[j] : aB[j];
                pk[j] = (bf16_t)(av * sarr[j] + cnt * tarr[j]);
            }
            *(bf16x8*)(&tile[row * 136 + (l16 << 3)]) = pk;
        }
    }
    __syncthreads();

    // ---- Phase 2: GEMM1 + bias + relu -> tile (reused) ----
    const int q = lane >> 4;
    const int c16 = lane & 15;
    const int arow = (w << 4) + c16;

    bf16x8 afr[4];
#pragma unroll
    for (int ks = 0; ks < 4; ++ks)
        afr[ks] = *(const bf16x8*)(&tile[arow * 136 + ks * 32 + q * 8]);
    __syncthreads();

    f32x4 acc[8];
#pragma unroll
    for (int nt = 0; nt < 8; ++nt) acc[nt] = (f32x4){0.f, 0.f, 0.f, 0.f};
#pragma unroll
    for (int ks = 0; ks < 4; ++ks) {
#pragma unroll
        for (int nt = 0; nt < 8; ++nt) {
            bf16x8 bfr = *(const bf16x8*)(w1s + (((ks << 3) + nt) * 64 + lane) * 8);
            acc[nt] = __builtin_amdgcn_mfma_f32_16x16x32_bf16(afr[ks], bfr, acc[nt], 0, 0, 0);
        }
    }
#pragma unroll
    for (int nt = 0; nt < 8; ++nt) {
        float bias = b1[(nt << 4) + c16];
#pragma unroll
        for (int i = 0; i < 4; ++i) {
            float v = fmaxf(acc[nt][i] + bias, 0.f);
            int row = (w << 4) + (q << 2) + i;
            tile[row * 136 + (nt << 4) + c16] = (bf16_t)v;
        }
    }
    __syncthreads();

    // ---- Phase 3: GEMM2 + bias + relu + BN partials -> tile ----
    bf16x8 afr2[4];
#pragma unroll
    for (int ks = 0; ks < 4; ++ks)
        afr2[ks] = *(const bf16x8*)(&tile[arow * 136 + ks * 32 + q * 8]);
    __syncthreads(); // tile overwritten below

#pragma unroll
    for (int nt = 0; nt < 8; ++nt) acc[nt] = (f32x4){0.f, 0.f, 0.f, 0.f};
#pragma unroll
    for (int ks = 0; ks < 4; ++ks) {
#pragma unroll
        for (int nt = 0; nt < 8; ++nt) {
            bf16x8 bfr = *(const bf16x8*)(w2s + (((ks << 3) + nt) * 64 + lane) * 8);
            acc[nt] = __builtin_amdgcn_mfma_f32_16x16x32_bf16(afr2[ks], bfr, acc[nt], 0, 0, 0);
        }
    }
#pragma unroll
    for (int nt = 0; nt < 8; ++nt) {
        float bias = b2[(nt << 4) + c16];
        float s1 = 0.f, s2 = 0.f;
#pragma unroll
        for (int i = 0; i < 4; ++i) {
            float v = fmaxf(acc[nt][i] + bias, 0.f);
            int row = (w << 4) + (q << 2) + i;
            s1 += v;
            s2 += v * v;
            tile[row * 136 + (nt << 4) + c16] = (bf16_t)v;
        }
        s1 += __shfl_down(s1, 32); s2 += __shfl_down(s2, 32);
        s1 += __shfl_down(s1, 16); s2 += __shfl_down(s2, 16);
        if (lane < 16) {
            swsum[w][(nt << 4) + lane] = s1;
            swsq[w][(nt << 4) + lane] = s2;
        }
    }
    __syncthreads();

    // per-block partial stats: plain coalesced stores (no atomics)
    {
        float ps = swsum[0][tid & 127] + swsum[1][tid & 127];
        float pq = swsq[0][tid & 127] + swsq[1][tid & 127];
        float* pb = pstats + (size_t)blockIdx.x * 256;
        pb[tid] = ps;          // tid in 0..127
        pb[128 + tid] = pq;
    }

    // ---- Phase 4: quantize rows -> uint8 + scale. 4 threads per row. ----
    {
        int row4 = tid >> 2, t4 = tid & 3;   // rows 0..31
        int node = base + row4;
        const bf16_t* tp = tile + row4 * 136 + t4 * 32;
        bf16x8 v0 = *(const bf16x8*)(tp);
        bf16x8 v1 = *(const bf16x8*)(tp + 8);
        bf16x8 v2 = *(const bf16x8*)(tp + 16);
        bf16x8 v3 = *(const bf16x8*)(tp + 24);
        float am = 0.f;
#pragma unroll
        for (int k = 0; k < 8; ++k) {
            am = fmaxf(am, (float)v0[k]);
            am = fmaxf(am, (float)v1[k]);
            am = fmaxf(am, (float)v2[k]);
            am = fmaxf(am, (float)v3[k]);
        }
        am = fmaxf(am, __shfl_xor(am, 1));
        am = fmaxf(am, __shfl_xor(am, 2));
        float inv = am > 0.f ? 255.f / am : 0.f;
        if (t4 == 0) ysc[node] = am * (1.f / 255.f);
        u32 u[8];
        u[0] = pack4u((float)v0[0], (float)v0[1], (float)v0[2], (float)v0[3], inv);
        u[1] = pack4u((float)v0[4], (float)v0[5], (float)v0[6], (float)v0[7], inv);
        u[2] = pack4u((float)v1[0], (float)v1[1], (float)v1[2], (float)v1[3], inv);
        u[3] = pack4u((float)v1[4], (float)v1[5], (float)v1[6], (float)v1[7], inv);
        u[4] = pack4u((float)v2[0], (float)v2[1], (float)v2[2], (float)v2[3], inv);
        u[5] = pack4u((float)v2[4], (float)v2[5], (float)v2[6], (float)v2[7], inv);
        u[6] = pack4u((float)v3[0], (float)v3[1], (float)v3[2], (float)v3[3], inv);
        u[7] = pack4u((float)v3[4], (float)v3[5], (float)v3[6], (float)v3[7], inv);
        uint4* yp = (uint4*)(y8 + (size_t)node * DD + t4 * 32);
        yp[0] = make_uint4(u[0], u[1], u[2], u[3]);
        yp[1] = make_uint4(u[4], u[5], u[6], u[7]);
    }
}

// ---------------- pooling + head ----------------

// dequantizing segmented mean-pool, 2 nodes in flight per block
__global__ __launch_bounds__(256) void k_pool2u(
    const u8* __restrict__ y8, const float* __restrict__ ysc,
    const int* __restrict__ gstart,
    const float* __restrict__ scale, const float* __restrict__ shift,
    float* __restrict__ pooled)
{
    __shared__ float part[128];
    int g = blockIdx.x;
    int t = threadIdx.x;
    int f = t & 127, h = t >> 7;
    int s = gstart[g], e = gstart[g + 1];
    float acc = 0.f;
    for (int n = s + h; n < e; n += 2)
        acc += ysc[n] * (float)y8[(size_t)n * DD + f];
    if (h == 1) part[f] = acc;
    __syncthreads();
    if (h == 0) {
        acc += part[f];
        float cnt = (float)(e - s);
        float v = acc * scale[f] + cnt * shift[f];
        pooled[g * DD + f] = v / fmaxf(cnt, 1.0f);
    }
}

__global__ void k_head(const float* __restrict__ pooled,
                       const float* __restrict__ lin1w, const float* __restrict__ lin1b,
                       const float* __restrict__ lin2w, const float* __restrict__ lin2b,
                       float* __restrict__ out) {
    __shared__ float p[DD];
    __shared__ float h[DD];
    int g = blockIdx.x;
    int t = threadIdx.x;
    p[t] = pooled[g * DD + t];
    __syncthreads();
    float a = lin1b[t];
    for (int k = 0; k < DD; ++k) a += p[k] * lin1w[k * DD + t];
    h[t] = fmaxf(a, 0.f);
    __syncthreads();
    if (t < 10) {
        float o = lin2b[t];
        for (int k = 0; k < DD; ++k) o += h[k] * lin2w[k * 10 + t];
        out[g * 10 + t] = o;
    }
}

// ---------------- launch ----------------

extern "C" void kernel_launch(void* const* d_in, const int* in_sizes, int n_in,
                              void* d_out, int out_size, void* d_ws, size_t ws_size,
                              hipStream_t stream) {
    const float* x      = (const float*)d_in[0];
    const int*   ei     = (const int*)d_in[1];
    const int*   batch  = (const int*)d_in[2];
    const float* W1s    = (const float*)d_in[3];
    const float* b1s    = (const float*)d_in[4];
    const float* W2s    = (const float*)d_in[5];
    const float* b2s    = (const float*)d_in[6];
    const float* gammas = (const float*)d_in[7];
    const float* betas  = (const float*)d_in[8];
    const float* lin1w  = (const float*)d_in[9];
    const float* lin1b  = (const float*)d_in[10];
    const float* lin2w  = (const float*)d_in[11];
    const float* lin2b  = (const float*)d_in[12];
    float* out = (float*)d_out;

    char* p = (char*)d_ws;
    size_t off = 0;
    auto alloc = [&](size_t bytes) -> char* {
        char* r = p + off;
        off += (bytes + 255) & ~(size_t)255;
        return r;
    };
    int*    deg    = (int*)alloc(N_NODES * 4);
    size_t zero_bytes = off;
    int*    poffs  = (int*)alloc((N_NODES + 1) * 4);
    int*    cursor = (int*)alloc(N_NODES * 4);
    int*    bsum   = (int*)alloc(128 * 4);
    int*    bbase  = (int*)alloc(128 * 4);
    int*    csr    = (int*)alloc(((size_t)N_EDGES + 4 * N_NODES + 64) * 4); // pad-4 + slack
    u8*     x8s    = (u8*)alloc((size_t)N_NODES * DD);   // i8 input; q8b aliases it after L0
    u8*     q8a    = (u8*)alloc((size_t)N_NODES * DD);
    float*  sci    = (float*)alloc(N_NODES * 4);
    float*  sca    = (float*)alloc(N_NODES * 4);
    float*  scb    = (float*)alloc(N_NODES * 4);
    bf16_t* wshuf  = (bf16_t*)alloc(6 * 16384 * 2);
    float*  ss     = (float*)alloc(4 * 256 * 4);
    int*    gstart = (int*)alloc((N_GRAPHS + 1) * 4);
    float*  pooled = (float*)alloc(N_GRAPHS * DD * 4);
    float*  pstats = (float*)alloc((size_t)NTILES * 256 * 4);    // per-block partials
    float*  red    = (float*)alloc(RED_B * 256 * 4);             // stage-2 partials
    if (off > ws_size) return;

    // q8b reuses x8s's storage: x8s is only read by L0; q8b is written by L1
    // and read by L2 (stream-ordered on one stream, no overlap).
    u8* q8b = x8s;

    const int* srcA = ei;
    const int* dstA = ei + N_EDGES;

    k_zero<<<256, 256, 0, stream>>>((float4*)d_ws, (int)(zero_bytes / 16));
    k_hist8<<<1024, 256, 0, stream>>>(dstA, deg);
    k_scan1<<<SCAN_B, 1024, 0, stream>>>(deg, bsum);
    k_scan2<<<1, 128, 0, stream>>>(bsum, bbase, poffs);
    k_scan3<<<SCAN_B, 1024, 0, stream>>>(deg, bbase, poffs, cursor);
    k_fill8<<<1024, 256, 0, stream>>>(srcA, dstA, cursor, csr);
    k_pad<<<(N_NODES * 4 + 255) / 256, 256, 0, stream>>>(deg, poffs, csr);
    k_cvt8<<<1024, 256, 0, stream>>>(x, x8s, sci);
    k_shufw<<<(6 * 16384 + 255) / 256, 256, 0, stream>>>(W1s, W2s, wshuf);
    k_aff_init<<<1, 128, 0, stream>>>(ss);
    k_gbounds<<<(N_NODES + 255) / 256, 256, 0, stream>>>(batch, gstart);

    // L0: x8s (i8) -> q8a. L1: q8a -> q8b (aliases x8s). L2: q8b -> q8a.
    k_layer<true><<<NTILES, 128, 0, stream>>>(
        x8s, sci, q8a, sca, poffs, csr, deg,
        ss + 0 * 256, ss + 0 * 256 + 128,
        wshuf + 0 * 16384, wshuf + 1 * 16384,
        b1s + 0 * DD, b2s + 0 * DD, pstats);
    k_red<<<RED_B, 256, 0, stream>>>(pstats, red);
    k_aff_update<<<1, 128, 0, stream>>>(red, gammas + 0 * DD, betas + 0 * DD,
                                        ss + 1 * 256, ss + 1 * 256 + 128);

    k_layer<false><<<NTILES, 128, 0, stream>>>(
        q8a, sca, q8b, scb, poffs, csr, deg,
        ss + 1 * 256, ss + 1 * 256 + 128,
        wshuf + 2 * 16384, wshuf + 3 * 16384,
        b1s + 1 * DD, b2s + 1 * DD, pstats);
    k_red<<<RED_B, 256, 0, stream>>>(pstats, red);
    k_aff_update<<<1, 128, 0, stream>>>(red, gammas + 1 * DD, betas + 1 * DD,
                                        ss + 2 * 256, ss + 2 * 256 + 128);

    k_layer<false><<<NTILES, 128, 0, stream>>>(
        q8b, scb, q8a, sca, poffs, csr, deg,
        ss + 2 * 256, ss + 2 * 256 + 128,
        wshuf + 4 * 16384, wshuf + 5 * 16384,
        b1s + 2 * DD, b2s + 2 * DD, pstats);
    k_red<<<RED_B, 256, 0, stream>>>(pstats, red);
    k_aff_update<<<1, 128, 0, stream>>>(red, gammas + 2 * DD, betas + 2 * DD,
                                        ss + 3 * 256, ss + 3 * 256 + 128);

    k_pool2u<<<N_GRAPHS, 256, 0, stream>>>(q8a, sca, gstart,
                                           ss + 3 * 256, ss + 3 * 256 + 128, pooled);
    k_head<<<N_GRAPHS, 128, 0, stream>>>(pooled, lin1w, lin1b, lin2w, lin2b, out);
}